// Round 1
// 952.083 us; speedup vs baseline: 1.1697x; 1.1697x over previous
//
#include <hip/hip_runtime.h>

// ---------------------------------------------------------------------------
// DomainGeneralisationBN (SPD batchnorm) — R4: kill global-atomic serialization.
// rocprof R3: k1_g0sum = 255us (longest dispatch), WRITE_SIZE = 64 MB for a
// 16 KB output -> 2M contended device-scope float atomics into 256 cache
// lines (~8K serialized RMW/line).  Same pattern in k3 (4M atomics) and k5.
// Fix: two-stage reduction through d_out (free until k5):
//   k1_xsum: per-n sums, plain stores (8 MB scratch)  -> kred -> G0SUM
//   k3: LDS-merge 2 waves, plain store per-n partial  -> kred -> GTSUM
//   k5: per-block var partial in ws (WS_VPART), k6 gathers.
// MFMA machinery (split-bf16 32x32x16, transposed packed LDS layout) unchanged.
// ---------------------------------------------------------------------------

#define LN  36
#define MSZ (32 * LN)

#define SROW  36
#define SMATU (32 * SROW)   // dwords per split-bf16 matrix buffer

// workspace layout (float offsets)
#define WS_G0SUM 0
#define WS_GTSUM 4096
#define WS_VAR   8192
#define WS_CNT   8196
#define WS_P     8200
#define WS_G0SQ  8208
#define WS_G0ISQ 12304
#define WS_GISQ  16400
#define WS_BSQ   20496
#define WS_VPART 24592      // N floats of per-block variance partials
#define WS_ZERO  8208

// (P+I)^-1 NS init: X0 = AL*I + BE*M, Chebyshev on eigs(M) in [1.15, 8]
#define LOG_AL 0.6073551f
#define LOG_BE (-0.0663776f)

typedef __attribute__((ext_vector_type(8)))  short bf16x8;
typedef __attribute__((ext_vector_type(16))) float f32x16;

union FragU { uint4 u; bf16x8 v; };

__device__ __forceinline__ float wsum(float v) {
#pragma unroll
  for (int o = 32; o > 0; o >>= 1) v += __shfl_xor(v, o, 64);
  return v;
}

// ---------------- MFMA-path helpers ----------------

__device__ __forceinline__ f32x16 mm_mfma(const unsigned* A, const unsigned* B, int ro) {
  f32x16 c;
#pragma unroll
  for (int i = 0; i < 16; ++i) c[i] = 0.f;
#pragma unroll
  for (int t = 0; t < 2; ++t) {
    FragU ah, al, bh, bl;
    ah.u = *(const uint4*)(A + ro + t * 8);
    al.u = *(const uint4*)(A + ro + 16 + t * 8);
    bh.u = *(const uint4*)(B + ro + t * 8);
    bl.u = *(const uint4*)(B + ro + 16 + t * 8);
    c = __builtin_amdgcn_mfma_f32_32x32x16_bf16(ah.v, bh.v, c, 0, 0, 0);
    c = __builtin_amdgcn_mfma_f32_32x32x16_bf16(ah.v, bl.v, c, 0, 0, 0);
    c = __builtin_amdgcn_mfma_f32_32x32x16_bf16(al.v, bh.v, c, 0, 0, 0);
  }
  return c;
}

// store C-regs into split-bf16 transposed storage (result usable as B-operand;
// as A-operand too when symmetric)
__device__ __forceinline__ void st_split(unsigned* buf, const f32x16 c,
                                         int ccol, int h) {
  const int wo = ccol * SROW + 2 * h;
#pragma unroll
  for (int g = 0; g < 4; ++g) {
    const float x0 = c[4*g+0], x1 = c[4*g+1], x2 = c[4*g+2], x3 = c[4*g+3];
    const unsigned a0 = __float_as_uint(x0) + 0x8000u;
    const unsigned a1 = __float_as_uint(x1) + 0x8000u;
    const unsigned a2 = __float_as_uint(x2) + 0x8000u;
    const unsigned a3 = __float_as_uint(x3) + 0x8000u;
    const float l0 = x0 - __uint_as_float(a0 & 0xFFFF0000u);
    const float l1 = x1 - __uint_as_float(a1 & 0xFFFF0000u);
    const float l2 = x2 - __uint_as_float(a2 & 0xFFFF0000u);
    const float l3 = x3 - __uint_as_float(a3 & 0xFFFF0000u);
    uint2 hp, lp;
    hp.x = __builtin_amdgcn_perm(a1, a0, 0x07060302u);
    hp.y = __builtin_amdgcn_perm(a3, a2, 0x07060302u);
    lp.x = __builtin_amdgcn_perm(__float_as_uint(l1), __float_as_uint(l0), 0x07060302u);
    lp.y = __builtin_amdgcn_perm(__float_as_uint(l3), __float_as_uint(l2), 0x07060302u);
    *(uint2*)(buf + wo + 4*g)      = hp;
    *(uint2*)(buf + wo + 16 + 4*g) = lp;
  }
}

// global fp32 row-major 32x32 -> split-bf16 LDS storage (row-major phys).
__device__ __forceinline__ void x2l(const float* __restrict__ g, unsigned* buf,
                                    int lane) {
  const int n = lane >> 1, cb = (lane & 1) * 8;
  unsigned hi[8], lo[8];
#pragma unroll
  for (int u = 0; u < 4; ++u) {
    float4 v = *(const float4*)(g + lane * 16 + u * 4);
    const unsigned a0 = __float_as_uint(v.x) + 0x8000u;
    const unsigned a1 = __float_as_uint(v.y) + 0x8000u;
    const unsigned a2 = __float_as_uint(v.z) + 0x8000u;
    const unsigned a3 = __float_as_uint(v.w) + 0x8000u;
    const float l0 = v.x - __uint_as_float(a0 & 0xFFFF0000u);
    const float l1 = v.y - __uint_as_float(a1 & 0xFFFF0000u);
    const float l2 = v.z - __uint_as_float(a2 & 0xFFFF0000u);
    const float l3 = v.w - __uint_as_float(a3 & 0xFFFF0000u);
    hi[2*u]   = __builtin_amdgcn_perm(a1, a0, 0x07060302u);
    hi[2*u+1] = __builtin_amdgcn_perm(a3, a2, 0x07060302u);
    lo[2*u]   = __builtin_amdgcn_perm(__float_as_uint(l1), __float_as_uint(l0), 0x07060302u);
    lo[2*u+1] = __builtin_amdgcn_perm(__float_as_uint(l3), __float_as_uint(l2), 0x07060302u);
  }
  *(uint4*)(buf + n * SROW + cb)          = make_uint4(hi[0], hi[1], hi[2], hi[3]);
  *(uint4*)(buf + n * SROW + cb + 4)      = make_uint4(hi[4], hi[5], hi[6], hi[7]);
  *(uint4*)(buf + n * SROW + 16 + cb)     = make_uint4(lo[0], lo[1], lo[2], lo[3]);
  *(uint4*)(buf + n * SROW + 16 + cb + 4) = make_uint4(lo[4], lo[5], lo[6], lo[7]);
}

__device__ __forceinline__ void addID(f32x16& c, float v, const float* dm) {
#pragma unroll
  for (int i = 0; i < 16; ++i) c[i] = fmaf(v, dm[i], c[i]);
}

// L = log(P), P = C-regs of the congruence product (SPD, eigs in ~[0.2,5.5]).
__device__ __forceinline__ f32x16 logm_mfma(unsigned* D1, unsigned* D2,
                                            f32x16 M, int ro, int ccol, int h,
                                            const float* dm) {
  addID(M, 1.f, dm);                         // M = P + I
  st_split(D1, M, ccol, h);
  f32x16 t = mm_mfma(D1, D1, ro);            // M^2
  f32x16 V;
#pragma unroll
  for (int i = 0; i < 16; ++i) V[i] = -(LOG_AL * M[i] + LOG_BE * t[i]);
  addID(V, 2.f, dm);                         // V = 2I - M*X0
  st_split(D2, V, ccol, h);
  t = mm_mfma(D1, D2, ro);                   // M*V
  f32x16 X;
#pragma unroll
  for (int i = 0; i < 16; ++i) X[i] = LOG_AL * V[i] + LOG_BE * t[i];  // X1=X0*V
  st_split(D2, X, ccol, h);
#pragma unroll 1
  for (int it = 0; it < 3; ++it) {           // X <- 2X - M X^2
    t = mm_mfma(D2, D2, ro);
    st_split(D2, t, ccol, h);
    t = mm_mfma(D1, D2, ro);
#pragma unroll
    for (int i = 0; i < 16; ++i) X[i] = 2.f * X[i] - t[i];
    st_split(D2, X, ccol, h);
  }
  // Q = X ~= M^-1.  S = I-2Q, S^2 = I-4Q+4Q^2
  t = mm_mfma(D2, D2, ro);                   // Q^2
  f32x16 S2;
#pragma unroll
  for (int i = 0; i < 16; ++i) S2[i] = 4.f * (t[i] - X[i]);
  addID(S2, 1.f, dm);
  st_split(D1, S2, ccol, h);
  f32x16 S;
#pragma unroll
  for (int i = 0; i < 16; ++i) S[i] = -2.f * X[i];
  addID(S, 1.f, dm);
  // Gregory: g(y)=sum_{j=0..8} y^j/(2j+1), Horner
  f32x16 H;
#pragma unroll
  for (int i = 0; i < 16; ++i) H[i] = (1.f / 17.f) * S2[i];
  addID(H, 1.f / 15.f, dm);
  st_split(D2, H, ccol, h);
#pragma unroll 1
  for (int j = 6; j >= 0; --j) {
    H = mm_mfma(D1, D2, ro);
    addID(H, 1.f / (float)(2 * j + 1), dm);
    st_split(D2, H, ccol, h);
  }
  st_split(D1, S, ccol, h);
  t = mm_mfma(D1, D2, ro);                   // S * g(S^2)
#pragma unroll
  for (int i = 0; i < 16; ++i) t[i] *= 2.f;
  return t;
}

// ---------------- fp32-VALU helpers (k2/k4 only, D=4 matrices) ----------------

__device__ __forceinline__ void zero16(float c[16]) {
#pragma unroll
  for (int i = 0; i < 16; ++i) c[i] = 0.f;
}
__device__ __forceinline__ void diag4(float c[16], float v, int dg) {
  if (dg) { c[0] += v; c[5] += v; c[10] += v; c[15] += v; }
}
__device__ __forceinline__ void mm_gen(const float* A, const float* B, float c[16],
                                       int bi4, int bj4) {
  zero16(c);
#pragma unroll 4
  for (int k = 0; k < 32; ++k) {
    float4 a = *(const float4*)(A + k * LN + bi4);
    float4 b = *(const float4*)(B + k * LN + bj4);
    c[0] = fmaf(a.x, b.x, c[0]);  c[1] = fmaf(a.x, b.y, c[1]);
    c[2] = fmaf(a.x, b.z, c[2]);  c[3] = fmaf(a.x, b.w, c[3]);
    c[4] = fmaf(a.y, b.x, c[4]);  c[5] = fmaf(a.y, b.y, c[5]);
    c[6] = fmaf(a.y, b.z, c[6]);  c[7] = fmaf(a.y, b.w, c[7]);
    c[8] = fmaf(a.z, b.x, c[8]);  c[9] = fmaf(a.z, b.y, c[9]);
    c[10]= fmaf(a.z, b.z, c[10]); c[11]= fmaf(a.z, b.w, c[11]);
    c[12]= fmaf(a.w, b.x, c[12]); c[13]= fmaf(a.w, b.y, c[13]);
    c[14]= fmaf(a.w, b.z, c[14]); c[15]= fmaf(a.w, b.w, c[15]);
  }
}
__device__ __forceinline__ void st_row(float* buf, const float c[16], int bi4, int bj4) {
#pragma unroll
  for (int di = 0; di < 4; ++di)
    *(float4*)(buf + (bi4 + di) * LN + bj4) =
        make_float4(c[di*4+0], c[di*4+1], c[di*4+2], c[di*4+3]);
}
__device__ __forceinline__ void st_colf(float* buf, const float c[16], int bi4, int bj4) {
#pragma unroll
  for (int dj = 0; dj < 4; ++dj)
    *(float4*)(buf + (bj4 + dj) * LN + bi4) =
        make_float4(c[0*4+dj], c[1*4+dj], c[2*4+dj], c[3*4+dj]);
}
__device__ __forceinline__ void ldg_mat(const float* __restrict__ g, float c[16],
                                        int bi4, int bj4) {
#pragma unroll
  for (int di = 0; di < 4; ++di) {
    float4 v = *(const float4*)(g + (bi4 + di) * 32 + bj4);
    c[di*4+0] = v.x; c[di*4+1] = v.y; c[di*4+2] = v.z; c[di*4+3] = v.w;
  }
}
__device__ __forceinline__ void stg_mat(float* __restrict__ g, const float c[16],
                                        int bi4, int bj4) {
#pragma unroll
  for (int di = 0; di < 4; ++di)
    *(float4*)(g + (bi4 + di) * 32 + bj4) =
        make_float4(c[di*4+0], c[di*4+1], c[di*4+2], c[di*4+3]);
}
__device__ __forceinline__ void wave_sqrtinv(const float A[16], float Ysq[16], float Zis[16],
                                             float* YB, float* ZB, float* TB,
                                             int bi4, int bj4) {
  const int dg = (bi4 == bj4);
  float ss = 0.f;
#pragma unroll
  for (int i = 0; i < 16; ++i) ss += A[i] * A[i];
  const float th = sqrtf(wsum(ss));
  const float inv = 1.f / th;
  float Y[16], Z[16];
#pragma unroll
  for (int i = 0; i < 16; ++i) Y[i] = A[i] * inv;
  zero16(Z); diag4(Z, 1.f, dg);
  st_row(YB, Y, bi4, bj4);
  st_row(ZB, Z, bi4, bj4);
#pragma unroll 1
  for (int it = 0; it < 13; ++it) {
    float W[16], T[16];
    mm_gen(ZB, YB, W, bi4, bj4);
#pragma unroll
    for (int i = 0; i < 16; ++i) T[i] = -0.5f * W[i];
    diag4(T, 1.5f, dg);
    st_row(TB, T, bi4, bj4);
    mm_gen(YB, TB, Y, bi4, bj4);
    mm_gen(TB, ZB, Z, bi4, bj4);
    st_row(YB, Y, bi4, bj4);
    st_row(ZB, Z, bi4, bj4);
  }
  const float sth = sqrtf(th), isth = 1.f / sth;
#pragma unroll
  for (int i = 0; i < 16; ++i) { Ysq[i] = Y[i] * sth; Zis[i] = Z[i] * isth; }
}

// ------------------------------- kernels -----------------------------------

// per-n sum over the q matrices, plain stores into scratch (d_out).
__global__ __launch_bounds__(256) void k1_xsum(const float* __restrict__ X,
                                               float* __restrict__ scr,
                                               int N, int q) {
  const int w = threadIdx.x >> 6, lane = threadIdx.x & 63;
  const int n = blockIdx.x * 4 + w;
  if (n >= N) return;
  float acc[16];
  zero16(acc);
  const float* base = X + (size_t)n * q * 1024 + lane * 16;
#pragma unroll 4
  for (int j = 0; j < q; ++j) {
    const float* g = base + (size_t)j * 1024;
#pragma unroll
    for (int u = 0; u < 4; ++u) {
      float4 v = *(const float4*)(g + u * 4);
      acc[u*4+0] += v.x; acc[u*4+1] += v.y; acc[u*4+2] += v.z; acc[u*4+3] += v.w;
    }
  }
  float* dst = scr + (size_t)n * 1024 + lane * 16;
#pragma unroll
  for (int u = 0; u < 4; ++u)
    *(float4*)(dst + u * 4) =
        make_float4(acc[u*4+0], acc[u*4+1], acc[u*4+2], acc[u*4+3]);
}

// gather-by-domain reduce: dst[d*1024+e] += sum_{n: ds[n]==d} src[n*1024+e].
// 8 n-chunks, branchless loads (full MLP), final atomics only 8-deep/address.
__global__ __launch_bounds__(256) void kred(const int* __restrict__ ds,
                                            const float* __restrict__ src,
                                            float* __restrict__ dst,
                                            int N, int D) {
  const int obln = D * 4;                    // blocks covering D*1024 outputs
  const int chunk = blockIdx.x / obln;       // 8 chunks over n
  const int ob    = blockIdx.x % obln;
  const int out   = ob * 256 + threadIdx.x;  // [0, D*1024)
  const int d = out >> 10, e = out & 1023;
  const int cs = (N + 7) >> 3;
  const int n0 = chunk * cs;
  const int n1 = min(N, n0 + cs);
  float acc = 0.f;
#pragma unroll 16
  for (int n = n0; n < n1; ++n) {
    const float v = src[(size_t)n * 1024 + e];
    acc += (ds[n] == d) ? v : 0.f;
  }
  atomicAdd(dst + out, acc);
}

__global__ __launch_bounds__(128) void k2_g0funcs(float* __restrict__ ws,
                                                  const int* __restrict__ ds,
                                                  const float* __restrict__ B,
                                                  int N, int q) {
  __shared__ float D[2][3][MSZ];
  const int d = blockIdx.x, tid = threadIdx.x;
  const int w = tid >> 6, lane = tid & 63;
  const int bi4 = (lane >> 3) * 4, bj4 = (lane & 7) * 4;
  float A[16], Y[16], Z[16];
  if (w == 0) {
    int cnt = 0;
    for (int i = lane; i < N; i += 64) cnt += (ds[i] == d) ? 1 : 0;
    const float cntf = wsum((float)cnt);
    if (lane == 0) ws[WS_CNT + d] = cntf;
    ldg_mat(ws + WS_G0SUM + d * 1024, A, bi4, bj4);
    const float s = 1.f / ((float)q * cntf);
#pragma unroll
    for (int i = 0; i < 16; ++i) A[i] *= s;
    wave_sqrtinv(A, Y, Z, D[0][0], D[0][1], D[0][2], bi4, bj4);
    stg_mat(ws + WS_G0SQ  + d * 1024, Y, bi4, bj4);
    stg_mat(ws + WS_G0ISQ + d * 1024, Z, bi4, bj4);
  } else {
    ldg_mat(B + d * 1024, A, bi4, bj4);
    wave_sqrtinv(A, Y, Z, D[1][0], D[1][1], D[1][2], bi4, bj4);
    stg_mat(ws + WS_BSQ + d * 1024, Y, bi4, bj4);
  }
}

__global__ __launch_bounds__(128) void k3_gt(const float* __restrict__ X,
                                             const int* __restrict__ ds,
                                             float* __restrict__ ws,
                                             float* __restrict__ scr, int q) {
  __shared__ unsigned GiB[SMATU], GsB[SMATU];
  __shared__ unsigned DYN[2][2][SMATU];
  __shared__ float RED[1024];
  const int n = blockIdx.x, tid = threadIdx.x;
  const int w = tid >> 6, lane = tid & 63;
  const int ccol = lane & 31, h = lane >> 5;
  const int ro = ccol * SROW + h * 4;
  float dm[16];
#pragma unroll
  for (int i = 0; i < 16; ++i) {
    const int row = (i & 3) + 8 * (i >> 2) + 4 * h;
    dm[i] = (row == ccol) ? 1.f : 0.f;
  }
  const int d = ds[n];
  if (w == 0) x2l(ws + WS_G0ISQ + d * 1024, GiB, lane);
  else        x2l(ws + WS_G0SQ  + d * 1024, GsB, lane);
  __syncthreads();
  unsigned* D1 = DYN[w][0]; unsigned* D2 = DYN[w][1];
  f32x16 acc;
#pragma unroll
  for (int i = 0; i < 16; ++i) acc[i] = 0.f;
  const int half = q >> 1;
#pragma unroll 1
  for (int j = 0; j < half; ++j) {
    const size_t m = (size_t)n * q + (size_t)w * half + j;
    x2l(X + m * 1024, D1, lane);
    f32x16 u = mm_mfma(D1, GiB, ro);           // X * Gi
    st_split(D2, u, ccol, h);
    f32x16 P = mm_mfma(GiB, D2, ro);           // Gi X Gi
    f32x16 L = logm_mfma(D1, D2, P, ro, ccol, h, dm);
    st_split(D1, L, ccol, h);
    u = mm_mfma(D1, GsB, ro);                  // L * Gs
    st_split(D2, u, ccol, h);
    u = mm_mfma(GsB, D2, ro);                  // Gs L Gs
#pragma unroll
    for (int i = 0; i < 16; ++i) acc[i] += u[i];
  }
  // merge the two waves through LDS, plain-store per-n partial (no atomics)
  if (w == 0) {
#pragma unroll
    for (int i = 0; i < 16; ++i) {
      const int row = (i & 3) + 8 * (i >> 2) + 4 * h;
      RED[row * 32 + ccol] = acc[i];
    }
  }
  __syncthreads();
  if (w == 1) {
    float* g = scr + (size_t)n * 1024;
#pragma unroll
    for (int i = 0; i < 16; ++i) {
      const int row = (i & 3) + 8 * (i >> 2) + 4 * h;
      g[row * 32 + ccol] = acc[i] + RED[row * 32 + ccol];
    }
  }
}

__global__ __launch_bounds__(64) void k4_mean(float* __restrict__ ws, int q) {
  __shared__ float GB[MSZ], D1[MSZ], D2[MSZ], D3[MSZ];
  const int d = blockIdx.x, lane = threadIdx.x;
  const int bi4 = (lane >> 3) * 4, bj4 = (lane & 7) * 4;
  const int dg = (bi4 == bj4);
  const float cntf = ws[WS_CNT + d];
  float c[16], t[16];
  ldg_mat(ws + WS_G0ISQ + d * 1024, c, bi4, bj4); st_row(GB, c, bi4, bj4);
  ldg_mat(ws + WS_GTSUM + d * 1024, c, bi4, bj4);
  const float s = 1.f / ((float)q * cntf);
#pragma unroll
  for (int i = 0; i < 16; ++i) c[i] *= s;
  st_row(D1, c, bi4, bj4);
  mm_gen(GB, D1, t, bi4, bj4); st_colf(D2, t, bi4, bj4);
  mm_gen(D2, GB, t, bi4, bj4); st_row(D1, t, bi4, bj4);   // E = Gi GT Gi
  float H[16];
  zero16(H); diag4(H, 2.7557319e-7f, dg);                 // 1/10!
  st_row(D2, H, bi4, bj4);
  float ck = 2.7557319e-7f;
#pragma unroll 1
  for (int kk = 9; kk >= 0; --kk) {
    ck *= (float)(kk + 1);
    mm_gen(D1, D2, H, bi4, bj4);
    diag4(H, ck, dg);
    st_row(D2, H, bi4, bj4);
  }                                                       // exp(E)
  ldg_mat(ws + WS_G0SQ + d * 1024, c, bi4, bj4); st_row(GB, c, bi4, bj4);
  st_row(D1, H, bi4, bj4);
  mm_gen(GB, D1, t, bi4, bj4); st_colf(D2, t, bi4, bj4);
  mm_gen(D2, GB, t, bi4, bj4);                            // G
  float Y[16], Z[16];
  wave_sqrtinv(t, Y, Z, D1, D2, D3, bi4, bj4);
  stg_mat(ws + WS_GISQ + d * 1024, Z, bi4, bj4);
}

__global__ __launch_bounds__(128) void k5_logxc(const float* __restrict__ X,
                                                const int* __restrict__ ds,
                                                float* __restrict__ ws,
                                                float* __restrict__ Lout, int q) {
  __shared__ unsigned GiB[SMATU];
  __shared__ unsigned DYN[2][2][SMATU];
  __shared__ float V2[2];
  const int n = blockIdx.x, tid = threadIdx.x;
  const int w = tid >> 6, lane = tid & 63;
  const int ccol = lane & 31, h = lane >> 5;
  const int ro = ccol * SROW + h * 4;
  float dm[16];
#pragma unroll
  for (int i = 0; i < 16; ++i) {
    const int row = (i & 3) + 8 * (i >> 2) + 4 * h;
    dm[i] = (row == ccol) ? 1.f : 0.f;
  }
  const int d = ds[n];
  if (w == 0) x2l(ws + WS_GISQ + d * 1024, GiB, lane);
  __syncthreads();
  unsigned* D1 = DYN[w][0]; unsigned* D2 = DYN[w][1];
  float vacc = 0.f;
  const int half = q >> 1;
#pragma unroll 1
  for (int j = 0; j < half; ++j) {
    const size_t m = (size_t)n * q + (size_t)w * half + j;
    x2l(X + m * 1024, D1, lane);
    f32x16 u = mm_mfma(D1, GiB, ro);           // X * Gi
    st_split(D2, u, ccol, h);
    f32x16 P = mm_mfma(GiB, D2, ro);           // Xc = Gi X Gi
    f32x16 L = logm_mfma(D1, D2, P, ro, ccol, h, dm);
    float sq = 0.f;
#pragma unroll
    for (int i = 0; i < 16; ++i) sq += L[i] * L[i];
    vacc += sq;
    float* g = Lout + m * 1024;
#pragma unroll
    for (int i = 0; i < 16; ++i) {
      const int row = (i & 3) + 8 * (i >> 2) + 4 * h;
      g[row * 32 + ccol] = L[i];
    }
  }
  vacc = wsum(vacc);
  if (lane == 0) V2[w] = vacc;
  __syncthreads();
  if (tid == 0) ws[WS_VPART + n] = V2[0] + V2[1];   // plain store, no atomics
}

__global__ __launch_bounds__(64) void k6_p(const int* __restrict__ ds,
                                           float* __restrict__ ws,
                                           int N, int q, int D) {
  const int lane = threadIdx.x;
  float a0 = 0.f, a1 = 0.f, a2 = 0.f, a3 = 0.f;
  for (int n = lane; n < N; n += 64) {
    const int d = ds[n];
    const float v = ws[WS_VPART + n];
    a0 += (d == 0) ? v : 0.f;
    a1 += (d == 1) ? v : 0.f;
    a2 += (d == 2) ? v : 0.f;
    a3 += (d == 3) ? v : 0.f;
  }
  a0 = wsum(a0); a1 = wsum(a1); a2 = wsum(a2); a3 = wsum(a3);
  if (lane < D) {
    const float var0 = (lane == 0) ? a0 : (lane == 1) ? a1 : (lane == 2) ? a2 : a3;
    const float cntf = ws[WS_CNT + lane];
    const float var = var0 / ((float)q * cntf);
    ws[WS_P + lane] = sqrtf(1.f / (var + 1e-5f));
  }
}

__global__ __launch_bounds__(128) void k7_out(const int* __restrict__ ds,
                                              const float* __restrict__ ws,
                                              const float* __restrict__ R,
                                              float* __restrict__ io, int q) {
  __shared__ unsigned RB[SMATU], BsB[SMATU];
  __shared__ unsigned DYN[2][2][SMATU];
  const int n = blockIdx.x, tid = threadIdx.x;
  const int w = tid >> 6, lane = tid & 63;
  const int ccol = lane & 31, h = lane >> 5;
  const int ro = ccol * SROW + h * 4;
  float dm[16];
#pragma unroll
  for (int i = 0; i < 16; ++i) {
    const int row = (i & 3) + 8 * (i >> 2) + 4 * h;
    dm[i] = (row == ccol) ? 1.f : 0.f;
  }
  const int d = ds[n];
  if (w == 0) x2l(R + d * 1024, RB, lane);
  else        x2l(ws + WS_BSQ + d * 1024, BsB, lane);
  __syncthreads();
  const float ph = 0.5f * ws[WS_P + d];
  // Taylor coeffs of exp(ph*L), deg 10, folded scale
  float coef[11];
  coef[0] = 1.f;
  coef[1] = ph;
  coef[2] = coef[1] * ph * 0.5f;
  coef[3] = coef[2] * ph * (1.f / 3.f);
  coef[4] = coef[3] * ph * 0.25f;
  coef[5] = coef[4] * ph * 0.2f;
  coef[6] = coef[5] * ph * (1.f / 6.f);
  coef[7] = coef[6] * ph * (1.f / 7.f);
  coef[8] = coef[7] * ph * 0.125f;
  coef[9] = coef[8] * ph * (1.f / 9.f);
  coef[10] = coef[9] * ph * 0.1f;
  unsigned* D1 = DYN[w][0]; unsigned* D2 = DYN[w][1];
  const int half = q >> 1;
#pragma unroll 1
  for (int j = 0; j < half; ++j) {
    const size_t m = (size_t)n * q + (size_t)w * half + j;
    x2l(io + m * 1024, D1, lane);              // L
    f32x16 H;
#pragma unroll
    for (int i = 0; i < 16; ++i) H[i] = 0.f;
    addID(H, coef[10], dm);
    st_split(D2, H, ccol, h);
#pragma unroll 1
    for (int kk = 9; kk >= 0; --kk) {          // H = L*H + c_kk I
      H = mm_mfma(D1, D2, ro);
      addID(H, coef[kk], dm);
      st_split(D2, H, ccol, h);
    }
    f32x16 t = mm_mfma(D2, D2, ro);            // Xp = H^2 = exp(p L)
    st_split(D1, t, ccol, h);
    t = mm_mfma(D1, RB, ro);                   // Xp * R^T
    st_split(D2, t, ccol, h);
    t = mm_mfma(RB, D2, ro);                   // Xr = R Xp R^T
    st_split(D1, t, ccol, h);
    t = mm_mfma(D1, BsB, ro);                  // Xr * Bs
    st_split(D2, t, ccol, h);
    t = mm_mfma(BsB, D2, ro);                  // out = Bs Xr Bs
    float* g = io + m * 1024;
#pragma unroll
    for (int i = 0; i < 16; ++i) {
      const int row = (i & 3) + 8 * (i >> 2) + 4 * h;
      g[row * 32 + ccol] = t[i];
    }
  }
}

// ------------------------------- launcher ----------------------------------

extern "C" void kernel_launch(void* const* d_in, const int* in_sizes, int n_in,
                              void* d_out, int out_size, void* d_ws, size_t ws_size,
                              hipStream_t stream) {
  const float* X  = (const float*)d_in[0];
  const int*   ds = (const int*)d_in[1];
  const float* R  = (const float*)d_in[2];
  const float* B  = (const float*)d_in[3];
  float* out = (float*)d_out;
  float* ws  = (float*)d_ws;
  const int N = in_sizes[1];
  const int q = in_sizes[0] / (N * 1024);
  const int D = in_sizes[2] / 1024;
  (void)n_in; (void)out_size; (void)ws_size;

  // d_out doubles as an 8 MB reduction scratch until k5 overwrites it.
  float* scr = out;

  hipMemsetAsync(d_ws, 0, WS_ZERO * sizeof(float), stream);
  k1_xsum   <<<dim3((N + 3) / 4), dim3(256), 0, stream>>>(X, scr, N, q);
  kred      <<<dim3(8 * D * 4), dim3(256), 0, stream>>>(ds, scr, ws + WS_G0SUM, N, D);
  k2_g0funcs<<<dim3(D), dim3(128), 0, stream>>>(ws, ds, B, N, q);
  k3_gt     <<<dim3(N), dim3(128), 0, stream>>>(X, ds, ws, scr, q);
  kred      <<<dim3(8 * D * 4), dim3(256), 0, stream>>>(ds, scr, ws + WS_GTSUM, N, D);
  k4_mean   <<<dim3(D), dim3(64),  0, stream>>>(ws, q);
  k5_logxc  <<<dim3(N), dim3(128), 0, stream>>>(X, ds, ws, out, q);
  k6_p      <<<dim3(1), dim3(64),  0, stream>>>(ds, ws, N, q, D);
  k7_out    <<<dim3(N), dim3(128), 0, stream>>>(ds, ws, R, out, q);
}

// Round 2
// 839.238 us; speedup vs baseline: 1.3270x; 1.1345x over previous
//
#include <hip/hip_runtime.h>

// ---------------------------------------------------------------------------
// DomainGeneralisationBN (SPD batchnorm) — R5: register-fragment forwarding +
// Paterson-Stockmeyer.  rocprof R4: k3=247us, MfmaUtil 24%, VALUBusy 56%,
// occupancy 20%, 2.4e7 LDS-conflict cycles -> latency-bound on LDS round-trips.
// Changes:
//  * Frag struct: split-bf16 operand fragments live in VGPRs; each produced
//    matrix does ONE st_split+ld_frag round-trip (stld), consumers are pure
//    register MFMA (mm_ff).  Loop-invariant frags (Gi,Gs,R,Bs) hoisted.
//  * PS regrouping: Gregory deg-8 via pair-Horner in y^2 (7->4 mm); k7 exp
//    deg-10 via pair-Horner in L^2 (10->5 mm); S*g folded to g-2Q*g.
//    k3: 21->18 mm/matrix, k5: 19->16, k7: 15->10.
//  * LDS: one scratch/wave; k3 31.7KB -> 17.9KB.
// Reduction scheme (R4) unchanged: k1_xsum+kred, k3 LDS-merge + kred, VPART.
// ---------------------------------------------------------------------------

#define LN  36
#define MSZ (32 * LN)

#define SROW  36
#define SMATU (32 * SROW)   // dwords per split-bf16 matrix buffer

// workspace layout (float offsets)
#define WS_G0SUM 0
#define WS_GTSUM 4096
#define WS_VAR   8192
#define WS_CNT   8196
#define WS_P     8200
#define WS_G0SQ  8208
#define WS_G0ISQ 12304
#define WS_GISQ  16400
#define WS_BSQ   20496
#define WS_VPART 24592      // N floats of per-block variance partials
#define WS_ZERO  8208

// (P+I)^-1 NS init: X0 = AL*I + BE*M, Chebyshev on eigs(M) in [1.15, 8]
#define LOG_AL 0.6073551f
#define LOG_BE (-0.0663776f)

typedef __attribute__((ext_vector_type(8)))  short bf16x8;
typedef __attribute__((ext_vector_type(16))) float f32x16;

union FragU { uint4 u; bf16x8 v; };

struct Frag { bf16x8 h0, h1, l0, l1; };

__device__ __forceinline__ float wsum(float v) {
#pragma unroll
  for (int o = 32; o > 0; o >>= 1) v += __shfl_xor(v, o, 64);
  return v;
}

// ---------------- MFMA-path helpers ----------------

// load a fragment (B-operand of stored matrix; A-operand too when the stored
// matrix is symmetric, or when stored row-major by x2l: A of M / B of M^T)
__device__ __forceinline__ Frag ld_frag(const unsigned* buf, int ro) {
  FragU a, b, c, d;
  a.u = *(const uint4*)(buf + ro);
  b.u = *(const uint4*)(buf + ro + 8);
  c.u = *(const uint4*)(buf + ro + 16);
  d.u = *(const uint4*)(buf + ro + 24);
  Frag f; f.h0 = a.v; f.h1 = b.v; f.l0 = c.v; f.l1 = d.v;
  return f;
}

// C = A*B with split-bf16 3-product scheme, all operands in registers.
__device__ __forceinline__ f32x16 mm_ff(const Frag A, const Frag B) {
  f32x16 c;
#pragma unroll
  for (int i = 0; i < 16; ++i) c[i] = 0.f;
  c = __builtin_amdgcn_mfma_f32_32x32x16_bf16(A.h0, B.h0, c, 0, 0, 0);
  c = __builtin_amdgcn_mfma_f32_32x32x16_bf16(A.h0, B.l0, c, 0, 0, 0);
  c = __builtin_amdgcn_mfma_f32_32x32x16_bf16(A.l0, B.h0, c, 0, 0, 0);
  c = __builtin_amdgcn_mfma_f32_32x32x16_bf16(A.h1, B.h1, c, 0, 0, 0);
  c = __builtin_amdgcn_mfma_f32_32x32x16_bf16(A.h1, B.l1, c, 0, 0, 0);
  c = __builtin_amdgcn_mfma_f32_32x32x16_bf16(A.l1, B.h1, c, 0, 0, 0);
  return c;
}

// store C-regs into split-bf16 transposed storage
__device__ __forceinline__ void st_split(unsigned* buf, const f32x16 c,
                                         int ccol, int h) {
  const int wo = ccol * SROW + 2 * h;
#pragma unroll
  for (int g = 0; g < 4; ++g) {
    const float x0 = c[4*g+0], x1 = c[4*g+1], x2 = c[4*g+2], x3 = c[4*g+3];
    const unsigned a0 = __float_as_uint(x0) + 0x8000u;
    const unsigned a1 = __float_as_uint(x1) + 0x8000u;
    const unsigned a2 = __float_as_uint(x2) + 0x8000u;
    const unsigned a3 = __float_as_uint(x3) + 0x8000u;
    const float l0 = x0 - __uint_as_float(a0 & 0xFFFF0000u);
    const float l1 = x1 - __uint_as_float(a1 & 0xFFFF0000u);
    const float l2 = x2 - __uint_as_float(a2 & 0xFFFF0000u);
    const float l3 = x3 - __uint_as_float(a3 & 0xFFFF0000u);
    uint2 hp, lp;
    hp.x = __builtin_amdgcn_perm(a1, a0, 0x07060302u);
    hp.y = __builtin_amdgcn_perm(a3, a2, 0x07060302u);
    lp.x = __builtin_amdgcn_perm(__float_as_uint(l1), __float_as_uint(l0), 0x07060302u);
    lp.y = __builtin_amdgcn_perm(__float_as_uint(l3), __float_as_uint(l2), 0x07060302u);
    *(uint2*)(buf + wo + 4*g)      = hp;
    *(uint2*)(buf + wo + 16 + 4*g) = lp;
  }
}

// round-trip: store C-regs, read back own fragment (wave-private buffer)
__device__ __forceinline__ Frag stld(unsigned* buf, const f32x16 c,
                                     int ccol, int h, int ro) {
  st_split(buf, c, ccol, h);
  return ld_frag(buf, ro);
}

// global fp32 row-major 32x32 -> split-bf16 LDS storage (row-major phys).
__device__ __forceinline__ void x2l(const float* __restrict__ g, unsigned* buf,
                                    int lane) {
  const int n = lane >> 1, cb = (lane & 1) * 8;
  unsigned hi[8], lo[8];
#pragma unroll
  for (int u = 0; u < 4; ++u) {
    float4 v = *(const float4*)(g + lane * 16 + u * 4);
    const unsigned a0 = __float_as_uint(v.x) + 0x8000u;
    const unsigned a1 = __float_as_uint(v.y) + 0x8000u;
    const unsigned a2 = __float_as_uint(v.z) + 0x8000u;
    const unsigned a3 = __float_as_uint(v.w) + 0x8000u;
    const float l0 = v.x - __uint_as_float(a0 & 0xFFFF0000u);
    const float l1 = v.y - __uint_as_float(a1 & 0xFFFF0000u);
    const float l2 = v.z - __uint_as_float(a2 & 0xFFFF0000u);
    const float l3 = v.w - __uint_as_float(a3 & 0xFFFF0000u);
    hi[2*u]   = __builtin_amdgcn_perm(a1, a0, 0x07060302u);
    hi[2*u+1] = __builtin_amdgcn_perm(a3, a2, 0x07060302u);
    lo[2*u]   = __builtin_amdgcn_perm(__float_as_uint(l1), __float_as_uint(l0), 0x07060302u);
    lo[2*u+1] = __builtin_amdgcn_perm(__float_as_uint(l3), __float_as_uint(l2), 0x07060302u);
  }
  *(uint4*)(buf + n * SROW + cb)          = make_uint4(hi[0], hi[1], hi[2], hi[3]);
  *(uint4*)(buf + n * SROW + cb + 4)      = make_uint4(hi[4], hi[5], hi[6], hi[7]);
  *(uint4*)(buf + n * SROW + 16 + cb)     = make_uint4(lo[0], lo[1], lo[2], lo[3]);
  *(uint4*)(buf + n * SROW + 16 + cb + 4) = make_uint4(lo[4], lo[5], lo[6], lo[7]);
}

__device__ __forceinline__ void addID(f32x16& c, float v, const float* dm) {
#pragma unroll
  for (int i = 0; i < 16; ++i) c[i] = fmaf(v, dm[i], c[i]);
}

// L = log(P), P in C-regs (SPD, eigs ~[0.2,5.5]).  One wave-private scratch D.
// NS inverse of M=P+I (Chebyshev init + 3 iters), Cayley S=I-2Q, Gregory
// deg-8 via pair-Horner in y^2 (PS), final L = 2g - 4*Q*g.
__device__ __forceinline__ f32x16 logm_ps(unsigned* D, f32x16 P, int ro,
                                          int ccol, int h, const float* dm) {
  f32x16 M = P;
  addID(M, 1.f, dm);                         // M = P + I
  Frag FM = stld(D, M, ccol, h, ro);
  f32x16 t = mm_ff(FM, FM);                  // M^2
  f32x16 V;
#pragma unroll
  for (int i = 0; i < 16; ++i) V[i] = -(LOG_AL * M[i] + LOG_BE * t[i]);
  addID(V, 2.f, dm);                         // V = 2I - M*X0
  Frag FV = stld(D, V, ccol, h, ro);
  t = mm_ff(FM, FV);                         // M*V
  f32x16 X;
#pragma unroll
  for (int i = 0; i < 16; ++i) X[i] = LOG_AL * V[i] + LOG_BE * t[i];  // X0*V
  Frag FX = stld(D, X, ccol, h, ro);
#pragma unroll 1
  for (int it = 0; it < 3; ++it) {           // X <- 2X - M X^2
    t = mm_ff(FX, FX);
    Frag Ft = stld(D, t, ccol, h, ro);
    t = mm_ff(FM, Ft);
#pragma unroll
    for (int i = 0; i < 16; ++i) X[i] = 2.f * X[i] - t[i];
    FX = stld(D, X, ccol, h, ro);
  }
  // Q = X ~= M^-1.  S2 = I - 4Q + 4Q^2 (eigs of S^2 in [0, ~0.48])
  t = mm_ff(FX, FX);                         // Q^2
  f32x16 S2;
#pragma unroll
  for (int i = 0; i < 16; ++i) S2[i] = 4.f * (t[i] - X[i]);
  addID(S2, 1.f, dm);
  Frag Fy = stld(D, S2, ccol, h, ro);
  t = mm_ff(Fy, Fy);                         // w = y^2 (C-regs in t)
  Frag Fw = stld(D, t, ccol, h, ro);
  // g(y) = sum_{j=0..8} y^j/(2j+1), pair-Horner in w:
  // G = ((P4w+P3)w+P2)w+P1)w+P0, Pj = c_{2j} I + c_{2j+1} y
  f32x16 G;
#pragma unroll
  for (int i = 0; i < 16; ++i) G[i] = (1.f/17.f) * t[i] + (1.f/15.f) * S2[i];
  addID(G, 1.f/13.f, dm);
  Frag FG = stld(D, G, ccol, h, ro);
  t = mm_ff(FG, Fw);
#pragma unroll
  for (int i = 0; i < 16; ++i) G[i] = t[i] + (1.f/11.f) * S2[i];
  addID(G, 1.f/9.f, dm);
  FG = stld(D, G, ccol, h, ro);
  t = mm_ff(FG, Fw);
#pragma unroll
  for (int i = 0; i < 16; ++i) G[i] = t[i] + (1.f/7.f) * S2[i];
  addID(G, 1.f/5.f, dm);
  FG = stld(D, G, ccol, h, ro);
  t = mm_ff(FG, Fw);
#pragma unroll
  for (int i = 0; i < 16; ++i) G[i] = t[i] + (1.f/3.f) * S2[i];
  addID(G, 1.f, dm);
  FG = stld(D, G, ccol, h, ro);
  // L = 2 S g = 2(I-2Q) g = 2G - 4 Q*g
  t = mm_ff(FX, FG);
  f32x16 L;
#pragma unroll
  for (int i = 0; i < 16; ++i) L[i] = 2.f * G[i] - 4.f * t[i];
  return L;
}

// ---------------- fp32-VALU helpers (k2/k4 only, D=4 matrices) ----------------

__device__ __forceinline__ void zero16(float c[16]) {
#pragma unroll
  for (int i = 0; i < 16; ++i) c[i] = 0.f;
}
__device__ __forceinline__ void diag4(float c[16], float v, int dg) {
  if (dg) { c[0] += v; c[5] += v; c[10] += v; c[15] += v; }
}
__device__ __forceinline__ void mm_gen(const float* A, const float* B, float c[16],
                                       int bi4, int bj4) {
  zero16(c);
#pragma unroll 4
  for (int k = 0; k < 32; ++k) {
    float4 a = *(const float4*)(A + k * LN + bi4);
    float4 b = *(const float4*)(B + k * LN + bj4);
    c[0] = fmaf(a.x, b.x, c[0]);  c[1] = fmaf(a.x, b.y, c[1]);
    c[2] = fmaf(a.x, b.z, c[2]);  c[3] = fmaf(a.x, b.w, c[3]);
    c[4] = fmaf(a.y, b.x, c[4]);  c[5] = fmaf(a.y, b.y, c[5]);
    c[6] = fmaf(a.y, b.z, c[6]);  c[7] = fmaf(a.y, b.w, c[7]);
    c[8] = fmaf(a.z, b.x, c[8]);  c[9] = fmaf(a.z, b.y, c[9]);
    c[10]= fmaf(a.z, b.z, c[10]); c[11]= fmaf(a.z, b.w, c[11]);
    c[12]= fmaf(a.w, b.x, c[12]); c[13]= fmaf(a.w, b.y, c[13]);
    c[14]= fmaf(a.w, b.z, c[14]); c[15]= fmaf(a.w, b.w, c[15]);
  }
}
__device__ __forceinline__ void st_row(float* buf, const float c[16], int bi4, int bj4) {
#pragma unroll
  for (int di = 0; di < 4; ++di)
    *(float4*)(buf + (bi4 + di) * LN + bj4) =
        make_float4(c[di*4+0], c[di*4+1], c[di*4+2], c[di*4+3]);
}
__device__ __forceinline__ void st_colf(float* buf, const float c[16], int bi4, int bj4) {
#pragma unroll
  for (int dj = 0; dj < 4; ++dj)
    *(float4*)(buf + (bj4 + dj) * LN + bi4) =
        make_float4(c[0*4+dj], c[1*4+dj], c[2*4+dj], c[3*4+dj]);
}
__device__ __forceinline__ void ldg_mat(const float* __restrict__ g, float c[16],
                                        int bi4, int bj4) {
#pragma unroll
  for (int di = 0; di < 4; ++di) {
    float4 v = *(const float4*)(g + (bi4 + di) * 32 + bj4);
    c[di*4+0] = v.x; c[di*4+1] = v.y; c[di*4+2] = v.z; c[di*4+3] = v.w;
  }
}
__device__ __forceinline__ void stg_mat(float* __restrict__ g, const float c[16],
                                        int bi4, int bj4) {
#pragma unroll
  for (int di = 0; di < 4; ++di)
    *(float4*)(g + (bi4 + di) * 32 + bj4) =
        make_float4(c[di*4+0], c[di*4+1], c[di*4+2], c[di*4+3]);
}
__device__ __forceinline__ void wave_sqrtinv(const float A[16], float Ysq[16], float Zis[16],
                                             float* YB, float* ZB, float* TB,
                                             int bi4, int bj4) {
  const int dg = (bi4 == bj4);
  float ss = 0.f;
#pragma unroll
  for (int i = 0; i < 16; ++i) ss += A[i] * A[i];
  const float th = sqrtf(wsum(ss));
  const float inv = 1.f / th;
  float Y[16], Z[16];
#pragma unroll
  for (int i = 0; i < 16; ++i) Y[i] = A[i] * inv;
  zero16(Z); diag4(Z, 1.f, dg);
  st_row(YB, Y, bi4, bj4);
  st_row(ZB, Z, bi4, bj4);
#pragma unroll 1
  for (int it = 0; it < 13; ++it) {
    float W[16], T[16];
    mm_gen(ZB, YB, W, bi4, bj4);
#pragma unroll
    for (int i = 0; i < 16; ++i) T[i] = -0.5f * W[i];
    diag4(T, 1.5f, dg);
    st_row(TB, T, bi4, bj4);
    mm_gen(YB, TB, Y, bi4, bj4);
    mm_gen(TB, ZB, Z, bi4, bj4);
    st_row(YB, Y, bi4, bj4);
    st_row(ZB, Z, bi4, bj4);
  }
  const float sth = sqrtf(th), isth = 1.f / sth;
#pragma unroll
  for (int i = 0; i < 16; ++i) { Ysq[i] = Y[i] * sth; Zis[i] = Z[i] * isth; }
}

// ------------------------------- kernels -----------------------------------

// per-n sum over the q matrices, plain stores into scratch (d_out).
__global__ __launch_bounds__(256) void k1_xsum(const float* __restrict__ X,
                                               float* __restrict__ scr,
                                               int N, int q) {
  const int w = threadIdx.x >> 6, lane = threadIdx.x & 63;
  const int n = blockIdx.x * 4 + w;
  if (n >= N) return;
  float acc[16];
  zero16(acc);
  const float* base = X + (size_t)n * q * 1024 + lane * 16;
#pragma unroll 4
  for (int j = 0; j < q; ++j) {
    const float* g = base + (size_t)j * 1024;
#pragma unroll
    for (int u = 0; u < 4; ++u) {
      float4 v = *(const float4*)(g + u * 4);
      acc[u*4+0] += v.x; acc[u*4+1] += v.y; acc[u*4+2] += v.z; acc[u*4+3] += v.w;
    }
  }
  float* dst = scr + (size_t)n * 1024 + lane * 16;
#pragma unroll
  for (int u = 0; u < 4; ++u)
    *(float4*)(dst + u * 4) =
        make_float4(acc[u*4+0], acc[u*4+1], acc[u*4+2], acc[u*4+3]);
}

// gather-by-domain reduce: dst[d*1024+e] += sum_{n: ds[n]==d} src[n*1024+e].
__global__ __launch_bounds__(256) void kred(const int* __restrict__ ds,
                                            const float* __restrict__ src,
                                            float* __restrict__ dst,
                                            int N, int D) {
  const int obln = D * 4;
  const int chunk = blockIdx.x / obln;
  const int ob    = blockIdx.x % obln;
  const int out   = ob * 256 + threadIdx.x;
  const int d = out >> 10, e = out & 1023;
  const int cs = (N + 7) >> 3;
  const int n0 = chunk * cs;
  const int n1 = min(N, n0 + cs);
  float acc = 0.f;
#pragma unroll 16
  for (int n = n0; n < n1; ++n) {
    const float v = src[(size_t)n * 1024 + e];
    acc += (ds[n] == d) ? v : 0.f;
  }
  atomicAdd(dst + out, acc);
}

__global__ __launch_bounds__(128) void k2_g0funcs(float* __restrict__ ws,
                                                  const int* __restrict__ ds,
                                                  const float* __restrict__ B,
                                                  int N, int q) {
  __shared__ float D[2][3][MSZ];
  const int d = blockIdx.x, tid = threadIdx.x;
  const int w = tid >> 6, lane = tid & 63;
  const int bi4 = (lane >> 3) * 4, bj4 = (lane & 7) * 4;
  float A[16], Y[16], Z[16];
  if (w == 0) {
    int cnt = 0;
    for (int i = lane; i < N; i += 64) cnt += (ds[i] == d) ? 1 : 0;
    const float cntf = wsum((float)cnt);
    if (lane == 0) ws[WS_CNT + d] = cntf;
    ldg_mat(ws + WS_G0SUM + d * 1024, A, bi4, bj4);
    const float s = 1.f / ((float)q * cntf);
#pragma unroll
    for (int i = 0; i < 16; ++i) A[i] *= s;
    wave_sqrtinv(A, Y, Z, D[0][0], D[0][1], D[0][2], bi4, bj4);
    stg_mat(ws + WS_G0SQ  + d * 1024, Y, bi4, bj4);
    stg_mat(ws + WS_G0ISQ + d * 1024, Z, bi4, bj4);
  } else {
    ldg_mat(B + d * 1024, A, bi4, bj4);
    wave_sqrtinv(A, Y, Z, D[1][0], D[1][1], D[1][2], bi4, bj4);
    stg_mat(ws + WS_BSQ + d * 1024, Y, bi4, bj4);
  }
}

__global__ __launch_bounds__(128) void k3_gt(const float* __restrict__ X,
                                             const int* __restrict__ ds,
                                             float* __restrict__ ws,
                                             float* __restrict__ scr, int q) {
  __shared__ unsigned SH[2][SMATU];
  __shared__ unsigned GsB[SMATU];
  __shared__ float RED[1024];
  const int n = blockIdx.x, tid = threadIdx.x;
  const int w = tid >> 6, lane = tid & 63;
  const int ccol = lane & 31, h = lane >> 5;
  const int ro = ccol * SROW + h * 4;
  float dm[16];
#pragma unroll
  for (int i = 0; i < 16; ++i) {
    const int row = (i & 3) + 8 * (i >> 2) + 4 * h;
    dm[i] = (row == ccol) ? 1.f : 0.f;
  }
  const int d = ds[n];
  if (w == 0) x2l(ws + WS_G0ISQ + d * 1024, SH[0], lane);
  else        x2l(ws + WS_G0SQ  + d * 1024, GsB, lane);
  __syncthreads();
  const Frag FGi = ld_frag(SH[0], ro);
  const Frag FGs = ld_frag(GsB, ro);
  __syncthreads();
  unsigned* Dw = SH[w];
  f32x16 acc;
#pragma unroll
  for (int i = 0; i < 16; ++i) acc[i] = 0.f;
  const int half = q >> 1;
#pragma unroll 1
  for (int j = 0; j < half; ++j) {
    const size_t m = (size_t)n * q + (size_t)w * half + j;
    x2l(X + m * 1024, Dw, lane);
    Frag FX0 = ld_frag(Dw, ro);
    f32x16 u = mm_ff(FX0, FGi);                // X * Gi
    Frag Fu = stld(Dw, u, ccol, h, ro);
    f32x16 P = mm_ff(FGi, Fu);                 // Gi X Gi
    f32x16 L = logm_ps(Dw, P, ro, ccol, h, dm);
    Frag FL = stld(Dw, L, ccol, h, ro);
    u = mm_ff(FL, FGs);                        // L * Gs
    Fu = stld(Dw, u, ccol, h, ro);
    u = mm_ff(FGs, Fu);                        // Gs L Gs
#pragma unroll
    for (int i = 0; i < 16; ++i) acc[i] += u[i];
  }
  // merge the two waves through LDS, plain-store per-n partial (no atomics)
  if (w == 0) {
#pragma unroll
    for (int i = 0; i < 16; ++i) {
      const int row = (i & 3) + 8 * (i >> 2) + 4 * h;
      RED[row * 32 + ccol] = acc[i];
    }
  }
  __syncthreads();
  if (w == 1) {
    float* g = scr + (size_t)n * 1024;
#pragma unroll
    for (int i = 0; i < 16; ++i) {
      const int row = (i & 3) + 8 * (i >> 2) + 4 * h;
      g[row * 32 + ccol] = acc[i] + RED[row * 32 + ccol];
    }
  }
}

__global__ __launch_bounds__(64) void k4_mean(float* __restrict__ ws, int q) {
  __shared__ float GB[MSZ], D1[MSZ], D2[MSZ], D3[MSZ];
  const int d = blockIdx.x, lane = threadIdx.x;
  const int bi4 = (lane >> 3) * 4, bj4 = (lane & 7) * 4;
  const int dg = (bi4 == bj4);
  const float cntf = ws[WS_CNT + d];
  float c[16], t[16];
  ldg_mat(ws + WS_G0ISQ + d * 1024, c, bi4, bj4); st_row(GB, c, bi4, bj4);
  ldg_mat(ws + WS_GTSUM + d * 1024, c, bi4, bj4);
  const float s = 1.f / ((float)q * cntf);
#pragma unroll
  for (int i = 0; i < 16; ++i) c[i] *= s;
  st_row(D1, c, bi4, bj4);
  mm_gen(GB, D1, t, bi4, bj4); st_colf(D2, t, bi4, bj4);
  mm_gen(D2, GB, t, bi4, bj4); st_row(D1, t, bi4, bj4);   // E = Gi GT Gi
  float H[16];
  zero16(H); diag4(H, 2.7557319e-7f, dg);                 // 1/10!
  st_row(D2, H, bi4, bj4);
  float ck = 2.7557319e-7f;
#pragma unroll 1
  for (int kk = 9; kk >= 0; --kk) {
    ck *= (float)(kk + 1);
    mm_gen(D1, D2, H, bi4, bj4);
    diag4(H, ck, dg);
    st_row(D2, H, bi4, bj4);
  }                                                       // exp(E)
  ldg_mat(ws + WS_G0SQ + d * 1024, c, bi4, bj4); st_row(GB, c, bi4, bj4);
  st_row(D1, H, bi4, bj4);
  mm_gen(GB, D1, t, bi4, bj4); st_colf(D2, t, bi4, bj4);
  mm_gen(D2, GB, t, bi4, bj4);                            // G
  float Y[16], Z[16];
  wave_sqrtinv(t, Y, Z, D1, D2, D3, bi4, bj4);
  stg_mat(ws + WS_GISQ + d * 1024, Z, bi4, bj4);
}

__global__ __launch_bounds__(128) void k5_logxc(const float* __restrict__ X,
                                                const int* __restrict__ ds,
                                                float* __restrict__ ws,
                                                float* __restrict__ Lout, int q) {
  __shared__ unsigned SH[2][SMATU];
  __shared__ float V2[2];
  const int n = blockIdx.x, tid = threadIdx.x;
  const int w = tid >> 6, lane = tid & 63;
  const int ccol = lane & 31, h = lane >> 5;
  const int ro = ccol * SROW + h * 4;
  float dm[16];
#pragma unroll
  for (int i = 0; i < 16; ++i) {
    const int row = (i & 3) + 8 * (i >> 2) + 4 * h;
    dm[i] = (row == ccol) ? 1.f : 0.f;
  }
  const int d = ds[n];
  if (w == 0) x2l(ws + WS_GISQ + d * 1024, SH[0], lane);
  __syncthreads();
  const Frag FGi = ld_frag(SH[0], ro);
  __syncthreads();
  unsigned* Dw = SH[w];
  float vacc = 0.f;
  const int half = q >> 1;
#pragma unroll 1
  for (int j = 0; j < half; ++j) {
    const size_t m = (size_t)n * q + (size_t)w * half + j;
    x2l(X + m * 1024, Dw, lane);
    Frag FX0 = ld_frag(Dw, ro);
    f32x16 u = mm_ff(FX0, FGi);                // X * Gi
    Frag Fu = stld(Dw, u, ccol, h, ro);
    f32x16 P = mm_ff(FGi, Fu);                 // Xc = Gi X Gi
    f32x16 L = logm_ps(Dw, P, ro, ccol, h, dm);
    float sq = 0.f;
#pragma unroll
    for (int i = 0; i < 16; ++i) sq += L[i] * L[i];
    vacc += sq;
    float* g = Lout + m * 1024;
#pragma unroll
    for (int i = 0; i < 16; ++i) {
      const int row = (i & 3) + 8 * (i >> 2) + 4 * h;
      g[row * 32 + ccol] = L[i];
    }
  }
  vacc = wsum(vacc);
  if (lane == 0) V2[w] = vacc;
  __syncthreads();
  if (tid == 0) ws[WS_VPART + n] = V2[0] + V2[1];   // plain store, no atomics
}

__global__ __launch_bounds__(64) void k6_p(const int* __restrict__ ds,
                                           float* __restrict__ ws,
                                           int N, int q, int D) {
  const int lane = threadIdx.x;
  float a0 = 0.f, a1 = 0.f, a2 = 0.f, a3 = 0.f;
  for (int n = lane; n < N; n += 64) {
    const int d = ds[n];
    const float v = ws[WS_VPART + n];
    a0 += (d == 0) ? v : 0.f;
    a1 += (d == 1) ? v : 0.f;
    a2 += (d == 2) ? v : 0.f;
    a3 += (d == 3) ? v : 0.f;
  }
  a0 = wsum(a0); a1 = wsum(a1); a2 = wsum(a2); a3 = wsum(a3);
  if (lane < D) {
    const float var0 = (lane == 0) ? a0 : (lane == 1) ? a1 : (lane == 2) ? a2 : a3;
    const float cntf = ws[WS_CNT + lane];
    const float var = var0 / ((float)q * cntf);
    ws[WS_P + lane] = sqrtf(1.f / (var + 1e-5f));
  }
}

__global__ __launch_bounds__(128) void k7_out(const int* __restrict__ ds,
                                              const float* __restrict__ ws,
                                              const float* __restrict__ R,
                                              float* __restrict__ io, int q) {
  __shared__ unsigned SH[2][SMATU];
  const int n = blockIdx.x, tid = threadIdx.x;
  const int w = tid >> 6, lane = tid & 63;
  const int ccol = lane & 31, h = lane >> 5;
  const int ro = ccol * SROW + h * 4;
  float dm[16];
#pragma unroll
  for (int i = 0; i < 16; ++i) {
    const int row = (i & 3) + 8 * (i >> 2) + 4 * h;
    dm[i] = (row == ccol) ? 1.f : 0.f;
  }
  const int d = ds[n];
  if (w == 0) x2l(R + d * 1024, SH[0], lane);
  else        x2l(ws + WS_BSQ + d * 1024, SH[1], lane);
  __syncthreads();
  const Frag FR  = ld_frag(SH[0], ro);   // A of R / B of R^T
  const Frag FBs = ld_frag(SH[1], ro);
  __syncthreads();
  const float ph = 0.5f * ws[WS_P + d];
  // Taylor coeffs of exp(ph*L), deg 10
  float coef[11];
  coef[0] = 1.f;
  coef[1] = ph;
  coef[2] = coef[1] * ph * 0.5f;
  coef[3] = coef[2] * ph * (1.f / 3.f);
  coef[4] = coef[3] * ph * 0.25f;
  coef[5] = coef[4] * ph * 0.2f;
  coef[6] = coef[5] * ph * (1.f / 6.f);
  coef[7] = coef[6] * ph * (1.f / 7.f);
  coef[8] = coef[7] * ph * 0.125f;
  coef[9] = coef[8] * ph * (1.f / 9.f);
  coef[10] = coef[9] * ph * 0.1f;
  unsigned* Dw = SH[w];
  const int half = q >> 1;
#pragma unroll 1
  for (int j = 0; j < half; ++j) {
    const size_t m = (size_t)n * q + (size_t)w * half + j;
    float* g = io + m * 1024;
    // load L in C-layout (coalesced 128B per i)
    f32x16 Lc;
#pragma unroll
    for (int i = 0; i < 16; ++i) {
      const int row = (i & 3) + 8 * (i >> 2) + 4 * h;
      Lc[i] = g[row * 32 + ccol];
    }
    Frag FL = stld(Dw, Lc, ccol, h, ro);
    f32x16 t = mm_ff(FL, FL);                  // wmat = L^2
    Frag Fw = stld(Dw, t, ccol, h, ro);
    // exp(ph L) deg-10 via pair-Horner in w: Pj = c_{2j} I + c_{2j+1} L
    f32x16 G;
#pragma unroll
    for (int i = 0; i < 16; ++i) G[i] = coef[10] * t[i] + coef[9] * Lc[i];
    addID(G, coef[8], dm);
    Frag FG = stld(Dw, G, ccol, h, ro);
#pragma unroll 1
    for (int kk = 7; kk >= 1; kk -= 2) {
      t = mm_ff(FG, Fw);
#pragma unroll
      for (int i = 0; i < 16; ++i) G[i] = t[i] + coef[kk] * Lc[i];
      addID(G, coef[kk - 1], dm);
      FG = stld(Dw, G, ccol, h, ro);
    }
    t = mm_ff(FG, FG);                         // Xp = H^2 = exp(p L)
    Frag FXp = stld(Dw, t, ccol, h, ro);
    t = mm_ff(FXp, FR);                        // Xp * R^T
    Frag Ft = stld(Dw, t, ccol, h, ro);
    t = mm_ff(FR, Ft);                         // Xr = R Xp R^T
    Frag FXr = stld(Dw, t, ccol, h, ro);
    t = mm_ff(FXr, FBs);                       // Xr * Bs
    Ft = stld(Dw, t, ccol, h, ro);
    t = mm_ff(FBs, Ft);                        // out = Bs Xr Bs
#pragma unroll
    for (int i = 0; i < 16; ++i) {
      const int row = (i & 3) + 8 * (i >> 2) + 4 * h;
      g[row * 32 + ccol] = t[i];
    }
  }
}

// ------------------------------- launcher ----------------------------------

extern "C" void kernel_launch(void* const* d_in, const int* in_sizes, int n_in,
                              void* d_out, int out_size, void* d_ws, size_t ws_size,
                              hipStream_t stream) {
  const float* X  = (const float*)d_in[0];
  const int*   ds = (const int*)d_in[1];
  const float* R  = (const float*)d_in[2];
  const float* B  = (const float*)d_in[3];
  float* out = (float*)d_out;
  float* ws  = (float*)d_ws;
  const int N = in_sizes[1];
  const int q = in_sizes[0] / (N * 1024);
  const int D = in_sizes[2] / 1024;
  (void)n_in; (void)out_size; (void)ws_size;

  // d_out doubles as an 8 MB reduction scratch until k5 overwrites it.
  float* scr = out;

  hipMemsetAsync(d_ws, 0, WS_ZERO * sizeof(float), stream);
  k1_xsum   <<<dim3((N + 3) / 4), dim3(256), 0, stream>>>(X, scr, N, q);
  kred      <<<dim3(8 * D * 4), dim3(256), 0, stream>>>(ds, scr, ws + WS_G0SUM, N, D);
  k2_g0funcs<<<dim3(D), dim3(128), 0, stream>>>(ws, ds, B, N, q);
  k3_gt     <<<dim3(N), dim3(128), 0, stream>>>(X, ds, ws, scr, q);
  kred      <<<dim3(8 * D * 4), dim3(256), 0, stream>>>(ds, scr, ws + WS_GTSUM, N, D);
  k4_mean   <<<dim3(D), dim3(64),  0, stream>>>(ws, q);
  k5_logxc  <<<dim3(N), dim3(128), 0, stream>>>(X, ds, ws, out, q);
  k6_p      <<<dim3(1), dim3(64),  0, stream>>>(ds, ws, N, q, D);
  k7_out    <<<dim3(N), dim3(128), 0, stream>>>(ds, ws, R, out, q);
}

// Round 3
// 778.784 us; speedup vs baseline: 1.4300x; 1.0776x over previous
//
#include <hip/hip_runtime.h>

// ---------------------------------------------------------------------------
// DomainGeneralisationBN (SPD batchnorm) — R6: LDS-free MFMA pipeline via
// permlane32_swap fragment assembly.
// rocprof R5: k3=238us, MfmaUtil 21%, VALUBusy 47%, 2.0e7 LDS-conflict cy ->
// still latency-bound on dependent st_split->lgkmcnt->ds_read round-trips.
// Fix: C-regs (lane=col ccol, rows split across half-waves) -> B-fragment
// (lane=col, k=rows h*8+j) differ only by a lane<->lane+32 exchange.
// v_permlane32_swap_b32 does that in-register: frag_from_c = bf16 hi/lo pack
// (+0x8000 trick, bit-identical to R5) + 8 permlane swaps.  All produced
// matrices are symmetric or B-only -> every stld replaced; global operands
// load as per-lane row-slices (frag_rowmajor).  k7 has ZERO LDS; k3/k5 keep
// only the 4KB merge buffers.  k7 coef[] dyn-index fixed (full unroll).
// Reduction scheme (R4) unchanged: k1_xsum+kred, k3 LDS-merge+kred, VPART.
// ---------------------------------------------------------------------------

#define LN  36
#define MSZ (32 * LN)

// workspace layout (float offsets)
#define WS_G0SUM 0
#define WS_GTSUM 4096
#define WS_VAR   8192
#define WS_CNT   8196
#define WS_P     8200
#define WS_G0SQ  8208
#define WS_G0ISQ 12304
#define WS_GISQ  16400
#define WS_BSQ   20496
#define WS_VPART 24592      // N floats of per-block variance partials
#define WS_ZERO  8208

// (P+I)^-1 NS init: X0 = AL*I + BE*M, Chebyshev on eigs(M) in [1.15, 8]
#define LOG_AL 0.6073551f
#define LOG_BE (-0.0663776f)

typedef __attribute__((ext_vector_type(8)))  short bf16x8;
typedef __attribute__((ext_vector_type(16))) float f32x16;

union FragU { uint4 u; bf16x8 v; };

struct Frag { bf16x8 h0, h1, l0, l1; };

__device__ __forceinline__ float wsum(float v) {
#pragma unroll
  for (int o = 32; o > 0; o >>= 1) v += __shfl_xor(v, o, 64);
  return v;
}

// ---------------- MFMA-path helpers ----------------

// C = A*B with split-bf16 3-product scheme, all operands in registers.
__device__ __forceinline__ f32x16 mm_ff(const Frag A, const Frag B) {
  f32x16 c;
#pragma unroll
  for (int i = 0; i < 16; ++i) c[i] = 0.f;
  c = __builtin_amdgcn_mfma_f32_32x32x16_bf16(A.h0, B.h0, c, 0, 0, 0);
  c = __builtin_amdgcn_mfma_f32_32x32x16_bf16(A.h0, B.l0, c, 0, 0, 0);
  c = __builtin_amdgcn_mfma_f32_32x32x16_bf16(A.l0, B.h0, c, 0, 0, 0);
  c = __builtin_amdgcn_mfma_f32_32x32x16_bf16(A.h1, B.h1, c, 0, 0, 0);
  c = __builtin_amdgcn_mfma_f32_32x32x16_bf16(A.h1, B.l1, c, 0, 0, 0);
  c = __builtin_amdgcn_mfma_f32_32x32x16_bf16(A.l1, B.h1, c, 0, 0, 0);
  return c;
}

// pack (x0,x1) -> hi word (bf16(x1)<<16 | bf16(x0), round-half-up) + lo word
__device__ __forceinline__ void packpair(float x0, float x1,
                                         unsigned& hw, unsigned& lw) {
  const unsigned a0 = __float_as_uint(x0) + 0x8000u;
  const unsigned a1 = __float_as_uint(x1) + 0x8000u;
  const float l0 = x0 - __uint_as_float(a0 & 0xFFFF0000u);
  const float l1 = x1 - __uint_as_float(a1 & 0xFFFF0000u);
  hw = __builtin_amdgcn_perm(a1, a0, 0x07060302u);
  lw = __builtin_amdgcn_perm(__float_as_uint(l1), __float_as_uint(l0), 0x07060302u);
}

__device__ __forceinline__ void plswap2(unsigned a, unsigned b,
                                        unsigned& r0, unsigned& r1) {
  auto p = __builtin_amdgcn_permlane32_swap(a, b, false, false);
  r0 = p[0]; r1 = p[1];
}

// C-regs (col=ccol, rows (i&3)+8*(i>>2)+4h) -> split-bf16 fragment of the
// SAME matrix: valid B-operand always; valid A-operand iff symmetric.
// Exchange between lane and lane+32 done by v_permlane32_swap_b32:
// swap(x,y) -> r0 = (h==0 ? own x : partner x), r1 = (h==0 ? partner x : own y)
// which is exactly the (own-half, partner-half) word pair each lane needs.
__device__ __forceinline__ Frag frag_from_c(const f32x16 c) {
  unsigned hw[8], lw[8];
#pragma unroll
  for (int g = 0; g < 4; ++g) {
    packpair(c[4*g+0], c[4*g+1], hw[2*g+0], lw[2*g+0]);
    packpair(c[4*g+2], c[4*g+3], hw[2*g+1], lw[2*g+1]);
  }
  unsigned w0, w1, w2, w3;
  FragU A, B, C, D;
  plswap2(hw[0], hw[2], w0, w2);
  plswap2(hw[1], hw[3], w1, w3);
  A.u = make_uint4(w0, w1, w2, w3);          // B.h0 : rows h*8..h*8+7
  plswap2(hw[4], hw[6], w0, w2);
  plswap2(hw[5], hw[7], w1, w3);
  B.u = make_uint4(w0, w1, w2, w3);          // B.h1 : rows 16+h*8..
  plswap2(lw[0], lw[2], w0, w2);
  plswap2(lw[1], lw[3], w1, w3);
  C.u = make_uint4(w0, w1, w2, w3);          // B.l0
  plswap2(lw[4], lw[6], w0, w2);
  plswap2(lw[5], lw[7], w1, w3);
  D.u = make_uint4(w0, w1, w2, w3);          // B.l1
  Frag f; f.h0 = A.v; f.h1 = B.v; f.l0 = C.v; f.l1 = D.v;
  return f;
}

// 32x32 f32 row-major global matrix M -> fragment = A-operand of M and
// B-operand of M^T (both A/B of M when symmetric).  No LDS, no exchange:
// lane (r=lane&31, h) loads M[r][h*8..h*8+7] and M[r][16+h*8..16+h*8+7].
__device__ __forceinline__ Frag frag_rowmajor(const float* __restrict__ g,
                                              int lane) {
  const int r = lane & 31, h = lane >> 5;
  const float* p = g + r * 32 + h * 8;
  const float4 v0 = *(const float4*)(p);
  const float4 v1 = *(const float4*)(p + 4);
  const float4 v2 = *(const float4*)(p + 16);
  const float4 v3 = *(const float4*)(p + 20);
  unsigned hw[8], lw[8];
  packpair(v0.x, v0.y, hw[0], lw[0]);
  packpair(v0.z, v0.w, hw[1], lw[1]);
  packpair(v1.x, v1.y, hw[2], lw[2]);
  packpair(v1.z, v1.w, hw[3], lw[3]);
  packpair(v2.x, v2.y, hw[4], lw[4]);
  packpair(v2.z, v2.w, hw[5], lw[5]);
  packpair(v3.x, v3.y, hw[6], lw[6]);
  packpair(v3.z, v3.w, hw[7], lw[7]);
  FragU A, B, C, D;
  A.u = make_uint4(hw[0], hw[1], hw[2], hw[3]);
  B.u = make_uint4(hw[4], hw[5], hw[6], hw[7]);
  C.u = make_uint4(lw[0], lw[1], lw[2], lw[3]);
  D.u = make_uint4(lw[4], lw[5], lw[6], lw[7]);
  Frag f; f.h0 = A.v; f.h1 = B.v; f.l0 = C.v; f.l1 = D.v;
  return f;
}

__device__ __forceinline__ void addID(f32x16& c, float v, const float* dm) {
#pragma unroll
  for (int i = 0; i < 16; ++i) c[i] = fmaf(v, dm[i], c[i]);
}

// L = log(P), P in C-regs (SPD, eigs ~[0.2,5.5]).  Fully in-register.
// NS inverse of M=P+I (Chebyshev init + 3 iters), Cayley S=I-2Q, Gregory
// deg-8 via pair-Horner in y^2, final L = 2g - 4*Q*g.
__device__ __forceinline__ f32x16 logm_reg(f32x16 P, const float* dm) {
  f32x16 M = P;
  addID(M, 1.f, dm);                         // M = P + I
  const Frag FM = frag_from_c(M);
  f32x16 t = mm_ff(FM, FM);                  // M^2
  f32x16 V;
#pragma unroll
  for (int i = 0; i < 16; ++i) V[i] = -(LOG_AL * M[i] + LOG_BE * t[i]);
  addID(V, 2.f, dm);                         // V = 2I - M*X0
  const Frag FV = frag_from_c(V);
  t = mm_ff(FM, FV);                         // M*V
  f32x16 X;
#pragma unroll
  for (int i = 0; i < 16; ++i) X[i] = LOG_AL * V[i] + LOG_BE * t[i];  // X0*V
  Frag FX = frag_from_c(X);
#pragma unroll 1
  for (int it = 0; it < 3; ++it) {           // X <- 2X - M X^2
    t = mm_ff(FX, FX);
    const Frag Ft = frag_from_c(t);
    t = mm_ff(FM, Ft);
#pragma unroll
    for (int i = 0; i < 16; ++i) X[i] = 2.f * X[i] - t[i];
    FX = frag_from_c(X);
  }
  // Q = X ~= M^-1.  S2 = I - 4Q + 4Q^2 (eigs of S^2 in [0, ~0.48])
  t = mm_ff(FX, FX);                         // Q^2
  f32x16 S2;
#pragma unroll
  for (int i = 0; i < 16; ++i) S2[i] = 4.f * (t[i] - X[i]);
  addID(S2, 1.f, dm);
  const Frag Fy = frag_from_c(S2);
  t = mm_ff(Fy, Fy);                         // w = y^2
  const Frag Fw = frag_from_c(t);
  // g(y) = sum_{j=0..8} y^j/(2j+1), pair-Horner in w; Pj = c2j I + c2j+1 y
  f32x16 G;
#pragma unroll
  for (int i = 0; i < 16; ++i) G[i] = (1.f/17.f) * t[i] + (1.f/15.f) * S2[i];
  addID(G, 1.f/13.f, dm);
  Frag FG = frag_from_c(G);
  t = mm_ff(FG, Fw);
#pragma unroll
  for (int i = 0; i < 16; ++i) G[i] = t[i] + (1.f/11.f) * S2[i];
  addID(G, 1.f/9.f, dm);
  FG = frag_from_c(G);
  t = mm_ff(FG, Fw);
#pragma unroll
  for (int i = 0; i < 16; ++i) G[i] = t[i] + (1.f/7.f) * S2[i];
  addID(G, 1.f/5.f, dm);
  FG = frag_from_c(G);
  t = mm_ff(FG, Fw);
#pragma unroll
  for (int i = 0; i < 16; ++i) G[i] = t[i] + (1.f/3.f) * S2[i];
  addID(G, 1.f, dm);
  FG = frag_from_c(G);
  // L = 2 S g = 2(I-2Q) g = 2G - 4 Q*g   (Q,G commute -> symmetric)
  t = mm_ff(FX, FG);
  f32x16 L;
#pragma unroll
  for (int i = 0; i < 16; ++i) L[i] = 2.f * G[i] - 4.f * t[i];
  return L;
}

// ---------------- fp32-VALU helpers (k2/k4 only, D=4 matrices) ----------------

__device__ __forceinline__ void zero16(float c[16]) {
#pragma unroll
  for (int i = 0; i < 16; ++i) c[i] = 0.f;
}
__device__ __forceinline__ void diag4(float c[16], float v, int dg) {
  if (dg) { c[0] += v; c[5] += v; c[10] += v; c[15] += v; }
}
__device__ __forceinline__ void mm_gen(const float* A, const float* B, float c[16],
                                       int bi4, int bj4) {
  zero16(c);
#pragma unroll 4
  for (int k = 0; k < 32; ++k) {
    float4 a = *(const float4*)(A + k * LN + bi4);
    float4 b = *(const float4*)(B + k * LN + bj4);
    c[0] = fmaf(a.x, b.x, c[0]);  c[1] = fmaf(a.x, b.y, c[1]);
    c[2] = fmaf(a.x, b.z, c[2]);  c[3] = fmaf(a.x, b.w, c[3]);
    c[4] = fmaf(a.y, b.x, c[4]);  c[5] = fmaf(a.y, b.y, c[5]);
    c[6] = fmaf(a.y, b.z, c[6]);  c[7] = fmaf(a.y, b.w, c[7]);
    c[8] = fmaf(a.z, b.x, c[8]);  c[9] = fmaf(a.z, b.y, c[9]);
    c[10]= fmaf(a.z, b.z, c[10]); c[11]= fmaf(a.z, b.w, c[11]);
    c[12]= fmaf(a.w, b.x, c[12]); c[13]= fmaf(a.w, b.y, c[13]);
    c[14]= fmaf(a.w, b.z, c[14]); c[15]= fmaf(a.w, b.w, c[15]);
  }
}
__device__ __forceinline__ void st_row(float* buf, const float c[16], int bi4, int bj4) {
#pragma unroll
  for (int di = 0; di < 4; ++di)
    *(float4*)(buf + (bi4 + di) * LN + bj4) =
        make_float4(c[di*4+0], c[di*4+1], c[di*4+2], c[di*4+3]);
}
__device__ __forceinline__ void st_colf(float* buf, const float c[16], int bi4, int bj4) {
#pragma unroll
  for (int dj = 0; dj < 4; ++dj)
    *(float4*)(buf + (bj4 + dj) * LN + bi4) =
        make_float4(c[0*4+dj], c[1*4+dj], c[2*4+dj], c[3*4+dj]);
}
__device__ __forceinline__ void ldg_mat(const float* __restrict__ g, float c[16],
                                        int bi4, int bj4) {
#pragma unroll
  for (int di = 0; di < 4; ++di) {
    float4 v = *(const float4*)(g + (bi4 + di) * 32 + bj4);
    c[di*4+0] = v.x; c[di*4+1] = v.y; c[di*4+2] = v.z; c[di*4+3] = v.w;
  }
}
__device__ __forceinline__ void stg_mat(float* __restrict__ g, const float c[16],
                                        int bi4, int bj4) {
#pragma unroll
  for (int di = 0; di < 4; ++di)
    *(float4*)(g + (bi4 + di) * 32 + bj4) =
        make_float4(c[di*4+0], c[di*4+1], c[di*4+2], c[di*4+3]);
}
__device__ __forceinline__ void wave_sqrtinv(const float A[16], float Ysq[16], float Zis[16],
                                             float* YB, float* ZB, float* TB,
                                             int bi4, int bj4) {
  const int dg = (bi4 == bj4);
  float ss = 0.f;
#pragma unroll
  for (int i = 0; i < 16; ++i) ss += A[i] * A[i];
  const float th = sqrtf(wsum(ss));
  const float inv = 1.f / th;
  float Y[16], Z[16];
#pragma unroll
  for (int i = 0; i < 16; ++i) Y[i] = A[i] * inv;
  zero16(Z); diag4(Z, 1.f, dg);
  st_row(YB, Y, bi4, bj4);
  st_row(ZB, Z, bi4, bj4);
#pragma unroll 1
  for (int it = 0; it < 13; ++it) {
    float W[16], T[16];
    mm_gen(ZB, YB, W, bi4, bj4);
#pragma unroll
    for (int i = 0; i < 16; ++i) T[i] = -0.5f * W[i];
    diag4(T, 1.5f, dg);
    st_row(TB, T, bi4, bj4);
    mm_gen(YB, TB, Y, bi4, bj4);
    mm_gen(TB, ZB, Z, bi4, bj4);
    st_row(YB, Y, bi4, bj4);
    st_row(ZB, Z, bi4, bj4);
  }
  const float sth = sqrtf(th), isth = 1.f / sth;
#pragma unroll
  for (int i = 0; i < 16; ++i) { Ysq[i] = Y[i] * sth; Zis[i] = Z[i] * isth; }
}

// ------------------------------- kernels -----------------------------------

// per-n sum over the q matrices, plain stores into scratch (d_out).
__global__ __launch_bounds__(256) void k1_xsum(const float* __restrict__ X,
                                               float* __restrict__ scr,
                                               int N, int q) {
  const int w = threadIdx.x >> 6, lane = threadIdx.x & 63;
  const int n = blockIdx.x * 4 + w;
  if (n >= N) return;
  float acc[16];
  zero16(acc);
  const float* base = X + (size_t)n * q * 1024 + lane * 16;
#pragma unroll 4
  for (int j = 0; j < q; ++j) {
    const float* g = base + (size_t)j * 1024;
#pragma unroll
    for (int u = 0; u < 4; ++u) {
      float4 v = *(const float4*)(g + u * 4);
      acc[u*4+0] += v.x; acc[u*4+1] += v.y; acc[u*4+2] += v.z; acc[u*4+3] += v.w;
    }
  }
  float* dst = scr + (size_t)n * 1024 + lane * 16;
#pragma unroll
  for (int u = 0; u < 4; ++u)
    *(float4*)(dst + u * 4) =
        make_float4(acc[u*4+0], acc[u*4+1], acc[u*4+2], acc[u*4+3]);
}

// gather-by-domain reduce: dst[d*1024+e] += sum_{n: ds[n]==d} src[n*1024+e].
__global__ __launch_bounds__(256) void kred(const int* __restrict__ ds,
                                            const float* __restrict__ src,
                                            float* __restrict__ dst,
                                            int N, int D) {
  const int obln = D * 4;
  const int chunk = blockIdx.x / obln;
  const int ob    = blockIdx.x % obln;
  const int out   = ob * 256 + threadIdx.x;
  const int d = out >> 10, e = out & 1023;
  const int cs = (N + 7) >> 3;
  const int n0 = chunk * cs;
  const int n1 = min(N, n0 + cs);
  float acc = 0.f;
#pragma unroll 16
  for (int n = n0; n < n1; ++n) {
    const float v = src[(size_t)n * 1024 + e];
    acc += (ds[n] == d) ? v : 0.f;
  }
  atomicAdd(dst + out, acc);
}

__global__ __launch_bounds__(128) void k2_g0funcs(float* __restrict__ ws,
                                                  const int* __restrict__ ds,
                                                  const float* __restrict__ B,
                                                  int N, int q) {
  __shared__ float D[2][3][MSZ];
  const int d = blockIdx.x, tid = threadIdx.x;
  const int w = tid >> 6, lane = tid & 63;
  const int bi4 = (lane >> 3) * 4, bj4 = (lane & 7) * 4;
  float A[16], Y[16], Z[16];
  if (w == 0) {
    int cnt = 0;
    for (int i = lane; i < N; i += 64) cnt += (ds[i] == d) ? 1 : 0;
    const float cntf = wsum((float)cnt);
    if (lane == 0) ws[WS_CNT + d] = cntf;
    ldg_mat(ws + WS_G0SUM + d * 1024, A, bi4, bj4);
    const float s = 1.f / ((float)q * cntf);
#pragma unroll
    for (int i = 0; i < 16; ++i) A[i] *= s;
    wave_sqrtinv(A, Y, Z, D[0][0], D[0][1], D[0][2], bi4, bj4);
    stg_mat(ws + WS_G0SQ  + d * 1024, Y, bi4, bj4);
    stg_mat(ws + WS_G0ISQ + d * 1024, Z, bi4, bj4);
  } else {
    ldg_mat(B + d * 1024, A, bi4, bj4);
    wave_sqrtinv(A, Y, Z, D[1][0], D[1][1], D[1][2], bi4, bj4);
    stg_mat(ws + WS_BSQ + d * 1024, Y, bi4, bj4);
  }
}

__global__ __launch_bounds__(128, 2) void k3_gt(const float* __restrict__ X,
                                                const int* __restrict__ ds,
                                                const float* __restrict__ ws,
                                                float* __restrict__ scr, int q) {
  __shared__ float RED[1024];
  const int n = blockIdx.x, tid = threadIdx.x;
  const int w = tid >> 6, lane = tid & 63;
  const int ccol = lane & 31, h = lane >> 5;
  float dm[16];
#pragma unroll
  for (int i = 0; i < 16; ++i) {
    const int row = (i & 3) + 8 * (i >> 2) + 4 * h;
    dm[i] = (row == ccol) ? 1.f : 0.f;
  }
  const int d = ds[n];
  const Frag FGi = frag_rowmajor(ws + WS_G0ISQ + d * 1024, lane);
  const Frag FGs = frag_rowmajor(ws + WS_G0SQ  + d * 1024, lane);
  f32x16 acc;
#pragma unroll
  for (int i = 0; i < 16; ++i) acc[i] = 0.f;
  const int half = q >> 1;
#pragma unroll 1
  for (int j = 0; j < half; ++j) {
    const size_t m = (size_t)n * q + (size_t)w * half + j;
    const Frag FX0 = frag_rowmajor(X + m * 1024, lane);   // symmetric
    f32x16 u = mm_ff(FX0, FGi);                // X * Gi
    Frag Fu = frag_from_c(u);                  // B-only use
    f32x16 P = mm_ff(FGi, Fu);                 // Gi X Gi
    f32x16 L = logm_reg(P, dm);
    const Frag FL = frag_from_c(L);            // symmetric
    u = mm_ff(FL, FGs);                        // L * Gs
    Fu = frag_from_c(u);
    u = mm_ff(FGs, Fu);                        // Gs L Gs
#pragma unroll
    for (int i = 0; i < 16; ++i) acc[i] += u[i];
  }
  // merge the two waves through LDS, plain-store per-n partial (no atomics)
  if (w == 0) {
#pragma unroll
    for (int i = 0; i < 16; ++i) {
      const int row = (i & 3) + 8 * (i >> 2) + 4 * h;
      RED[row * 32 + ccol] = acc[i];
    }
  }
  __syncthreads();
  if (w == 1) {
    float* g = scr + (size_t)n * 1024;
#pragma unroll
    for (int i = 0; i < 16; ++i) {
      const int row = (i & 3) + 8 * (i >> 2) + 4 * h;
      g[row * 32 + ccol] = acc[i] + RED[row * 32 + ccol];
    }
  }
}

__global__ __launch_bounds__(64) void k4_mean(float* __restrict__ ws, int q) {
  __shared__ float GB[MSZ], D1[MSZ], D2[MSZ], D3[MSZ];
  const int d = blockIdx.x, lane = threadIdx.x;
  const int bi4 = (lane >> 3) * 4, bj4 = (lane & 7) * 4;
  const int dg = (bi4 == bj4);
  const float cntf = ws[WS_CNT + d];
  float c[16], t[16];
  ldg_mat(ws + WS_G0ISQ + d * 1024, c, bi4, bj4); st_row(GB, c, bi4, bj4);
  ldg_mat(ws + WS_GTSUM + d * 1024, c, bi4, bj4);
  const float s = 1.f / ((float)q * cntf);
#pragma unroll
  for (int i = 0; i < 16; ++i) c[i] *= s;
  st_row(D1, c, bi4, bj4);
  mm_gen(GB, D1, t, bi4, bj4); st_colf(D2, t, bi4, bj4);
  mm_gen(D2, GB, t, bi4, bj4); st_row(D1, t, bi4, bj4);   // E = Gi GT Gi
  float H[16];
  zero16(H); diag4(H, 2.7557319e-7f, dg);                 // 1/10!
  st_row(D2, H, bi4, bj4);
  float ck = 2.7557319e-7f;
#pragma unroll 1
  for (int kk = 9; kk >= 0; --kk) {
    ck *= (float)(kk + 1);
    mm_gen(D1, D2, H, bi4, bj4);
    diag4(H, ck, dg);
    st_row(D2, H, bi4, bj4);
  }                                                       // exp(E)
  ldg_mat(ws + WS_G0SQ + d * 1024, c, bi4, bj4); st_row(GB, c, bi4, bj4);
  st_row(D1, H, bi4, bj4);
  mm_gen(GB, D1, t, bi4, bj4); st_colf(D2, t, bi4, bj4);
  mm_gen(D2, GB, t, bi4, bj4);                            // G
  float Y[16], Z[16];
  wave_sqrtinv(t, Y, Z, D1, D2, D3, bi4, bj4);
  stg_mat(ws + WS_GISQ + d * 1024, Z, bi4, bj4);
}

__global__ __launch_bounds__(128, 2) void k5_logxc(const float* __restrict__ X,
                                                   const int* __restrict__ ds,
                                                   float* __restrict__ ws,
                                                   float* __restrict__ Lout, int q) {
  __shared__ float V2[2];
  const int n = blockIdx.x, tid = threadIdx.x;
  const int w = tid >> 6, lane = tid & 63;
  const int ccol = lane & 31, h = lane >> 5;
  float dm[16];
#pragma unroll
  for (int i = 0; i < 16; ++i) {
    const int row = (i & 3) + 8 * (i >> 2) + 4 * h;
    dm[i] = (row == ccol) ? 1.f : 0.f;
  }
  const int d = ds[n];
  const Frag FGi = frag_rowmajor(ws + WS_GISQ + d * 1024, lane);
  float vacc = 0.f;
  const int half = q >> 1;
#pragma unroll 1
  for (int j = 0; j < half; ++j) {
    const size_t m = (size_t)n * q + (size_t)w * half + j;
    const Frag FX0 = frag_rowmajor(X + m * 1024, lane);
    f32x16 u = mm_ff(FX0, FGi);                // X * Gi
    const Frag Fu = frag_from_c(u);
    f32x16 P = mm_ff(FGi, Fu);                 // Xc = Gi X Gi
    f32x16 L = logm_reg(P, dm);
    float sq = 0.f;
#pragma unroll
    for (int i = 0; i < 16; ++i) sq += L[i] * L[i];
    vacc += sq;
    float* g = Lout + m * 1024;
#pragma unroll
    for (int i = 0; i < 16; ++i) {
      const int row = (i & 3) + 8 * (i >> 2) + 4 * h;
      g[row * 32 + ccol] = L[i];
    }
  }
  vacc = wsum(vacc);
  if (lane == 0) V2[w] = vacc;
  __syncthreads();
  if (tid == 0) ws[WS_VPART + n] = V2[0] + V2[1];   // plain store, no atomics
}

__global__ __launch_bounds__(64) void k6_p(const int* __restrict__ ds,
                                           float* __restrict__ ws,
                                           int N, int q, int D) {
  const int lane = threadIdx.x;
  float a0 = 0.f, a1 = 0.f, a2 = 0.f, a3 = 0.f;
  for (int n = lane; n < N; n += 64) {
    const int d = ds[n];
    const float v = ws[WS_VPART + n];
    a0 += (d == 0) ? v : 0.f;
    a1 += (d == 1) ? v : 0.f;
    a2 += (d == 2) ? v : 0.f;
    a3 += (d == 3) ? v : 0.f;
  }
  a0 = wsum(a0); a1 = wsum(a1); a2 = wsum(a2); a3 = wsum(a3);
  if (lane < D) {
    const float var0 = (lane == 0) ? a0 : (lane == 1) ? a1 : (lane == 2) ? a2 : a3;
    const float cntf = ws[WS_CNT + lane];
    const float var = var0 / ((float)q * cntf);
    ws[WS_P + lane] = sqrtf(1.f / (var + 1e-5f));
  }
}

__global__ __launch_bounds__(128, 2) void k7_out(const int* __restrict__ ds,
                                                 const float* __restrict__ ws,
                                                 const float* __restrict__ R,
                                                 float* __restrict__ io, int q) {
  const int n = blockIdx.x, tid = threadIdx.x;
  const int w = tid >> 6, lane = tid & 63;
  const int ccol = lane & 31, h = lane >> 5;
  float dm[16];
#pragma unroll
  for (int i = 0; i < 16; ++i) {
    const int row = (i & 3) + 8 * (i >> 2) + 4 * h;
    dm[i] = (row == ccol) ? 1.f : 0.f;
  }
  const int d = ds[n];
  const Frag FR  = frag_rowmajor(R + d * 1024, lane);        // A of R / B of R^T
  const Frag FBs = frag_rowmajor(ws + WS_BSQ + d * 1024, lane);
  const float ph = 0.5f * ws[WS_P + d];
  // Taylor coeffs of exp(ph*L), deg 10
  float coef[11];
  coef[0] = 1.f;
  coef[1] = ph;
  coef[2] = coef[1] * ph * 0.5f;
  coef[3] = coef[2] * ph * (1.f / 3.f);
  coef[4] = coef[3] * ph * 0.25f;
  coef[5] = coef[4] * ph * 0.2f;
  coef[6] = coef[5] * ph * (1.f / 6.f);
  coef[7] = coef[6] * ph * (1.f / 7.f);
  coef[8] = coef[7] * ph * 0.125f;
  coef[9] = coef[8] * ph * (1.f / 9.f);
  coef[10] = coef[9] * ph * 0.1f;
  const int half = q >> 1;
#pragma unroll 1
  for (int j = 0; j < half; ++j) {
    const size_t m = (size_t)n * q + (size_t)w * half + j;
    float* g = io + m * 1024;
    // load L in C-layout (coalesced 128B per i)
    f32x16 Lc;
#pragma unroll
    for (int i = 0; i < 16; ++i) {
      const int row = (i & 3) + 8 * (i >> 2) + 4 * h;
      Lc[i] = g[row * 32 + ccol];
    }
    const Frag FL = frag_from_c(Lc);           // symmetric
    f32x16 t = mm_ff(FL, FL);                  // wmat = L^2
    const Frag Fw = frag_from_c(t);
    // exp(ph L) deg-10 via pair-Horner in w: Pj = c_{2j} I + c_{2j+1} L
    f32x16 G;
#pragma unroll
    for (int i = 0; i < 16; ++i) G[i] = coef[10] * t[i] + coef[9] * Lc[i];
    addID(G, coef[8], dm);
    Frag FG = frag_from_c(G);
#pragma unroll
    for (int kk = 7; kk >= 1; kk -= 2) {       // full unroll: coef idx constant
      t = mm_ff(FG, Fw);
#pragma unroll
      for (int i = 0; i < 16; ++i) G[i] = t[i] + coef[kk] * Lc[i];
      addID(G, coef[kk - 1], dm);
      FG = frag_from_c(G);
    }
    t = mm_ff(FG, FG);                         // Xp = H^2 = exp(p L)
    const Frag FXp = frag_from_c(t);           // symmetric
    t = mm_ff(FXp, FR);                        // Xp * R^T
    Frag Ft = frag_from_c(t);
    t = mm_ff(FR, Ft);                         // Xr = R Xp R^T
    const Frag FXr = frag_from_c(t);           // symmetric
    t = mm_ff(FXr, FBs);                       // Xr * Bs
    Ft = frag_from_c(t);
    t = mm_ff(FBs, Ft);                        // out = Bs Xr Bs
#pragma unroll
    for (int i = 0; i < 16; ++i) {
      const int row = (i & 3) + 8 * (i >> 2) + 4 * h;
      g[row * 32 + ccol] = t[i];
    }
  }
}

// ------------------------------- launcher ----------------------------------

extern "C" void kernel_launch(void* const* d_in, const int* in_sizes, int n_in,
                              void* d_out, int out_size, void* d_ws, size_t ws_size,
                              hipStream_t stream) {
  const float* X  = (const float*)d_in[0];
  const int*   ds = (const int*)d_in[1];
  const float* R  = (const float*)d_in[2];
  const float* B  = (const float*)d_in[3];
  float* out = (float*)d_out;
  float* ws  = (float*)d_ws;
  const int N = in_sizes[1];
  const int q = in_sizes[0] / (N * 1024);
  const int D = in_sizes[2] / 1024;
  (void)n_in; (void)out_size; (void)ws_size;

  // d_out doubles as an 8 MB reduction scratch until k5 overwrites it.
  float* scr = out;

  hipMemsetAsync(d_ws, 0, WS_ZERO * sizeof(float), stream);
  k1_xsum   <<<dim3((N + 3) / 4), dim3(256), 0, stream>>>(X, scr, N, q);
  kred      <<<dim3(8 * D * 4), dim3(256), 0, stream>>>(ds, scr, ws + WS_G0SUM, N, D);
  k2_g0funcs<<<dim3(D), dim3(128), 0, stream>>>(ws, ds, B, N, q);
  k3_gt     <<<dim3(N), dim3(128), 0, stream>>>(X, ds, ws, scr, q);
  kred      <<<dim3(8 * D * 4), dim3(256), 0, stream>>>(ds, scr, ws + WS_GTSUM, N, D);
  k4_mean   <<<dim3(D), dim3(64),  0, stream>>>(ws, q);
  k5_logxc  <<<dim3(N), dim3(128), 0, stream>>>(X, ds, ws, out, q);
  k6_p      <<<dim3(1), dim3(64),  0, stream>>>(ds, ws, N, q, D);
  k7_out    <<<dim3(N), dim3(128), 0, stream>>>(ds, ws, R, out, q);
}

// Round 4
// 717.174 us; speedup vs baseline: 1.5528x; 1.0859x over previous
//
#include <hip/hip_runtime.h>

// ---------------------------------------------------------------------------
// DomainGeneralisationBN (SPD batchnorm) — R7: dual-matrix ILP + cvt_pk pack
// + hoisted congruence.
// rocprof R6: k3=185us, MfmaUtil 27%, VALUBusy 63%, occupancy 17%, conflicts 0
// -> bound by frag-pack VALU + exposed dependent-chain latency (1 serial
// chain/wave).  Changes (math-identical):
//  * each wave processes TWO matrices (j, j+1) as independent a/b chains —
//    fills VALU+MFMA dependency gaps in-wave;
//  * packpair via v_cvt_pk_bf16_f32 (hi=RTNE, lo=exact residual RTNE):
//    frag_from_c 72->56 VALU, frag_rowmajor 64->48;
//  * k3: sum_j Gs L_j Gs = Gs (sum L_j) Gs — trailing congruence hoisted out
//    of the j-loop, applied once after the cross-wave merge.
// Reduction scheme (R4) unchanged: k1_xsum+kred, k3 LDS-merge+kred, VPART.
// ---------------------------------------------------------------------------

#define LN  36
#define MSZ (32 * LN)

// workspace layout (float offsets)
#define WS_G0SUM 0
#define WS_GTSUM 4096
#define WS_VAR   8192
#define WS_CNT   8196
#define WS_P     8200
#define WS_G0SQ  8208
#define WS_G0ISQ 12304
#define WS_GISQ  16400
#define WS_BSQ   20496
#define WS_VPART 24592      // N floats of per-block variance partials
#define WS_ZERO  8208

// (P+I)^-1 NS init: X0 = AL*I + BE*M, Chebyshev on eigs(M) in [1.15, 8]
#define LOG_AL 0.6073551f
#define LOG_BE (-0.0663776f)

typedef __attribute__((ext_vector_type(8)))  short bf16x8;
typedef __attribute__((ext_vector_type(16))) float f32x16;

union FragU { uint4 u; bf16x8 v; };

struct Frag { bf16x8 h0, h1, l0, l1; };

__device__ __forceinline__ float wsum(float v) {
#pragma unroll
  for (int o = 32; o > 0; o >>= 1) v += __shfl_xor(v, o, 64);
  return v;
}

// ---------------- MFMA-path helpers ----------------

// C = A*B with split-bf16 3-product scheme, all operands in registers.
__device__ __forceinline__ f32x16 mm_ff(const Frag A, const Frag B) {
  f32x16 c;
#pragma unroll
  for (int i = 0; i < 16; ++i) c[i] = 0.f;
  c = __builtin_amdgcn_mfma_f32_32x32x16_bf16(A.h0, B.h0, c, 0, 0, 0);
  c = __builtin_amdgcn_mfma_f32_32x32x16_bf16(A.h0, B.l0, c, 0, 0, 0);
  c = __builtin_amdgcn_mfma_f32_32x32x16_bf16(A.l0, B.h0, c, 0, 0, 0);
  c = __builtin_amdgcn_mfma_f32_32x32x16_bf16(A.h1, B.h1, c, 0, 0, 0);
  c = __builtin_amdgcn_mfma_f32_32x32x16_bf16(A.h1, B.l1, c, 0, 0, 0);
  c = __builtin_amdgcn_mfma_f32_32x32x16_bf16(A.l1, B.h1, c, 0, 0, 0);
  return c;
}

// pack (x0,x1) -> hi word [bf16(x1)|bf16(x0)] (RTNE) + lo residual word.
// lo = x - fl_bf16(x) is exactly representable in fp32 -> same split quality
// as the +0x8000 integer trick, at 6 VALU/pair instead of 8.
__device__ __forceinline__ void packpair(float x0, float x1,
                                         unsigned& hw, unsigned& lw) {
  unsigned h;
  asm("v_cvt_pk_bf16_f32 %0, %1, %2" : "=v"(h) : "v"(x0), "v"(x1));
  const float h0 = __uint_as_float(h << 16);
  const float h1 = __uint_as_float(h & 0xFFFF0000u);
  const float l0 = x0 - h0;
  const float l1 = x1 - h1;
  asm("v_cvt_pk_bf16_f32 %0, %1, %2" : "=v"(lw) : "v"(l0), "v"(l1));
  hw = h;
}

__device__ __forceinline__ void plswap2(unsigned a, unsigned b,
                                        unsigned& r0, unsigned& r1) {
  auto p = __builtin_amdgcn_permlane32_swap(a, b, false, false);
  r0 = p[0]; r1 = p[1];
}

// C-regs (col=ccol, rows (i&3)+8*(i>>2)+4h) -> split-bf16 fragment of the
// SAME matrix: valid B-operand always; valid A-operand iff symmetric.
__device__ __forceinline__ Frag frag_from_c(const f32x16 c) {
  unsigned hw[8], lw[8];
#pragma unroll
  for (int g = 0; g < 4; ++g) {
    packpair(c[4*g+0], c[4*g+1], hw[2*g+0], lw[2*g+0]);
    packpair(c[4*g+2], c[4*g+3], hw[2*g+1], lw[2*g+1]);
  }
  unsigned w0, w1, w2, w3;
  FragU A, B, C, D;
  plswap2(hw[0], hw[2], w0, w2);
  plswap2(hw[1], hw[3], w1, w3);
  A.u = make_uint4(w0, w1, w2, w3);          // h0 : rows h*8..h*8+7
  plswap2(hw[4], hw[6], w0, w2);
  plswap2(hw[5], hw[7], w1, w3);
  B.u = make_uint4(w0, w1, w2, w3);          // h1 : rows 16+h*8..
  plswap2(lw[0], lw[2], w0, w2);
  plswap2(lw[1], lw[3], w1, w3);
  C.u = make_uint4(w0, w1, w2, w3);          // l0
  plswap2(lw[4], lw[6], w0, w2);
  plswap2(lw[5], lw[7], w1, w3);
  D.u = make_uint4(w0, w1, w2, w3);          // l1
  Frag f; f.h0 = A.v; f.h1 = B.v; f.l0 = C.v; f.l1 = D.v;
  return f;
}

// 32x32 f32 row-major global matrix M -> fragment = A-operand of M and
// B-operand of M^T (both A/B of M when symmetric).
__device__ __forceinline__ Frag frag_rowmajor(const float* __restrict__ g,
                                              int lane) {
  const int r = lane & 31, h = lane >> 5;
  const float* p = g + r * 32 + h * 8;
  const float4 v0 = *(const float4*)(p);
  const float4 v1 = *(const float4*)(p + 4);
  const float4 v2 = *(const float4*)(p + 16);
  const float4 v3 = *(const float4*)(p + 20);
  unsigned hw[8], lw[8];
  packpair(v0.x, v0.y, hw[0], lw[0]);
  packpair(v0.z, v0.w, hw[1], lw[1]);
  packpair(v1.x, v1.y, hw[2], lw[2]);
  packpair(v1.z, v1.w, hw[3], lw[3]);
  packpair(v2.x, v2.y, hw[4], lw[4]);
  packpair(v2.z, v2.w, hw[5], lw[5]);
  packpair(v3.x, v3.y, hw[6], lw[6]);
  packpair(v3.z, v3.w, hw[7], lw[7]);
  FragU A, B, C, D;
  A.u = make_uint4(hw[0], hw[1], hw[2], hw[3]);
  B.u = make_uint4(hw[4], hw[5], hw[6], hw[7]);
  C.u = make_uint4(lw[0], lw[1], lw[2], lw[3]);
  D.u = make_uint4(lw[4], lw[5], lw[6], lw[7]);
  Frag f; f.h0 = A.v; f.h1 = B.v; f.l0 = C.v; f.l1 = D.v;
  return f;
}

__device__ __forceinline__ void addID(f32x16& c, float v, const float* dm) {
#pragma unroll
  for (int i = 0; i < 16; ++i) c[i] = fmaf(v, dm[i], c[i]);
}

// L = log(P) for TWO independent matrices (a/b chains interleaved for ILP).
// NS inverse of M=P+I (Chebyshev init + 3 iters), Cayley S=I-2Q, Gregory
// deg-8 via pair-Horner in y^2, final L = 2g - 4*Q*g.  Fully in-register.
__device__ __forceinline__ void logm2(f32x16 Pa, f32x16 Pb,
                                      f32x16& La, f32x16& Lb,
                                      const float* dm) {
  addID(Pa, 1.f, dm);  addID(Pb, 1.f, dm);         // M = P + I
  const Frag FMa = frag_from_c(Pa);
  const Frag FMb = frag_from_c(Pb);
  f32x16 ta = mm_ff(FMa, FMa);                     // M^2
  f32x16 tb = mm_ff(FMb, FMb);
  f32x16 Va, Vb;
#pragma unroll
  for (int i = 0; i < 16; ++i) {
    Va[i] = -(LOG_AL * Pa[i] + LOG_BE * ta[i]);
    Vb[i] = -(LOG_AL * Pb[i] + LOG_BE * tb[i]);
  }
  addID(Va, 2.f, dm);  addID(Vb, 2.f, dm);         // V = 2I - M*X0
  const Frag FVa = frag_from_c(Va);
  const Frag FVb = frag_from_c(Vb);
  ta = mm_ff(FMa, FVa);                            // M*V
  tb = mm_ff(FMb, FVb);
  f32x16 Xa, Xb;
#pragma unroll
  for (int i = 0; i < 16; ++i) {
    Xa[i] = LOG_AL * Va[i] + LOG_BE * ta[i];       // X1 = X0*V
    Xb[i] = LOG_AL * Vb[i] + LOG_BE * tb[i];
  }
  Frag FXa = frag_from_c(Xa);
  Frag FXb = frag_from_c(Xb);
#pragma unroll 1
  for (int it = 0; it < 3; ++it) {                 // X <- 2X - M X^2
    ta = mm_ff(FXa, FXa);
    tb = mm_ff(FXb, FXb);
    const Frag Fta = frag_from_c(ta);
    const Frag Ftb = frag_from_c(tb);
    ta = mm_ff(FMa, Fta);
    tb = mm_ff(FMb, Ftb);
#pragma unroll
    for (int i = 0; i < 16; ++i) {
      Xa[i] = 2.f * Xa[i] - ta[i];
      Xb[i] = 2.f * Xb[i] - tb[i];
    }
    FXa = frag_from_c(Xa);
    FXb = frag_from_c(Xb);
  }
  // Q = X ~= M^-1.  S2 = I - 4Q + 4Q^2 (eigs of S^2 in [0, ~0.48])
  ta = mm_ff(FXa, FXa);
  tb = mm_ff(FXb, FXb);
  f32x16 S2a, S2b;
#pragma unroll
  for (int i = 0; i < 16; ++i) {
    S2a[i] = 4.f * (ta[i] - Xa[i]);
    S2b[i] = 4.f * (tb[i] - Xb[i]);
  }
  addID(S2a, 1.f, dm);  addID(S2b, 1.f, dm);
  const Frag Fya = frag_from_c(S2a);
  const Frag Fyb = frag_from_c(S2b);
  ta = mm_ff(Fya, Fya);                            // w = y^2
  tb = mm_ff(Fyb, Fyb);
  const Frag Fwa = frag_from_c(ta);
  const Frag Fwb = frag_from_c(tb);
  // g(y) = sum_{j=0..8} y^j/(2j+1), pair-Horner in w; Pj = c2j I + c2j+1 y
  f32x16 Ga, Gb;
#pragma unroll
  for (int i = 0; i < 16; ++i) {
    Ga[i] = (1.f/17.f) * ta[i] + (1.f/15.f) * S2a[i];
    Gb[i] = (1.f/17.f) * tb[i] + (1.f/15.f) * S2b[i];
  }
  addID(Ga, 1.f/13.f, dm);  addID(Gb, 1.f/13.f, dm);
  Frag FGa = frag_from_c(Ga);
  Frag FGb = frag_from_c(Gb);
  ta = mm_ff(FGa, Fwa);
  tb = mm_ff(FGb, Fwb);
#pragma unroll
  for (int i = 0; i < 16; ++i) {
    Ga[i] = ta[i] + (1.f/11.f) * S2a[i];
    Gb[i] = tb[i] + (1.f/11.f) * S2b[i];
  }
  addID(Ga, 1.f/9.f, dm);  addID(Gb, 1.f/9.f, dm);
  FGa = frag_from_c(Ga);
  FGb = frag_from_c(Gb);
  ta = mm_ff(FGa, Fwa);
  tb = mm_ff(FGb, Fwb);
#pragma unroll
  for (int i = 0; i < 16; ++i) {
    Ga[i] = ta[i] + (1.f/7.f) * S2a[i];
    Gb[i] = tb[i] + (1.f/7.f) * S2b[i];
  }
  addID(Ga, 1.f/5.f, dm);  addID(Gb, 1.f/5.f, dm);
  FGa = frag_from_c(Ga);
  FGb = frag_from_c(Gb);
  ta = mm_ff(FGa, Fwa);
  tb = mm_ff(FGb, Fwb);
#pragma unroll
  for (int i = 0; i < 16; ++i) {
    Ga[i] = ta[i] + (1.f/3.f) * S2a[i];
    Gb[i] = tb[i] + (1.f/3.f) * S2b[i];
  }
  addID(Ga, 1.f, dm);  addID(Gb, 1.f, dm);
  FGa = frag_from_c(Ga);
  FGb = frag_from_c(Gb);
  // L = 2 S g = 2(I-2Q) g = 2G - 4 Q*g   (Q,G commute -> symmetric)
  ta = mm_ff(FXa, FGa);
  tb = mm_ff(FXb, FGb);
#pragma unroll
  for (int i = 0; i < 16; ++i) {
    La[i] = 2.f * Ga[i] - 4.f * ta[i];
    Lb[i] = 2.f * Gb[i] - 4.f * tb[i];
  }
}

// ---------------- fp32-VALU helpers (k2/k4 only, D=4 matrices) ----------------

__device__ __forceinline__ void zero16(float c[16]) {
#pragma unroll
  for (int i = 0; i < 16; ++i) c[i] = 0.f;
}
__device__ __forceinline__ void diag4(float c[16], float v, int dg) {
  if (dg) { c[0] += v; c[5] += v; c[10] += v; c[15] += v; }
}
__device__ __forceinline__ void mm_gen(const float* A, const float* B, float c[16],
                                       int bi4, int bj4) {
  zero16(c);
#pragma unroll 4
  for (int k = 0; k < 32; ++k) {
    float4 a = *(const float4*)(A + k * LN + bi4);
    float4 b = *(const float4*)(B + k * LN + bj4);
    c[0] = fmaf(a.x, b.x, c[0]);  c[1] = fmaf(a.x, b.y, c[1]);
    c[2] = fmaf(a.x, b.z, c[2]);  c[3] = fmaf(a.x, b.w, c[3]);
    c[4] = fmaf(a.y, b.x, c[4]);  c[5] = fmaf(a.y, b.y, c[5]);
    c[6] = fmaf(a.y, b.z, c[6]);  c[7] = fmaf(a.y, b.w, c[7]);
    c[8] = fmaf(a.z, b.x, c[8]);  c[9] = fmaf(a.z, b.y, c[9]);
    c[10]= fmaf(a.z, b.z, c[10]); c[11]= fmaf(a.z, b.w, c[11]);
    c[12]= fmaf(a.w, b.x, c[12]); c[13]= fmaf(a.w, b.y, c[13]);
    c[14]= fmaf(a.w, b.z, c[14]); c[15]= fmaf(a.w, b.w, c[15]);
  }
}
__device__ __forceinline__ void st_row(float* buf, const float c[16], int bi4, int bj4) {
#pragma unroll
  for (int di = 0; di < 4; ++di)
    *(float4*)(buf + (bi4 + di) * LN + bj4) =
        make_float4(c[di*4+0], c[di*4+1], c[di*4+2], c[di*4+3]);
}
__device__ __forceinline__ void st_colf(float* buf, const float c[16], int bi4, int bj4) {
#pragma unroll
  for (int dj = 0; dj < 4; ++dj)
    *(float4*)(buf + (bj4 + dj) * LN + bi4) =
        make_float4(c[0*4+dj], c[1*4+dj], c[2*4+dj], c[3*4+dj]);
}
__device__ __forceinline__ void ldg_mat(const float* __restrict__ g, float c[16],
                                        int bi4, int bj4) {
#pragma unroll
  for (int di = 0; di < 4; ++di) {
    float4 v = *(const float4*)(g + (bi4 + di) * 32 + bj4);
    c[di*4+0] = v.x; c[di*4+1] = v.y; c[di*4+2] = v.z; c[di*4+3] = v.w;
  }
}
__device__ __forceinline__ void stg_mat(float* __restrict__ g, const float c[16],
                                        int bi4, int bj4) {
#pragma unroll
  for (int di = 0; di < 4; ++di)
    *(float4*)(g + (bi4 + di) * 32 + bj4) =
        make_float4(c[di*4+0], c[di*4+1], c[di*4+2], c[di*4+3]);
}
__device__ __forceinline__ void wave_sqrtinv(const float A[16], float Ysq[16], float Zis[16],
                                             float* YB, float* ZB, float* TB,
                                             int bi4, int bj4) {
  const int dg = (bi4 == bj4);
  float ss = 0.f;
#pragma unroll
  for (int i = 0; i < 16; ++i) ss += A[i] * A[i];
  const float th = sqrtf(wsum(ss));
  const float inv = 1.f / th;
  float Y[16], Z[16];
#pragma unroll
  for (int i = 0; i < 16; ++i) Y[i] = A[i] * inv;
  zero16(Z); diag4(Z, 1.f, dg);
  st_row(YB, Y, bi4, bj4);
  st_row(ZB, Z, bi4, bj4);
#pragma unroll 1
  for (int it = 0; it < 13; ++it) {
    float W[16], T[16];
    mm_gen(ZB, YB, W, bi4, bj4);
#pragma unroll
    for (int i = 0; i < 16; ++i) T[i] = -0.5f * W[i];
    diag4(T, 1.5f, dg);
    st_row(TB, T, bi4, bj4);
    mm_gen(YB, TB, Y, bi4, bj4);
    mm_gen(TB, ZB, Z, bi4, bj4);
    st_row(YB, Y, bi4, bj4);
    st_row(ZB, Z, bi4, bj4);
  }
  const float sth = sqrtf(th), isth = 1.f / sth;
#pragma unroll
  for (int i = 0; i < 16; ++i) { Ysq[i] = Y[i] * sth; Zis[i] = Z[i] * isth; }
}

// ------------------------------- kernels -----------------------------------

// per-n sum over the q matrices, plain stores into scratch (d_out).
__global__ __launch_bounds__(256) void k1_xsum(const float* __restrict__ X,
                                               float* __restrict__ scr,
                                               int N, int q) {
  const int w = threadIdx.x >> 6, lane = threadIdx.x & 63;
  const int n = blockIdx.x * 4 + w;
  if (n >= N) return;
  float acc[16];
  zero16(acc);
  const float* base = X + (size_t)n * q * 1024 + lane * 16;
#pragma unroll 4
  for (int j = 0; j < q; ++j) {
    const float* g = base + (size_t)j * 1024;
#pragma unroll
    for (int u = 0; u < 4; ++u) {
      float4 v = *(const float4*)(g + u * 4);
      acc[u*4+0] += v.x; acc[u*4+1] += v.y; acc[u*4+2] += v.z; acc[u*4+3] += v.w;
    }
  }
  float* dst = scr + (size_t)n * 1024 + lane * 16;
#pragma unroll
  for (int u = 0; u < 4; ++u)
    *(float4*)(dst + u * 4) =
        make_float4(acc[u*4+0], acc[u*4+1], acc[u*4+2], acc[u*4+3]);
}

// gather-by-domain reduce: dst[d*1024+e] += sum_{n: ds[n]==d} src[n*1024+e].
__global__ __launch_bounds__(256) void kred(const int* __restrict__ ds,
                                            const float* __restrict__ src,
                                            float* __restrict__ dst,
                                            int N, int D) {
  const int obln = D * 4;
  const int chunk = blockIdx.x / obln;
  const int ob    = blockIdx.x % obln;
  const int out   = ob * 256 + threadIdx.x;
  const int d = out >> 10, e = out & 1023;
  const int cs = (N + 7) >> 3;
  const int n0 = chunk * cs;
  const int n1 = min(N, n0 + cs);
  float acc = 0.f;
#pragma unroll 16
  for (int n = n0; n < n1; ++n) {
    const float v = src[(size_t)n * 1024 + e];
    acc += (ds[n] == d) ? v : 0.f;
  }
  atomicAdd(dst + out, acc);
}

__global__ __launch_bounds__(128) void k2_g0funcs(float* __restrict__ ws,
                                                  const int* __restrict__ ds,
                                                  const float* __restrict__ B,
                                                  int N, int q) {
  __shared__ float D[2][3][MSZ];
  const int d = blockIdx.x, tid = threadIdx.x;
  const int w = tid >> 6, lane = tid & 63;
  const int bi4 = (lane >> 3) * 4, bj4 = (lane & 7) * 4;
  float A[16], Y[16], Z[16];
  if (w == 0) {
    int cnt = 0;
    for (int i = lane; i < N; i += 64) cnt += (ds[i] == d) ? 1 : 0;
    const float cntf = wsum((float)cnt);
    if (lane == 0) ws[WS_CNT + d] = cntf;
    ldg_mat(ws + WS_G0SUM + d * 1024, A, bi4, bj4);
    const float s = 1.f / ((float)q * cntf);
#pragma unroll
    for (int i = 0; i < 16; ++i) A[i] *= s;
    wave_sqrtinv(A, Y, Z, D[0][0], D[0][1], D[0][2], bi4, bj4);
    stg_mat(ws + WS_G0SQ  + d * 1024, Y, bi4, bj4);
    stg_mat(ws + WS_G0ISQ + d * 1024, Z, bi4, bj4);
  } else {
    ldg_mat(B + d * 1024, A, bi4, bj4);
    wave_sqrtinv(A, Y, Z, D[1][0], D[1][1], D[1][2], bi4, bj4);
    stg_mat(ws + WS_BSQ + d * 1024, Y, bi4, bj4);
  }
}

__global__ __launch_bounds__(128, 2) void k3_gt(const float* __restrict__ X,
                                                const int* __restrict__ ds,
                                                const float* __restrict__ ws,
                                                float* __restrict__ scr, int q) {
  __shared__ float RED[1024];
  const int n = blockIdx.x, tid = threadIdx.x;
  const int w = tid >> 6, lane = tid & 63;
  const int ccol = lane & 31, h = lane >> 5;
  float dm[16];
#pragma unroll
  for (int i = 0; i < 16; ++i) {
    const int row = (i & 3) + 8 * (i >> 2) + 4 * h;
    dm[i] = (row == ccol) ? 1.f : 0.f;
  }
  const int d = ds[n];
  const Frag FGi = frag_rowmajor(ws + WS_G0ISQ + d * 1024, lane);
  f32x16 acc;
#pragma unroll
  for (int i = 0; i < 16; ++i) acc[i] = 0.f;
  const int half = q >> 1;
#pragma unroll 1
  for (int j = 0; j < half; j += 2) {
    const bool dual = (j + 1 < half);
    const size_t ma = (size_t)n * q + (size_t)w * half + j;
    const size_t mb = dual ? ma + 1 : ma;
    const Frag FXa = frag_rowmajor(X + ma * 1024, lane);   // symmetric
    const Frag FXb = frag_rowmajor(X + mb * 1024, lane);
    f32x16 ua = mm_ff(FXa, FGi);               // X * Gi
    f32x16 ub = mm_ff(FXb, FGi);
    const Frag Fua = frag_from_c(ua);          // B-only use
    const Frag Fub = frag_from_c(ub);
    f32x16 Pa = mm_ff(FGi, Fua);               // Gi X Gi
    f32x16 Pb = mm_ff(FGi, Fub);
    f32x16 La, Lb;
    logm2(Pa, Pb, La, Lb, dm);
#pragma unroll
    for (int i = 0; i < 16; ++i) acc[i] += La[i];
    if (dual) {
#pragma unroll
      for (int i = 0; i < 16; ++i) acc[i] += Lb[i];
    }
  }
  // merge the two waves through LDS, then ONE hoisted congruence:
  // sum_j Gs L_j Gs = Gs (sum_j L_j) Gs   (linear)
  if (w == 0) {
#pragma unroll
    for (int i = 0; i < 16; ++i) {
      const int row = (i & 3) + 8 * (i >> 2) + 4 * h;
      RED[row * 32 + ccol] = acc[i];
    }
  }
  __syncthreads();
  if (w == 1) {
#pragma unroll
    for (int i = 0; i < 16; ++i) {
      const int row = (i & 3) + 8 * (i >> 2) + 4 * h;
      acc[i] += RED[row * 32 + ccol];
    }
    const Frag FGs = frag_rowmajor(ws + WS_G0SQ + d * 1024, lane);
    const Frag FA  = frag_from_c(acc);         // symmetric
    f32x16 u = mm_ff(FA, FGs);                 // (sumL) * Gs
    const Frag Fu = frag_from_c(u);
    u = mm_ff(FGs, Fu);                        // Gs (sumL) Gs
    float* g = scr + (size_t)n * 1024;
#pragma unroll
    for (int i = 0; i < 16; ++i) {
      const int row = (i & 3) + 8 * (i >> 2) + 4 * h;
      g[row * 32 + ccol] = u[i];
    }
  }
}

__global__ __launch_bounds__(64) void k4_mean(float* __restrict__ ws, int q) {
  __shared__ float GB[MSZ], D1[MSZ], D2[MSZ], D3[MSZ];
  const int d = blockIdx.x, lane = threadIdx.x;
  const int bi4 = (lane >> 3) * 4, bj4 = (lane & 7) * 4;
  const int dg = (bi4 == bj4);
  const float cntf = ws[WS_CNT + d];
  float c[16], t[16];
  ldg_mat(ws + WS_G0ISQ + d * 1024, c, bi4, bj4); st_row(GB, c, bi4, bj4);
  ldg_mat(ws + WS_GTSUM + d * 1024, c, bi4, bj4);
  const float s = 1.f / ((float)q * cntf);
#pragma unroll
  for (int i = 0; i < 16; ++i) c[i] *= s;
  st_row(D1, c, bi4, bj4);
  mm_gen(GB, D1, t, bi4, bj4); st_colf(D2, t, bi4, bj4);
  mm_gen(D2, GB, t, bi4, bj4); st_row(D1, t, bi4, bj4);   // E = Gi GT Gi
  float H[16];
  zero16(H); diag4(H, 2.7557319e-7f, dg);                 // 1/10!
  st_row(D2, H, bi4, bj4);
  float ck = 2.7557319e-7f;
#pragma unroll 1
  for (int kk = 9; kk >= 0; --kk) {
    ck *= (float)(kk + 1);
    mm_gen(D1, D2, H, bi4, bj4);
    diag4(H, ck, dg);
    st_row(D2, H, bi4, bj4);
  }                                                       // exp(E)
  ldg_mat(ws + WS_G0SQ + d * 1024, c, bi4, bj4); st_row(GB, c, bi4, bj4);
  st_row(D1, H, bi4, bj4);
  mm_gen(GB, D1, t, bi4, bj4); st_colf(D2, t, bi4, bj4);
  mm_gen(D2, GB, t, bi4, bj4);                            // G
  float Y[16], Z[16];
  wave_sqrtinv(t, Y, Z, D1, D2, D3, bi4, bj4);
  stg_mat(ws + WS_GISQ + d * 1024, Z, bi4, bj4);
}

__global__ __launch_bounds__(128, 2) void k5_logxc(const float* __restrict__ X,
                                                   const int* __restrict__ ds,
                                                   float* __restrict__ ws,
                                                   float* __restrict__ Lout, int q) {
  __shared__ float V2[2];
  const int n = blockIdx.x, tid = threadIdx.x;
  const int w = tid >> 6, lane = tid & 63;
  const int ccol = lane & 31, h = lane >> 5;
  float dm[16];
#pragma unroll
  for (int i = 0; i < 16; ++i) {
    const int row = (i & 3) + 8 * (i >> 2) + 4 * h;
    dm[i] = (row == ccol) ? 1.f : 0.f;
  }
  const int d = ds[n];
  const Frag FGi = frag_rowmajor(ws + WS_GISQ + d * 1024, lane);
  float vacc = 0.f;
  const int half = q >> 1;
#pragma unroll 1
  for (int j = 0; j < half; j += 2) {
    const bool dual = (j + 1 < half);
    const size_t ma = (size_t)n * q + (size_t)w * half + j;
    const size_t mb = dual ? ma + 1 : ma;
    const Frag FXa = frag_rowmajor(X + ma * 1024, lane);
    const Frag FXb = frag_rowmajor(X + mb * 1024, lane);
    f32x16 ua = mm_ff(FXa, FGi);               // X * Gi
    f32x16 ub = mm_ff(FXb, FGi);
    const Frag Fua = frag_from_c(ua);
    const Frag Fub = frag_from_c(ub);
    f32x16 Pa = mm_ff(FGi, Fua);               // Xc = Gi X Gi
    f32x16 Pb = mm_ff(FGi, Fub);
    f32x16 La, Lb;
    logm2(Pa, Pb, La, Lb, dm);
    float sq = 0.f;
#pragma unroll
    for (int i = 0; i < 16; ++i) sq += La[i] * La[i];
    vacc += sq;
    float* ga = Lout + ma * 1024;
#pragma unroll
    for (int i = 0; i < 16; ++i) {
      const int row = (i & 3) + 8 * (i >> 2) + 4 * h;
      ga[row * 32 + ccol] = La[i];
    }
    if (dual) {
      float sqb = 0.f;
#pragma unroll
      for (int i = 0; i < 16; ++i) sqb += Lb[i] * Lb[i];
      vacc += sqb;
      float* gb = Lout + mb * 1024;
#pragma unroll
      for (int i = 0; i < 16; ++i) {
        const int row = (i & 3) + 8 * (i >> 2) + 4 * h;
        gb[row * 32 + ccol] = Lb[i];
      }
    }
  }
  vacc = wsum(vacc);
  if (lane == 0) V2[w] = vacc;
  __syncthreads();
  if (tid == 0) ws[WS_VPART + n] = V2[0] + V2[1];   // plain store, no atomics
}

__global__ __launch_bounds__(64) void k6_p(const int* __restrict__ ds,
                                           float* __restrict__ ws,
                                           int N, int q, int D) {
  const int lane = threadIdx.x;
  float a0 = 0.f, a1 = 0.f, a2 = 0.f, a3 = 0.f;
  for (int n = lane; n < N; n += 64) {
    const int d = ds[n];
    const float v = ws[WS_VPART + n];
    a0 += (d == 0) ? v : 0.f;
    a1 += (d == 1) ? v : 0.f;
    a2 += (d == 2) ? v : 0.f;
    a3 += (d == 3) ? v : 0.f;
  }
  a0 = wsum(a0); a1 = wsum(a1); a2 = wsum(a2); a3 = wsum(a3);
  if (lane < D) {
    const float var0 = (lane == 0) ? a0 : (lane == 1) ? a1 : (lane == 2) ? a2 : a3;
    const float cntf = ws[WS_CNT + lane];
    const float var = var0 / ((float)q * cntf);
    ws[WS_P + lane] = sqrtf(1.f / (var + 1e-5f));
  }
}

__global__ __launch_bounds__(128, 2) void k7_out(const int* __restrict__ ds,
                                                 const float* __restrict__ ws,
                                                 const float* __restrict__ R,
                                                 float* __restrict__ io, int q) {
  const int n = blockIdx.x, tid = threadIdx.x;
  const int w = tid >> 6, lane = tid & 63;
  const int ccol = lane & 31, h = lane >> 5;
  float dm[16];
#pragma unroll
  for (int i = 0; i < 16; ++i) {
    const int row = (i & 3) + 8 * (i >> 2) + 4 * h;
    dm[i] = (row == ccol) ? 1.f : 0.f;
  }
  const int d = ds[n];
  const Frag FR  = frag_rowmajor(R + d * 1024, lane);        // A of R / B of R^T
  const Frag FBs = frag_rowmajor(ws + WS_BSQ + d * 1024, lane);
  const float ph = 0.5f * ws[WS_P + d];
  // Taylor coeffs of exp(ph*L), deg 10
  float coef[11];
  coef[0] = 1.f;
  coef[1] = ph;
  coef[2] = coef[1] * ph * 0.5f;
  coef[3] = coef[2] * ph * (1.f / 3.f);
  coef[4] = coef[3] * ph * 0.25f;
  coef[5] = coef[4] * ph * 0.2f;
  coef[6] = coef[5] * ph * (1.f / 6.f);
  coef[7] = coef[6] * ph * (1.f / 7.f);
  coef[8] = coef[7] * ph * 0.125f;
  coef[9] = coef[8] * ph * (1.f / 9.f);
  coef[10] = coef[9] * ph * 0.1f;
  const int half = q >> 1;
#pragma unroll 1
  for (int j = 0; j < half; j += 2) {
    const bool dual = (j + 1 < half);
    const size_t ma = (size_t)n * q + (size_t)w * half + j;
    const size_t mb = dual ? ma + 1 : ma;
    float* ga = io + ma * 1024;
    float* gb = io + mb * 1024;
    // load L in C-layout (coalesced 128B per i)
    f32x16 Lca, Lcb;
#pragma unroll
    for (int i = 0; i < 16; ++i) {
      const int row = (i & 3) + 8 * (i >> 2) + 4 * h;
      Lca[i] = ga[row * 32 + ccol];
      Lcb[i] = gb[row * 32 + ccol];
    }
    const Frag FLa = frag_from_c(Lca);         // symmetric
    const Frag FLb = frag_from_c(Lcb);
    f32x16 ta = mm_ff(FLa, FLa);               // wmat = L^2
    f32x16 tb = mm_ff(FLb, FLb);
    const Frag Fwa = frag_from_c(ta);
    const Frag Fwb = frag_from_c(tb);
    // exp(ph L) deg-10 via pair-Horner in w: Pj = c_{2j} I + c_{2j+1} L
    f32x16 Ga, Gb;
#pragma unroll
    for (int i = 0; i < 16; ++i) {
      Ga[i] = coef[10] * ta[i] + coef[9] * Lca[i];
      Gb[i] = coef[10] * tb[i] + coef[9] * Lcb[i];
    }
    addID(Ga, coef[8], dm);  addID(Gb, coef[8], dm);
    Frag FGa = frag_from_c(Ga);
    Frag FGb = frag_from_c(Gb);
#pragma unroll
    for (int kk = 7; kk >= 1; kk -= 2) {       // full unroll: coef idx constant
      ta = mm_ff(FGa, Fwa);
      tb = mm_ff(FGb, Fwb);
#pragma unroll
      for (int i = 0; i < 16; ++i) {
        Ga[i] = ta[i] + coef[kk] * Lca[i];
        Gb[i] = tb[i] + coef[kk] * Lcb[i];
      }
      addID(Ga, coef[kk - 1], dm);  addID(Gb, coef[kk - 1], dm);
      FGa = frag_from_c(Ga);
      FGb = frag_from_c(Gb);
    }
    ta = mm_ff(FGa, FGa);                      // Xp = H^2 = exp(p L)
    tb = mm_ff(FGb, FGb);
    const Frag FXpa = frag_from_c(ta);         // symmetric
    const Frag FXpb = frag_from_c(tb);
    ta = mm_ff(FXpa, FR);                      // Xp * R^T
    tb = mm_ff(FXpb, FR);
    Frag Fta = frag_from_c(ta);
    Frag Ftb = frag_from_c(tb);
    ta = mm_ff(FR, Fta);                       // Xr = R Xp R^T
    tb = mm_ff(FR, Ftb);
    const Frag FXra = frag_from_c(ta);         // symmetric
    const Frag FXrb = frag_from_c(tb);
    ta = mm_ff(FXra, FBs);                     // Xr * Bs
    tb = mm_ff(FXrb, FBs);
    Fta = frag_from_c(ta);
    Ftb = frag_from_c(tb);
    ta = mm_ff(FBs, Fta);                      // out = Bs Xr Bs
    tb = mm_ff(FBs, Ftb);
#pragma unroll
    for (int i = 0; i < 16; ++i) {
      const int row = (i & 3) + 8 * (i >> 2) + 4 * h;
      ga[row * 32 + ccol] = ta[i];
    }
    if (dual) {
#pragma unroll
      for (int i = 0; i < 16; ++i) {
        const int row = (i & 3) + 8 * (i >> 2) + 4 * h;
        gb[row * 32 + ccol] = tb[i];
      }
    }
  }
}

// ------------------------------- launcher ----------------------------------

extern "C" void kernel_launch(void* const* d_in, const int* in_sizes, int n_in,
                              void* d_out, int out_size, void* d_ws, size_t ws_size,
                              hipStream_t stream) {
  const float* X  = (const float*)d_in[0];
  const int*   ds = (const int*)d_in[1];
  const float* R  = (const float*)d_in[2];
  const float* B  = (const float*)d_in[3];
  float* out = (float*)d_out;
  float* ws  = (float*)d_ws;
  const int N = in_sizes[1];
  const int q = in_sizes[0] / (N * 1024);
  const int D = in_sizes[2] / 1024;
  (void)n_in; (void)out_size; (void)ws_size;

  // d_out doubles as an 8 MB reduction scratch until k5 overwrites it.
  float* scr = out;

  hipMemsetAsync(d_ws, 0, WS_ZERO * sizeof(float), stream);
  k1_xsum   <<<dim3((N + 3) / 4), dim3(256), 0, stream>>>(X, scr, N, q);
  kred      <<<dim3(8 * D * 4), dim3(256), 0, stream>>>(ds, scr, ws + WS_G0SUM, N, D);
  k2_g0funcs<<<dim3(D), dim3(128), 0, stream>>>(ws, ds, B, N, q);
  k3_gt     <<<dim3(N), dim3(128), 0, stream>>>(X, ds, ws, scr, q);
  kred      <<<dim3(8 * D * 4), dim3(256), 0, stream>>>(ds, scr, ws + WS_GTSUM, N, D);
  k4_mean   <<<dim3(D), dim3(64),  0, stream>>>(ws, q);
  k5_logxc  <<<dim3(N), dim3(128), 0, stream>>>(X, ds, ws, out, q);
  k6_p      <<<dim3(1), dim3(64),  0, stream>>>(ds, ws, N, q, D);
  k7_out    <<<dim3(N), dim3(128), 0, stream>>>(ds, ws, R, out, q);
}

// Round 5
// 669.930 us; speedup vs baseline: 1.6623x; 1.0705x over previous
//
#include <hip/hip_runtime.h>

// ---------------------------------------------------------------------------
// DomainGeneralisationBN (SPD batchnorm) — R8: C-init folding + 4-wave blocks.
// rocprof R7: k5=156us top, MfmaUtil 29%, VALUBusy 58%, occupancy 17% ->
// VALU-bound (VALU floor ~90us) with zero oversubscription (4096 waves = cap).
// Changes (math-identical):
//  * mm_ffc: seed MFMA accumulator with the algebraic tail (M^2+(AL/BE)M,
//    MV+(AL/BE)V, NS u=MX^2-2X with sign tracking + free neg repack,
//    Q^2-Q via C=-Q, Horner +c*S2 in C, QG-G/2, P+I via C=diag) — kills
//    per-mm zero-inits and ~6 elementwise passes per matrix.
//  * k3/k5/k7: 256-thread blocks (4 waves), each wave owns q/4 matrices
//    (dual-ILP inside) -> 8192 waves = 2x oversubscription; k3 merges 4 accs
//    in LDS, wave 3 applies the hoisted Gs(sumL)Gs congruence.
//  * k5 accumulates sum(uf^2), scales by 16 once (L = -4*uf).
// Reduction scheme (R4) unchanged: k1_xsum+kred, VPART.
// ---------------------------------------------------------------------------

#define LN  36
#define MSZ (32 * LN)

// workspace layout (float offsets)
#define WS_G0SUM 0
#define WS_GTSUM 4096
#define WS_VAR   8192
#define WS_CNT   8196
#define WS_P     8200
#define WS_G0SQ  8208
#define WS_G0ISQ 12304
#define WS_GISQ  16400
#define WS_BSQ   20496
#define WS_VPART 24592      // N floats of per-block variance partials
#define WS_ZERO  8208

// (P+I)^-1 NS init: X0 = AL*I + BE*M, Chebyshev on eigs(M) in [1.15, 8]
#define LOG_AL 0.6073551f
#define LOG_BE (-0.0663776f)
#define LOG_RAB (-9.1500001f)   // AL/BE

typedef __attribute__((ext_vector_type(8)))  short bf16x8;
typedef __attribute__((ext_vector_type(16))) float f32x16;

union FragU { uint4 u; bf16x8 v; };

struct Frag { bf16x8 h0, h1, l0, l1; };

__device__ __forceinline__ float wsum(float v) {
#pragma unroll
  for (int o = 32; o > 0; o >>= 1) v += __shfl_xor(v, o, 64);
  return v;
}

// ---------------- MFMA-path helpers ----------------

// C = A*B + Cin with split-bf16 3-product scheme, all operands in registers.
__device__ __forceinline__ f32x16 mm_ffc(const Frag A, const Frag B,
                                         const f32x16 cin) {
  f32x16 c = cin;
  c = __builtin_amdgcn_mfma_f32_32x32x16_bf16(A.h0, B.h0, c, 0, 0, 0);
  c = __builtin_amdgcn_mfma_f32_32x32x16_bf16(A.h0, B.l0, c, 0, 0, 0);
  c = __builtin_amdgcn_mfma_f32_32x32x16_bf16(A.l0, B.h0, c, 0, 0, 0);
  c = __builtin_amdgcn_mfma_f32_32x32x16_bf16(A.h1, B.h1, c, 0, 0, 0);
  c = __builtin_amdgcn_mfma_f32_32x32x16_bf16(A.h1, B.l1, c, 0, 0, 0);
  c = __builtin_amdgcn_mfma_f32_32x32x16_bf16(A.l1, B.h1, c, 0, 0, 0);
  return c;
}

__device__ __forceinline__ f32x16 mm_ff(const Frag A, const Frag B) {
  f32x16 z;
#pragma unroll
  for (int i = 0; i < 16; ++i) z[i] = 0.f;
  return mm_ffc(A, B, z);
}

// pack (x0,x1) -> hi word [bf16(x1)|bf16(x0)] (RTNE) + lo residual word.
__device__ __forceinline__ void packpair(float x0, float x1,
                                         unsigned& hw, unsigned& lw) {
  unsigned h;
  asm("v_cvt_pk_bf16_f32 %0, %1, %2" : "=v"(h) : "v"(x0), "v"(x1));
  const float h0 = __uint_as_float(h << 16);
  const float h1 = __uint_as_float(h & 0xFFFF0000u);
  const float l0 = x0 - h0;
  const float l1 = x1 - h1;
  asm("v_cvt_pk_bf16_f32 %0, %1, %2" : "=v"(lw) : "v"(l0), "v"(l1));
  hw = h;
}

__device__ __forceinline__ void plswap2(unsigned a, unsigned b,
                                        unsigned& r0, unsigned& r1) {
  auto p = __builtin_amdgcn_permlane32_swap(a, b, false, false);
  r0 = p[0]; r1 = p[1];
}

// C-regs (col=ccol, rows (i&3)+8*(i>>2)+4h) -> split-bf16 fragment of the
// SAME matrix: valid B-operand always; valid A-operand iff symmetric.
__device__ __forceinline__ Frag frag_from_c(const f32x16 c) {
  unsigned hw[8], lw[8];
#pragma unroll
  for (int g = 0; g < 4; ++g) {
    packpair(c[4*g+0], c[4*g+1], hw[2*g+0], lw[2*g+0]);
    packpair(c[4*g+2], c[4*g+3], hw[2*g+1], lw[2*g+1]);
  }
  unsigned w0, w1, w2, w3;
  FragU A, B, C, D;
  plswap2(hw[0], hw[2], w0, w2);
  plswap2(hw[1], hw[3], w1, w3);
  A.u = make_uint4(w0, w1, w2, w3);          // h0 : rows h*8..h*8+7
  plswap2(hw[4], hw[6], w0, w2);
  plswap2(hw[5], hw[7], w1, w3);
  B.u = make_uint4(w0, w1, w2, w3);          // h1 : rows 16+h*8..
  plswap2(lw[0], lw[2], w0, w2);
  plswap2(lw[1], lw[3], w1, w3);
  C.u = make_uint4(w0, w1, w2, w3);          // l0
  plswap2(lw[4], lw[6], w0, w2);
  plswap2(lw[5], lw[7], w1, w3);
  D.u = make_uint4(w0, w1, w2, w3);          // l1
  Frag f; f.h0 = A.v; f.h1 = B.v; f.l0 = C.v; f.l1 = D.v;
  return f;
}

// fragment of (-M) given C-regs of M (negation folds into cvt modifiers/subs)
__device__ __forceinline__ Frag frag_from_c_neg(const f32x16 c) {
  f32x16 n;
#pragma unroll
  for (int i = 0; i < 16; ++i) n[i] = -c[i];
  return frag_from_c(n);
}

// 32x32 f32 row-major global matrix M -> fragment = A-operand of M and
// B-operand of M^T (both A/B of M when symmetric).
__device__ __forceinline__ Frag frag_rowmajor(const float* __restrict__ g,
                                              int lane) {
  const int r = lane & 31, h = lane >> 5;
  const float* p = g + r * 32 + h * 8;
  const float4 v0 = *(const float4*)(p);
  const float4 v1 = *(const float4*)(p + 4);
  const float4 v2 = *(const float4*)(p + 16);
  const float4 v3 = *(const float4*)(p + 20);
  unsigned hw[8], lw[8];
  packpair(v0.x, v0.y, hw[0], lw[0]);
  packpair(v0.z, v0.w, hw[1], lw[1]);
  packpair(v1.x, v1.y, hw[2], lw[2]);
  packpair(v1.z, v1.w, hw[3], lw[3]);
  packpair(v2.x, v2.y, hw[4], lw[4]);
  packpair(v2.z, v2.w, hw[5], lw[5]);
  packpair(v3.x, v3.y, hw[6], lw[6]);
  packpair(v3.z, v3.w, hw[7], lw[7]);
  FragU A, B, C, D;
  A.u = make_uint4(hw[0], hw[1], hw[2], hw[3]);
  B.u = make_uint4(hw[4], hw[5], hw[6], hw[7]);
  C.u = make_uint4(lw[0], lw[1], lw[2], lw[3]);
  D.u = make_uint4(lw[4], lw[5], lw[6], lw[7]);
  Frag f; f.h0 = A.v; f.h1 = B.v; f.l0 = C.v; f.l1 = D.v;
  return f;
}

__device__ __forceinline__ void addID(f32x16& c, float v, const f32x16 dm) {
#pragma unroll
  for (int i = 0; i < 16; ++i) c[i] = fmaf(v, dm[i], c[i]);
}

// Dual logm with C-init folds.  Input: Ma/Mb = Gi X Gi + I (the P+I fold is
// done by the caller via mm_ffc C=dm).  Output: uf with L = -4*uf.
// NS inverse (Chebyshev init + 3 iters, sign-tracked), Cayley S=I-2Q,
// Gregory deg-8 pair-Horner in y^2.
__device__ __forceinline__ void logm2(const f32x16 Ma, const f32x16 Mb,
                                      f32x16& ufa, f32x16& ufb,
                                      const f32x16 dm) {
  const Frag FMa = frag_from_c(Ma);
  const Frag FMb = frag_from_c(Mb);
  f32x16 ca, cb, ta, tb;
  // t = M^2 + (AL/BE) M ; V = 2I - BE*t
#pragma unroll
  for (int i = 0; i < 16; ++i) { ca[i] = LOG_RAB * Ma[i]; cb[i] = LOG_RAB * Mb[i]; }
  ta = mm_ffc(FMa, FMa, ca);
  tb = mm_ffc(FMb, FMb, cb);
  f32x16 Va, Vb;
#pragma unroll
  for (int i = 0; i < 16; ++i) {
    Va[i] = fmaf(-LOG_BE, ta[i], 2.f * dm[i]);
    Vb[i] = fmaf(-LOG_BE, tb[i], 2.f * dm[i]);
  }
  const Frag FVa = frag_from_c(Va);
  const Frag FVb = frag_from_c(Vb);
  // u = MV + (AL/BE) V ; X1 = BE*u
#pragma unroll
  for (int i = 0; i < 16; ++i) { ca[i] = LOG_RAB * Va[i]; cb[i] = LOG_RAB * Vb[i]; }
  ta = mm_ffc(FMa, FVa, ca);
  tb = mm_ffc(FMb, FVb, cb);
  f32x16 Xa, Xb;
#pragma unroll
  for (int i = 0; i < 16; ++i) { Xa[i] = LOG_BE * ta[i]; Xb[i] = LOG_BE * tb[i]; }
  Frag FXa = frag_from_c(Xa);
  Frag FXb = frag_from_c(Xb);
  // NS1: t = M*X1^2 - 2*X1 = -X2
#pragma unroll
  for (int i = 0; i < 16; ++i) { ca[i] = -2.f * Xa[i]; cb[i] = -2.f * Xb[i]; }
  {
    f32x16 sa = mm_ff(FXa, FXa);
    f32x16 sb = mm_ff(FXb, FXb);
    const Frag Fsa = frag_from_c(sa);
    const Frag Fsb = frag_from_c(sb);
    ta = mm_ffc(FMa, Fsa, ca);               // -X2
    tb = mm_ffc(FMb, Fsb, cb);
  }
  FXa = frag_from_c_neg(ta);                 // X2
  FXb = frag_from_c_neg(tb);
  // NS2: -X3 = M*X2^2 - 2*X2, C = 2*(-X2)
#pragma unroll
  for (int i = 0; i < 16; ++i) { ca[i] = 2.f * ta[i]; cb[i] = 2.f * tb[i]; }
  {
    f32x16 sa = mm_ff(FXa, FXa);
    f32x16 sb = mm_ff(FXb, FXb);
    const Frag Fsa = frag_from_c(sa);
    const Frag Fsb = frag_from_c(sb);
    ta = mm_ffc(FMa, Fsa, ca);               // -X3
    tb = mm_ffc(FMb, Fsb, cb);
  }
  FXa = frag_from_c_neg(ta);                 // X3
  FXb = frag_from_c_neg(tb);
  // NS3: -Q = M*X3^2 - 2*X3
#pragma unroll
  for (int i = 0; i < 16; ++i) { ca[i] = 2.f * ta[i]; cb[i] = 2.f * tb[i]; }
  {
    f32x16 sa = mm_ff(FXa, FXa);
    f32x16 sb = mm_ff(FXb, FXb);
    const Frag Fsa = frag_from_c(sa);
    const Frag Fsb = frag_from_c(sb);
    ta = mm_ffc(FMa, Fsa, ca);               // -Q
    tb = mm_ffc(FMb, Fsb, cb);
  }
  const Frag FQa = frag_from_c_neg(ta);      // Q
  const Frag FQb = frag_from_c_neg(tb);
  // S2 = 4*(Q^2 - Q) + I ; Q^2 - Q via C = -Q (= ta, zero extra ops)
  f32x16 S2a, S2b;
  {
    f32x16 va = mm_ffc(FQa, FQa, ta);
    f32x16 vb = mm_ffc(FQb, FQb, tb);
#pragma unroll
    for (int i = 0; i < 16; ++i) {
      S2a[i] = fmaf(4.f, va[i], dm[i]);
      S2b[i] = fmaf(4.f, vb[i], dm[i]);
    }
  }
  const Frag Fya = frag_from_c(S2a);
  const Frag Fyb = frag_from_c(S2b);
  f32x16 wa = mm_ff(Fya, Fya);               // w = y^2
  f32x16 wb = mm_ff(Fyb, Fyb);
  const Frag Fwa = frag_from_c(wa);
  const Frag Fwb = frag_from_c(wb);
  // G0 = c17*w + c15*S2 + c13*I
  f32x16 Ga, Gb;
#pragma unroll
  for (int i = 0; i < 16; ++i) {
    Ga[i] = fmaf(1.f/17.f, wa[i], (1.f/15.f) * S2a[i]);
    Gb[i] = fmaf(1.f/17.f, wb[i], (1.f/15.f) * S2b[i]);
  }
  addID(Ga, 1.f/13.f, dm);  addID(Gb, 1.f/13.f, dm);
  Frag FGa = frag_from_c(Ga);
  Frag FGb = frag_from_c(Gb);
  // 3 Horner steps: G' = G*w + chi*S2 + clo*I  (chi*S2 folded into C)
#pragma unroll
  for (int s = 0; s < 3; ++s) {
    const float chi = (s == 0) ? (1.f/11.f) : (s == 1) ? (1.f/7.f) : (1.f/3.f);
    const float clo = (s == 0) ? (1.f/9.f)  : (s == 1) ? (1.f/5.f) : 1.f;
#pragma unroll
    for (int i = 0; i < 16; ++i) { ca[i] = chi * S2a[i]; cb[i] = chi * S2b[i]; }
    Ga = mm_ffc(FGa, Fwa, ca);
    Gb = mm_ffc(FGb, Fwb, cb);
    addID(Ga, clo, dm);  addID(Gb, clo, dm);
    FGa = frag_from_c(Ga);
    FGb = frag_from_c(Gb);
  }
  // uf = Q*G - 0.5*G ;  L = -4*uf = 2G - 4QG
#pragma unroll
  for (int i = 0; i < 16; ++i) { ca[i] = -0.5f * Ga[i]; cb[i] = -0.5f * Gb[i]; }
  ufa = mm_ffc(FQa, FGa, ca);
  ufb = mm_ffc(FQb, FGb, cb);
}

// ---------------- fp32-VALU helpers (k2/k4 only, D=4 matrices) ----------------

__device__ __forceinline__ void zero16(float c[16]) {
#pragma unroll
  for (int i = 0; i < 16; ++i) c[i] = 0.f;
}
__device__ __forceinline__ void diag4(float c[16], float v, int dg) {
  if (dg) { c[0] += v; c[5] += v; c[10] += v; c[15] += v; }
}
__device__ __forceinline__ void mm_gen(const float* A, const float* B, float c[16],
                                       int bi4, int bj4) {
  zero16(c);
#pragma unroll 4
  for (int k = 0; k < 32; ++k) {
    float4 a = *(const float4*)(A + k * LN + bi4);
    float4 b = *(const float4*)(B + k * LN + bj4);
    c[0] = fmaf(a.x, b.x, c[0]);  c[1] = fmaf(a.x, b.y, c[1]);
    c[2] = fmaf(a.x, b.z, c[2]);  c[3] = fmaf(a.x, b.w, c[3]);
    c[4] = fmaf(a.y, b.x, c[4]);  c[5] = fmaf(a.y, b.y, c[5]);
    c[6] = fmaf(a.y, b.z, c[6]);  c[7] = fmaf(a.y, b.w, c[7]);
    c[8] = fmaf(a.z, b.x, c[8]);  c[9] = fmaf(a.z, b.y, c[9]);
    c[10]= fmaf(a.z, b.z, c[10]); c[11]= fmaf(a.z, b.w, c[11]);
    c[12]= fmaf(a.w, b.x, c[12]); c[13]= fmaf(a.w, b.y, c[13]);
    c[14]= fmaf(a.w, b.z, c[14]); c[15]= fmaf(a.w, b.w, c[15]);
  }
}
__device__ __forceinline__ void st_row(float* buf, const float c[16], int bi4, int bj4) {
#pragma unroll
  for (int di = 0; di < 4; ++di)
    *(float4*)(buf + (bi4 + di) * LN + bj4) =
        make_float4(c[di*4+0], c[di*4+1], c[di*4+2], c[di*4+3]);
}
__device__ __forceinline__ void st_colf(float* buf, const float c[16], int bi4, int bj4) {
#pragma unroll
  for (int dj = 0; dj < 4; ++dj)
    *(float4*)(buf + (bj4 + dj) * LN + bi4) =
        make_float4(c[0*4+dj], c[1*4+dj], c[2*4+dj], c[3*4+dj]);
}
__device__ __forceinline__ void ldg_mat(const float* __restrict__ g, float c[16],
                                        int bi4, int bj4) {
#pragma unroll
  for (int di = 0; di < 4; ++di) {
    float4 v = *(const float4*)(g + (bi4 + di) * 32 + bj4);
    c[di*4+0] = v.x; c[di*4+1] = v.y; c[di*4+2] = v.z; c[di*4+3] = v.w;
  }
}
__device__ __forceinline__ void stg_mat(float* __restrict__ g, const float c[16],
                                        int bi4, int bj4) {
#pragma unroll
  for (int di = 0; di < 4; ++di)
    *(float4*)(g + (bi4 + di) * 32 + bj4) =
        make_float4(c[di*4+0], c[di*4+1], c[di*4+2], c[di*4+3]);
}
__device__ __forceinline__ void wave_sqrtinv(const float A[16], float Ysq[16], float Zis[16],
                                             float* YB, float* ZB, float* TB,
                                             int bi4, int bj4) {
  const int dg = (bi4 == bj4);
  float ss = 0.f;
#pragma unroll
  for (int i = 0; i < 16; ++i) ss += A[i] * A[i];
  const float th = sqrtf(wsum(ss));
  const float inv = 1.f / th;
  float Y[16], Z[16];
#pragma unroll
  for (int i = 0; i < 16; ++i) Y[i] = A[i] * inv;
  zero16(Z); diag4(Z, 1.f, dg);
  st_row(YB, Y, bi4, bj4);
  st_row(ZB, Z, bi4, bj4);
#pragma unroll 1
  for (int it = 0; it < 13; ++it) {
    float W[16], T[16];
    mm_gen(ZB, YB, W, bi4, bj4);
#pragma unroll
    for (int i = 0; i < 16; ++i) T[i] = -0.5f * W[i];
    diag4(T, 1.5f, dg);
    st_row(TB, T, bi4, bj4);
    mm_gen(YB, TB, Y, bi4, bj4);
    mm_gen(TB, ZB, Z, bi4, bj4);
    st_row(YB, Y, bi4, bj4);
    st_row(ZB, Z, bi4, bj4);
  }
  const float sth = sqrtf(th), isth = 1.f / sth;
#pragma unroll
  for (int i = 0; i < 16; ++i) { Ysq[i] = Y[i] * sth; Zis[i] = Z[i] * isth; }
}

// ------------------------------- kernels -----------------------------------

// per-n sum over the q matrices, plain stores into scratch (d_out).
__global__ __launch_bounds__(256) void k1_xsum(const float* __restrict__ X,
                                               float* __restrict__ scr,
                                               int N, int q) {
  const int w = threadIdx.x >> 6, lane = threadIdx.x & 63;
  const int n = blockIdx.x * 4 + w;
  if (n >= N) return;
  float acc[16];
  zero16(acc);
  const float* base = X + (size_t)n * q * 1024 + lane * 16;
#pragma unroll 4
  for (int j = 0; j < q; ++j) {
    const float* g = base + (size_t)j * 1024;
#pragma unroll
    for (int u = 0; u < 4; ++u) {
      float4 v = *(const float4*)(g + u * 4);
      acc[u*4+0] += v.x; acc[u*4+1] += v.y; acc[u*4+2] += v.z; acc[u*4+3] += v.w;
    }
  }
  float* dst = scr + (size_t)n * 1024 + lane * 16;
#pragma unroll
  for (int u = 0; u < 4; ++u)
    *(float4*)(dst + u * 4) =
        make_float4(acc[u*4+0], acc[u*4+1], acc[u*4+2], acc[u*4+3]);
}

// gather-by-domain reduce: dst[d*1024+e] += sum_{n: ds[n]==d} src[n*1024+e].
__global__ __launch_bounds__(256) void kred(const int* __restrict__ ds,
                                            const float* __restrict__ src,
                                            float* __restrict__ dst,
                                            int N, int D) {
  const int obln = D * 4;
  const int chunk = blockIdx.x / obln;
  const int ob    = blockIdx.x % obln;
  const int out   = ob * 256 + threadIdx.x;
  const int d = out >> 10, e = out & 1023;
  const int cs = (N + 7) >> 3;
  const int n0 = chunk * cs;
  const int n1 = min(N, n0 + cs);
  float acc = 0.f;
#pragma unroll 16
  for (int n = n0; n < n1; ++n) {
    const float v = src[(size_t)n * 1024 + e];
    acc += (ds[n] == d) ? v : 0.f;
  }
  atomicAdd(dst + out, acc);
}

__global__ __launch_bounds__(128) void k2_g0funcs(float* __restrict__ ws,
                                                  const int* __restrict__ ds,
                                                  const float* __restrict__ B,
                                                  int N, int q) {
  __shared__ float D[2][3][MSZ];
  const int d = blockIdx.x, tid = threadIdx.x;
  const int w = tid >> 6, lane = tid & 63;
  const int bi4 = (lane >> 3) * 4, bj4 = (lane & 7) * 4;
  float A[16], Y[16], Z[16];
  if (w == 0) {
    int cnt = 0;
    for (int i = lane; i < N; i += 64) cnt += (ds[i] == d) ? 1 : 0;
    const float cntf = wsum((float)cnt);
    if (lane == 0) ws[WS_CNT + d] = cntf;
    ldg_mat(ws + WS_G0SUM + d * 1024, A, bi4, bj4);
    const float s = 1.f / ((float)q * cntf);
#pragma unroll
    for (int i = 0; i < 16; ++i) A[i] *= s;
    wave_sqrtinv(A, Y, Z, D[0][0], D[0][1], D[0][2], bi4, bj4);
    stg_mat(ws + WS_G0SQ  + d * 1024, Y, bi4, bj4);
    stg_mat(ws + WS_G0ISQ + d * 1024, Z, bi4, bj4);
  } else {
    ldg_mat(B + d * 1024, A, bi4, bj4);
    wave_sqrtinv(A, Y, Z, D[1][0], D[1][1], D[1][2], bi4, bj4);
    stg_mat(ws + WS_BSQ + d * 1024, Y, bi4, bj4);
  }
}

__global__ __launch_bounds__(256, 2) void k3_gt(const float* __restrict__ X,
                                                const int* __restrict__ ds,
                                                const float* __restrict__ ws,
                                                float* __restrict__ scr, int q) {
  __shared__ float RED[3][1024];
  const int n = blockIdx.x, tid = threadIdx.x;
  const int w = tid >> 6, lane = tid & 63;
  const int ccol = lane & 31, h = lane >> 5;
  f32x16 dm;
#pragma unroll
  for (int i = 0; i < 16; ++i) {
    const int row = (i & 3) + 8 * (i >> 2) + 4 * h;
    dm[i] = (row == ccol) ? 1.f : 0.f;
  }
  const int d = ds[n];
  const Frag FGi = frag_rowmajor(ws + WS_G0ISQ + d * 1024, lane);
  f32x16 acc;
#pragma unroll
  for (int i = 0; i < 16; ++i) acc[i] = 0.f;
  const int qw = (q + 3) >> 2;
  const int jbeg = w * qw;
  const int jend = min(q, jbeg + qw);
#pragma unroll 1
  for (int j = jbeg; j < jend; j += 2) {
    const bool dual = (j + 1 < jend);
    const size_t ma = (size_t)n * q + j;
    const size_t mb = dual ? ma + 1 : ma;
    const Frag FXa = frag_rowmajor(X + ma * 1024, lane);   // symmetric
    const Frag FXb = frag_rowmajor(X + mb * 1024, lane);
    f32x16 ua = mm_ff(FXa, FGi);               // X * Gi
    f32x16 ub = mm_ff(FXb, FGi);
    const Frag Fua = frag_from_c(ua);          // B-only use
    const Frag Fub = frag_from_c(ub);
    f32x16 Pa = mm_ffc(FGi, Fua, dm);          // Gi X Gi + I
    f32x16 Pb = mm_ffc(FGi, Fub, dm);
    f32x16 ufa, ufb;
    logm2(Pa, Pb, ufa, ufb, dm);               // L = -4*uf
#pragma unroll
    for (int i = 0; i < 16; ++i) acc[i] = fmaf(-4.f, ufa[i], acc[i]);
    if (dual) {
#pragma unroll
      for (int i = 0; i < 16; ++i) acc[i] = fmaf(-4.f, ufb[i], acc[i]);
    }
  }
  // merge 4 waves via LDS, then ONE hoisted congruence by wave 3:
  // sum_j Gs L_j Gs = Gs (sum_j L_j) Gs
  if (w < 3) {
#pragma unroll
    for (int i = 0; i < 16; ++i) {
      const int row = (i & 3) + 8 * (i >> 2) + 4 * h;
      RED[w][row * 32 + ccol] = acc[i];
    }
  }
  __syncthreads();
  if (w == 3) {
#pragma unroll
    for (int i = 0; i < 16; ++i) {
      const int row = (i & 3) + 8 * (i >> 2) + 4 * h;
      const int e = row * 32 + ccol;
      acc[i] += RED[0][e] + RED[1][e] + RED[2][e];
    }
    const Frag FGs = frag_rowmajor(ws + WS_G0SQ + d * 1024, lane);
    const Frag FA  = frag_from_c(acc);         // symmetric
    f32x16 u = mm_ff(FA, FGs);                 // (sumL) * Gs
    const Frag Fu = frag_from_c(u);
    u = mm_ff(FGs, Fu);                        // Gs (sumL) Gs
    float* g = scr + (size_t)n * 1024;
#pragma unroll
    for (int i = 0; i < 16; ++i) {
      const int row = (i & 3) + 8 * (i >> 2) + 4 * h;
      g[row * 32 + ccol] = u[i];
    }
  }
}

__global__ __launch_bounds__(64) void k4_mean(float* __restrict__ ws, int q) {
  __shared__ float GB[MSZ], D1[MSZ], D2[MSZ], D3[MSZ];
  const int d = blockIdx.x, lane = threadIdx.x;
  const int bi4 = (lane >> 3) * 4, bj4 = (lane & 7) * 4;
  const int dg = (bi4 == bj4);
  const float cntf = ws[WS_CNT + d];
  float c[16], t[16];
  ldg_mat(ws + WS_G0ISQ + d * 1024, c, bi4, bj4); st_row(GB, c, bi4, bj4);
  ldg_mat(ws + WS_GTSUM + d * 1024, c, bi4, bj4);
  const float s = 1.f / ((float)q * cntf);
#pragma unroll
  for (int i = 0; i < 16; ++i) c[i] *= s;
  st_row(D1, c, bi4, bj4);
  mm_gen(GB, D1, t, bi4, bj4); st_colf(D2, t, bi4, bj4);
  mm_gen(D2, GB, t, bi4, bj4); st_row(D1, t, bi4, bj4);   // E = Gi GT Gi
  float H[16];
  zero16(H); diag4(H, 2.7557319e-7f, dg);                 // 1/10!
  st_row(D2, H, bi4, bj4);
  float ck = 2.7557319e-7f;
#pragma unroll 1
  for (int kk = 9; kk >= 0; --kk) {
    ck *= (float)(kk + 1);
    mm_gen(D1, D2, H, bi4, bj4);
    diag4(H, ck, dg);
    st_row(D2, H, bi4, bj4);
  }                                                       // exp(E)
  ldg_mat(ws + WS_G0SQ + d * 1024, c, bi4, bj4); st_row(GB, c, bi4, bj4);
  st_row(D1, H, bi4, bj4);
  mm_gen(GB, D1, t, bi4, bj4); st_colf(D2, t, bi4, bj4);
  mm_gen(D2, GB, t, bi4, bj4);                            // G
  float Y[16], Z[16];
  wave_sqrtinv(t, Y, Z, D1, D2, D3, bi4, bj4);
  stg_mat(ws + WS_GISQ + d * 1024, Z, bi4, bj4);
}

__global__ __launch_bounds__(256, 2) void k5_logxc(const float* __restrict__ X,
                                                   const int* __restrict__ ds,
                                                   float* __restrict__ ws,
                                                   float* __restrict__ Lout, int q) {
  __shared__ float V4[4];
  const int n = blockIdx.x, tid = threadIdx.x;
  const int w = tid >> 6, lane = tid & 63;
  const int ccol = lane & 31, h = lane >> 5;
  f32x16 dm;
#pragma unroll
  for (int i = 0; i < 16; ++i) {
    const int row = (i & 3) + 8 * (i >> 2) + 4 * h;
    dm[i] = (row == ccol) ? 1.f : 0.f;
  }
  const int d = ds[n];
  const Frag FGi = frag_rowmajor(ws + WS_GISQ + d * 1024, lane);
  float vacc = 0.f;
  const int qw = (q + 3) >> 2;
  const int jbeg = w * qw;
  const int jend = min(q, jbeg + qw);
#pragma unroll 1
  for (int j = jbeg; j < jend; j += 2) {
    const bool dual = (j + 1 < jend);
    const size_t ma = (size_t)n * q + j;
    const size_t mb = dual ? ma + 1 : ma;
    const Frag FXa = frag_rowmajor(X + ma * 1024, lane);
    const Frag FXb = frag_rowmajor(X + mb * 1024, lane);
    f32x16 ua = mm_ff(FXa, FGi);               // X * Gi
    f32x16 ub = mm_ff(FXb, FGi);
    const Frag Fua = frag_from_c(ua);
    const Frag Fub = frag_from_c(ub);
    f32x16 Pa = mm_ffc(FGi, Fua, dm);          // Gi X Gi + I
    f32x16 Pb = mm_ffc(FGi, Fub, dm);
    f32x16 ufa, ufb;
    logm2(Pa, Pb, ufa, ufb, dm);               // L = -4*uf
    float sq = 0.f;
#pragma unroll
    for (int i = 0; i < 16; ++i) sq += ufa[i] * ufa[i];
    vacc += sq;
    float* ga = Lout + ma * 1024;
#pragma unroll
    for (int i = 0; i < 16; ++i) {
      const int row = (i & 3) + 8 * (i >> 2) + 4 * h;
      ga[row * 32 + ccol] = -4.f * ufa[i];
    }
    if (dual) {
      float sqb = 0.f;
#pragma unroll
      for (int i = 0; i < 16; ++i) sqb += ufb[i] * ufb[i];
      vacc += sqb;
      float* gb = Lout + mb * 1024;
#pragma unroll
      for (int i = 0; i < 16; ++i) {
        const int row = (i & 3) + 8 * (i >> 2) + 4 * h;
        gb[row * 32 + ccol] = -4.f * ufb[i];
      }
    }
  }
  vacc = wsum(vacc * 16.f);                    // ||L||^2 = 16*||uf||^2
  if (lane == 0) V4[w] = vacc;
  __syncthreads();
  if (tid == 0) ws[WS_VPART + n] = V4[0] + V4[1] + V4[2] + V4[3];
}

__global__ __launch_bounds__(64) void k6_p(const int* __restrict__ ds,
                                           float* __restrict__ ws,
                                           int N, int q, int D) {
  const int lane = threadIdx.x;
  float a0 = 0.f, a1 = 0.f, a2 = 0.f, a3 = 0.f;
  for (int n = lane; n < N; n += 64) {
    const int d = ds[n];
    const float v = ws[WS_VPART + n];
    a0 += (d == 0) ? v : 0.f;
    a1 += (d == 1) ? v : 0.f;
    a2 += (d == 2) ? v : 0.f;
    a3 += (d == 3) ? v : 0.f;
  }
  a0 = wsum(a0); a1 = wsum(a1); a2 = wsum(a2); a3 = wsum(a3);
  if (lane < D) {
    const float var0 = (lane == 0) ? a0 : (lane == 1) ? a1 : (lane == 2) ? a2 : a3;
    const float cntf = ws[WS_CNT + lane];
    const float var = var0 / ((float)q * cntf);
    ws[WS_P + lane] = sqrtf(1.f / (var + 1e-5f));
  }
}

__global__ __launch_bounds__(256, 2) void k7_out(const int* __restrict__ ds,
                                                 const float* __restrict__ ws,
                                                 const float* __restrict__ R,
                                                 float* __restrict__ io, int q) {
  const int n = blockIdx.x, tid = threadIdx.x;
  const int w = tid >> 6, lane = tid & 63;
  const int ccol = lane & 31, h = lane >> 5;
  f32x16 dm;
#pragma unroll
  for (int i = 0; i < 16; ++i) {
    const int row = (i & 3) + 8 * (i >> 2) + 4 * h;
    dm[i] = (row == ccol) ? 1.f : 0.f;
  }
  const int d = ds[n];
  const Frag FR  = frag_rowmajor(R + d * 1024, lane);        // A of R / B of R^T
  const Frag FBs = frag_rowmajor(ws + WS_BSQ + d * 1024, lane);
  const float ph = 0.5f * ws[WS_P + d];
  // Taylor coeffs of exp(ph*L), deg 10
  float coef[11];
  coef[0] = 1.f;
  coef[1] = ph;
  coef[2] = coef[1] * ph * 0.5f;
  coef[3] = coef[2] * ph * (1.f / 3.f);
  coef[4] = coef[3] * ph * 0.25f;
  coef[5] = coef[4] * ph * 0.2f;
  coef[6] = coef[5] * ph * (1.f / 6.f);
  coef[7] = coef[6] * ph * (1.f / 7.f);
  coef[8] = coef[7] * ph * 0.125f;
  coef[9] = coef[8] * ph * (1.f / 9.f);
  coef[10] = coef[9] * ph * 0.1f;
  const int qw = (q + 3) >> 2;
  const int jbeg = w * qw;
  const int jend = min(q, jbeg + qw);
#pragma unroll 1
  for (int j = jbeg; j < jend; j += 2) {
    const bool dual = (j + 1 < jend);
    const size_t ma = (size_t)n * q + j;
    const size_t mb = dual ? ma + 1 : ma;
    float* ga = io + ma * 1024;
    float* gb = io + mb * 1024;
    // load L in C-layout (coalesced 128B per i)
    f32x16 Lca, Lcb;
#pragma unroll
    for (int i = 0; i < 16; ++i) {
      const int row = (i & 3) + 8 * (i >> 2) + 4 * h;
      Lca[i] = ga[row * 32 + ccol];
      Lcb[i] = gb[row * 32 + ccol];
    }
    const Frag FLa = frag_from_c(Lca);         // symmetric
    const Frag FLb = frag_from_c(Lcb);
    f32x16 ta = mm_ff(FLa, FLa);               // wmat = L^2
    f32x16 tb = mm_ff(FLb, FLb);
    const Frag Fwa = frag_from_c(ta);
    const Frag Fwb = frag_from_c(tb);
    // exp(ph L) deg-10 pair-Horner in w, coef[kk]*L folded into C
    f32x16 Ga, Gb;
#pragma unroll
    for (int i = 0; i < 16; ++i) {
      Ga[i] = fmaf(coef[10], ta[i], coef[9] * Lca[i]);
      Gb[i] = fmaf(coef[10], tb[i], coef[9] * Lcb[i]);
    }
    addID(Ga, coef[8], dm);  addID(Gb, coef[8], dm);
    Frag FGa = frag_from_c(Ga);
    Frag FGb = frag_from_c(Gb);
#pragma unroll
    for (int kk = 7; kk >= 1; kk -= 2) {       // full unroll: coef idx constant
      f32x16 cca, ccb;
#pragma unroll
      for (int i = 0; i < 16; ++i) {
        cca[i] = coef[kk] * Lca[i];
        ccb[i] = coef[kk] * Lcb[i];
      }
      Ga = mm_ffc(FGa, Fwa, cca);
      Gb = mm_ffc(FGb, Fwb, ccb);
      addID(Ga, coef[kk - 1], dm);  addID(Gb, coef[kk - 1], dm);
      FGa = frag_from_c(Ga);
      FGb = frag_from_c(Gb);
    }
    ta = mm_ff(FGa, FGa);                      // Xp = H^2 = exp(p L)
    tb = mm_ff(FGb, FGb);
    const Frag FXpa = frag_from_c(ta);         // symmetric
    const Frag FXpb = frag_from_c(tb);
    ta = mm_ff(FXpa, FR);                      // Xp * R^T
    tb = mm_ff(FXpb, FR);
    Frag Fta = frag_from_c(ta);
    Frag Ftb = frag_from_c(tb);
    ta = mm_ff(FR, Fta);                       // Xr = R Xp R^T
    tb = mm_ff(FR, Ftb);
    const Frag FXra = frag_from_c(ta);         // symmetric
    const Frag FXrb = frag_from_c(tb);
    ta = mm_ff(FXra, FBs);                     // Xr * Bs
    tb = mm_ff(FXrb, FBs);
    Fta = frag_from_c(ta);
    Ftb = frag_from_c(tb);
    ta = mm_ff(FBs, Fta);                      // out = Bs Xr Bs
    tb = mm_ff(FBs, Ftb);
#pragma unroll
    for (int i = 0; i < 16; ++i) {
      const int row = (i & 3) + 8 * (i >> 2) + 4 * h;
      ga[row * 32 + ccol] = ta[i];
    }
    if (dual) {
#pragma unroll
      for (int i = 0; i < 16; ++i) {
        const int row = (i & 3) + 8 * (i >> 2) + 4 * h;
        gb[row * 32 + ccol] = tb[i];
      }
    }
  }
}

// ------------------------------- launcher ----------------------------------

extern "C" void kernel_launch(void* const* d_in, const int* in_sizes, int n_in,
                              void* d_out, int out_size, void* d_ws, size_t ws_size,
                              hipStream_t stream) {
  const float* X  = (const float*)d_in[0];
  const int*   ds = (const int*)d_in[1];
  const float* R  = (const float*)d_in[2];
  const float* B  = (const float*)d_in[3];
  float* out = (float*)d_out;
  float* ws  = (float*)d_ws;
  const int N = in_sizes[1];
  const int q = in_sizes[0] / (N * 1024);
  const int D = in_sizes[2] / 1024;
  (void)n_in; (void)out_size; (void)ws_size;

  // d_out doubles as an 8 MB reduction scratch until k5 overwrites it.
  float* scr = out;

  hipMemsetAsync(d_ws, 0, WS_ZERO * sizeof(float), stream);
  k1_xsum   <<<dim3((N + 3) / 4), dim3(256), 0, stream>>>(X, scr, N, q);
  kred      <<<dim3(8 * D * 4), dim3(256), 0, stream>>>(ds, scr, ws + WS_G0SUM, N, D);
  k2_g0funcs<<<dim3(D), dim3(128), 0, stream>>>(ws, ds, B, N, q);
  k3_gt     <<<dim3(N), dim3(256), 0, stream>>>(X, ds, ws, scr, q);
  kred      <<<dim3(8 * D * 4), dim3(256), 0, stream>>>(ds, scr, ws + WS_GTSUM, N, D);
  k4_mean   <<<dim3(D), dim3(64),  0, stream>>>(ws, q);
  k5_logxc  <<<dim3(N), dim3(256), 0, stream>>>(X, ds, ws, out, q);
  k6_p      <<<dim3(1), dim3(64),  0, stream>>>(ds, ws, N, q, D);
  k7_out    <<<dim3(N), dim3(256), 0, stream>>>(ds, ws, R, out, q);
}

// Round 6
// 559.029 us; speedup vs baseline: 1.9921x; 1.1984x over previous
//
#include <hip/hip_runtime.h>

// ---------------------------------------------------------------------------
// DomainGeneralisationBN (SPD batchnorm) — R9: hi-only NS intermediates +
// MFMA-ized k2/k4.
// rocprof R8: k5=130us (MfmaUtil 34%, VALUBusy 67%) -> VALU-count bound;
// k2/k4 (D=4 blocks) still fp32-VALU serial chains (~50-75us of idle GPU).
// Changes:
//  * logm2: V/X1/X2/X3 + NS1-square packed hi-only bf16 (28 vs 56 insts;
//    2/4-MFMA products vs 6).  Each NS step uses the ROUNDED Xr consistently
//    (C=-2Xr, s=Xr^2) so rounding is self-corrected quadratically; s2/s3 and
//    Q/S2/Gregory stay split -> E(Q)~(4e-3)^2, L error ~1e-4 (negligible).
//    MFMA/matrix 84->68, pack VALU -11%.
//  * k2/k4 rewritten on the in-register Frag machinery (no LDS, no fp32 mm);
//    k4 exp = deg-10 pair-Horner (10->5 mm); same polynomials.
// Reduction scheme (R4) unchanged: k1_xsum+kred, k3 LDS-merge+kred, VPART.
// ---------------------------------------------------------------------------

// workspace layout (float offsets)
#define WS_G0SUM 0
#define WS_GTSUM 4096
#define WS_VAR   8192
#define WS_CNT   8196
#define WS_P     8200
#define WS_G0SQ  8208
#define WS_G0ISQ 12304
#define WS_GISQ  16400
#define WS_BSQ   20496
#define WS_VPART 24592      // N floats of per-block variance partials
#define WS_ZERO  8208

// (P+I)^-1 NS init: X0 = AL*I + BE*M, Chebyshev on eigs(M) in [1.15, 8]
#define LOG_AL 0.6073551f
#define LOG_BE (-0.0663776f)
#define LOG_RAB (-9.1500001f)   // AL/BE

typedef __attribute__((ext_vector_type(8)))  short bf16x8;
typedef __attribute__((ext_vector_type(16))) float f32x16;

union FragU { uint4 u; bf16x8 v; };

struct Frag  { bf16x8 h0, h1, l0, l1; };
struct FragH { bf16x8 h0, h1; };

__device__ __forceinline__ float wsum(float v) {
#pragma unroll
  for (int o = 32; o > 0; o >>= 1) v += __shfl_xor(v, o, 64);
  return v;
}

// ---------------- MFMA helpers ----------------

// C = A*B + Cin, split x split (3-term scheme), 6 MFMA.
__device__ __forceinline__ f32x16 mm_ffc(const Frag A, const Frag B,
                                         const f32x16 cin) {
  f32x16 c = cin;
  c = __builtin_amdgcn_mfma_f32_32x32x16_bf16(A.h0, B.h0, c, 0, 0, 0);
  c = __builtin_amdgcn_mfma_f32_32x32x16_bf16(A.h0, B.l0, c, 0, 0, 0);
  c = __builtin_amdgcn_mfma_f32_32x32x16_bf16(A.l0, B.h0, c, 0, 0, 0);
  c = __builtin_amdgcn_mfma_f32_32x32x16_bf16(A.h1, B.h1, c, 0, 0, 0);
  c = __builtin_amdgcn_mfma_f32_32x32x16_bf16(A.h1, B.l1, c, 0, 0, 0);
  c = __builtin_amdgcn_mfma_f32_32x32x16_bf16(A.l1, B.h1, c, 0, 0, 0);
  return c;
}

__device__ __forceinline__ f32x16 mm_ff(const Frag A, const Frag B) {
  f32x16 z;
#pragma unroll
  for (int i = 0; i < 16; ++i) z[i] = 0.f;
  return mm_ffc(A, B, z);
}

// hi x hi (exact product of rounded values), 2 MFMA.
__device__ __forceinline__ f32x16 mm_hh(const FragH A, const FragH B) {
  f32x16 c;
#pragma unroll
  for (int i = 0; i < 16; ++i) c[i] = 0.f;
  c = __builtin_amdgcn_mfma_f32_32x32x16_bf16(A.h0, B.h0, c, 0, 0, 0);
  c = __builtin_amdgcn_mfma_f32_32x32x16_bf16(A.h1, B.h1, c, 0, 0, 0);
  return c;
}

// split x hi, 4 MFMA.
__device__ __forceinline__ f32x16 mm_shc(const Frag A, const FragH B,
                                         const f32x16 cin) {
  f32x16 c = cin;
  c = __builtin_amdgcn_mfma_f32_32x32x16_bf16(A.h0, B.h0, c, 0, 0, 0);
  c = __builtin_amdgcn_mfma_f32_32x32x16_bf16(A.l0, B.h0, c, 0, 0, 0);
  c = __builtin_amdgcn_mfma_f32_32x32x16_bf16(A.h1, B.h1, c, 0, 0, 0);
  c = __builtin_amdgcn_mfma_f32_32x32x16_bf16(A.l1, B.h1, c, 0, 0, 0);
  return c;
}

// pack (x0,x1) -> hi word [bf16(x1)|bf16(x0)] (RTNE) + lo residual word.
__device__ __forceinline__ void packpair(float x0, float x1,
                                         unsigned& hw, unsigned& lw) {
  unsigned h;
  asm("v_cvt_pk_bf16_f32 %0, %1, %2" : "=v"(h) : "v"(x0), "v"(x1));
  const float h0 = __uint_as_float(h << 16);
  const float h1 = __uint_as_float(h & 0xFFFF0000u);
  const float l0 = x0 - h0;
  const float l1 = x1 - h1;
  asm("v_cvt_pk_bf16_f32 %0, %1, %2" : "=v"(lw) : "v"(l0), "v"(l1));
  hw = h;
}

__device__ __forceinline__ void plswap2(unsigned a, unsigned b,
                                        unsigned& r0, unsigned& r1) {
  auto p = __builtin_amdgcn_permlane32_swap(a, b, false, false);
  r0 = p[0]; r1 = p[1];
}

// C-regs (col=ccol, rows (i&3)+8*(i>>2)+4h) -> split-bf16 fragment of the
// SAME matrix: valid B-operand always; valid A-operand iff symmetric.
__device__ __forceinline__ Frag frag_from_c(const f32x16 c) {
  unsigned hw[8], lw[8];
#pragma unroll
  for (int g = 0; g < 4; ++g) {
    packpair(c[4*g+0], c[4*g+1], hw[2*g+0], lw[2*g+0]);
    packpair(c[4*g+2], c[4*g+3], hw[2*g+1], lw[2*g+1]);
  }
  unsigned w0, w1, w2, w3;
  FragU A, B, C, D;
  plswap2(hw[0], hw[2], w0, w2);
  plswap2(hw[1], hw[3], w1, w3);
  A.u = make_uint4(w0, w1, w2, w3);          // h0 : rows h*8..h*8+7
  plswap2(hw[4], hw[6], w0, w2);
  plswap2(hw[5], hw[7], w1, w3);
  B.u = make_uint4(w0, w1, w2, w3);          // h1 : rows 16+h*8..
  plswap2(lw[0], lw[2], w0, w2);
  plswap2(lw[1], lw[3], w1, w3);
  C.u = make_uint4(w0, w1, w2, w3);          // l0
  plswap2(lw[4], lw[6], w0, w2);
  plswap2(lw[5], lw[7], w1, w3);
  D.u = make_uint4(w0, w1, w2, w3);          // l1
  Frag f; f.h0 = A.v; f.h1 = B.v; f.l0 = C.v; f.l1 = D.v;
  return f;
}

__device__ __forceinline__ Frag frag_from_c_neg(const f32x16 c) {
  f32x16 n;
#pragma unroll
  for (int i = 0; i < 16; ++i) n[i] = -c[i];
  return frag_from_c(n);
}

// hi-only pack; also returns the ROUNDED values (C-layout) for consistent
// self-correcting NS steps.
__device__ __forceinline__ FragH fragh_from_c(const f32x16 c, f32x16& cr) {
  unsigned hw[8];
#pragma unroll
  for (int g = 0; g < 4; ++g) {
    unsigned w0, w1;
    asm("v_cvt_pk_bf16_f32 %0, %1, %2" : "=v"(w0) : "v"(c[4*g+0]), "v"(c[4*g+1]));
    asm("v_cvt_pk_bf16_f32 %0, %1, %2" : "=v"(w1) : "v"(c[4*g+2]), "v"(c[4*g+3]));
    cr[4*g+0] = __uint_as_float(w0 << 16);
    cr[4*g+1] = __uint_as_float(w0 & 0xFFFF0000u);
    cr[4*g+2] = __uint_as_float(w1 << 16);
    cr[4*g+3] = __uint_as_float(w1 & 0xFFFF0000u);
    hw[2*g] = w0; hw[2*g+1] = w1;
  }
  unsigned a0, a1, a2, a3, b0, b1, b2, b3;
  plswap2(hw[0], hw[2], a0, a2);
  plswap2(hw[1], hw[3], a1, a3);
  plswap2(hw[4], hw[6], b0, b2);
  plswap2(hw[5], hw[7], b1, b3);
  FragU A, B;
  A.u = make_uint4(a0, a1, a2, a3);
  B.u = make_uint4(b0, b1, b2, b3);
  FragH f; f.h0 = A.v; f.h1 = B.v;
  return f;
}

// hi-only pack without rounded-value output (for squares).
__device__ __forceinline__ FragH fragh_only(const f32x16 c) {
  unsigned hw[8];
#pragma unroll
  for (int g = 0; g < 4; ++g) {
    asm("v_cvt_pk_bf16_f32 %0, %1, %2" : "=v"(hw[2*g])   : "v"(c[4*g+0]), "v"(c[4*g+1]));
    asm("v_cvt_pk_bf16_f32 %0, %1, %2" : "=v"(hw[2*g+1]) : "v"(c[4*g+2]), "v"(c[4*g+3]));
  }
  unsigned a0, a1, a2, a3, b0, b1, b2, b3;
  plswap2(hw[0], hw[2], a0, a2);
  plswap2(hw[1], hw[3], a1, a3);
  plswap2(hw[4], hw[6], b0, b2);
  plswap2(hw[5], hw[7], b1, b3);
  FragU A, B;
  A.u = make_uint4(a0, a1, a2, a3);
  B.u = make_uint4(b0, b1, b2, b3);
  FragH f; f.h0 = A.v; f.h1 = B.v;
  return f;
}

// 32x32 f32 row-major global matrix M -> split fragment.
__device__ __forceinline__ Frag frag_rowmajor(const float* __restrict__ g,
                                              int lane) {
  const int r = lane & 31, h = lane >> 5;
  const float* p = g + r * 32 + h * 8;
  const float4 v0 = *(const float4*)(p);
  const float4 v1 = *(const float4*)(p + 4);
  const float4 v2 = *(const float4*)(p + 16);
  const float4 v3 = *(const float4*)(p + 20);
  unsigned hw[8], lw[8];
  packpair(v0.x, v0.y, hw[0], lw[0]);
  packpair(v0.z, v0.w, hw[1], lw[1]);
  packpair(v1.x, v1.y, hw[2], lw[2]);
  packpair(v1.z, v1.w, hw[3], lw[3]);
  packpair(v2.x, v2.y, hw[4], lw[4]);
  packpair(v2.z, v2.w, hw[5], lw[5]);
  packpair(v3.x, v3.y, hw[6], lw[6]);
  packpair(v3.z, v3.w, hw[7], lw[7]);
  FragU A, B, C, D;
  A.u = make_uint4(hw[0], hw[1], hw[2], hw[3]);
  B.u = make_uint4(hw[4], hw[5], hw[6], hw[7]);
  C.u = make_uint4(lw[0], lw[1], lw[2], lw[3]);
  D.u = make_uint4(lw[4], lw[5], lw[6], lw[7]);
  Frag f; f.h0 = A.v; f.h1 = B.v; f.l0 = C.v; f.l1 = D.v;
  return f;
}

__device__ __forceinline__ void addID(f32x16& c, float v, const f32x16 dm) {
#pragma unroll
  for (int i = 0; i < 16; ++i) c[i] = fmaf(v, dm[i], c[i]);
}

// C-layout global load/store (row = (i&3)+8*(i>>2)+4h, col = ccol).
__device__ __forceinline__ void ldg_c(const float* __restrict__ g, f32x16& c,
                                      int ccol, int h) {
#pragma unroll
  for (int i = 0; i < 16; ++i) {
    const int row = (i & 3) + 8 * (i >> 2) + 4 * h;
    c[i] = g[row * 32 + ccol];
  }
}
__device__ __forceinline__ void stg_c(float* __restrict__ g, const f32x16 c,
                                      int ccol, int h) {
#pragma unroll
  for (int i = 0; i < 16; ++i) {
    const int row = (i & 3) + 8 * (i >> 2) + 4 * h;
    g[row * 32 + ccol] = c[i];
  }
}

// Dual logm: input Ma/Mb = Gi X Gi + I.  Output uf with L = -4*uf.
// NS inverse (Chebyshev init + 3 iters; V/X packs hi-only, self-corrected on
// the ROUNDED values), Cayley S=I-2Q, Gregory deg-8 pair-Horner in y^2.
__device__ __forceinline__ void logm2(const f32x16 Ma, const f32x16 Mb,
                                      f32x16& ufa, f32x16& ufb,
                                      const f32x16 dm) {
  const Frag FMa = frag_from_c(Ma);
  const Frag FMb = frag_from_c(Mb);
  f32x16 ca, cb, ta, tb;
  // t = M^2 + (AL/BE) M ; V = 2I - BE*t
#pragma unroll
  for (int i = 0; i < 16; ++i) { ca[i] = LOG_RAB * Ma[i]; cb[i] = LOG_RAB * Mb[i]; }
  ta = mm_ffc(FMa, FMa, ca);
  tb = mm_ffc(FMb, FMb, cb);
  f32x16 Va, Vb;
#pragma unroll
  for (int i = 0; i < 16; ++i) {
    Va[i] = fmaf(-LOG_BE, ta[i], 2.f * dm[i]);
    Vb[i] = fmaf(-LOG_BE, tb[i], 2.f * dm[i]);
  }
  f32x16 Xra, Xrb;                            // rounded-value carriers
  const FragH FVa = fragh_from_c(Va, Xra);    // Xra = Vr for now
  const FragH FVb = fragh_from_c(Vb, Xrb);
  // X1 = BE*(M*Vr + (AL/BE)*Vr)
#pragma unroll
  for (int i = 0; i < 16; ++i) { ca[i] = LOG_RAB * Xra[i]; cb[i] = LOG_RAB * Xrb[i]; }
  ta = mm_shc(FMa, FVa, ca);
  tb = mm_shc(FMb, FVb, cb);
  f32x16 Xa, Xb;
#pragma unroll
  for (int i = 0; i < 16; ++i) { Xa[i] = LOG_BE * ta[i]; Xb[i] = LOG_BE * tb[i]; }
  FragH FXa = fragh_from_c(Xa, Xra);
  FragH FXb = fragh_from_c(Xb, Xrb);
  // NS1 (hi-only square): X2 = 2*X1r - M*round(X1r^2)
  {
    f32x16 sa = mm_hh(FXa, FXa);
    f32x16 sb = mm_hh(FXb, FXb);
    const FragH Fsa = fragh_only(sa);
    const FragH Fsb = fragh_only(sb);
#pragma unroll
    for (int i = 0; i < 16; ++i) { ca[i] = -2.f * Xra[i]; cb[i] = -2.f * Xrb[i]; }
    ta = mm_shc(FMa, Fsa, ca);               // -X2
    tb = mm_shc(FMb, Fsb, cb);
#pragma unroll
    for (int i = 0; i < 16; ++i) { Xa[i] = -ta[i]; Xb[i] = -tb[i]; }
    FXa = fragh_from_c(Xa, Xra);
    FXb = fragh_from_c(Xb, Xrb);
  }
  // NS2 (split square): X3 = 2*X2r - M*split(X2r^2)
  {
    f32x16 sa = mm_hh(FXa, FXa);
    f32x16 sb = mm_hh(FXb, FXb);
    const Frag Fsa = frag_from_c(sa);
    const Frag Fsb = frag_from_c(sb);
#pragma unroll
    for (int i = 0; i < 16; ++i) { ca[i] = -2.f * Xra[i]; cb[i] = -2.f * Xrb[i]; }
    ta = mm_ffc(FMa, Fsa, ca);               // -X3
    tb = mm_ffc(FMb, Fsb, cb);
#pragma unroll
    for (int i = 0; i < 16; ++i) { Xa[i] = -ta[i]; Xb[i] = -tb[i]; }
    FXa = fragh_from_c(Xa, Xra);
    FXb = fragh_from_c(Xb, Xrb);
  }
  // NS3 (split): Q = 2*X3r - M*split(X3r^2)
  {
    f32x16 sa = mm_hh(FXa, FXa);
    f32x16 sb = mm_hh(FXb, FXb);
    const Frag Fsa = frag_from_c(sa);
    const Frag Fsb = frag_from_c(sb);
#pragma unroll
    for (int i = 0; i < 16; ++i) { ca[i] = -2.f * Xra[i]; cb[i] = -2.f * Xrb[i]; }
    ta = mm_ffc(FMa, Fsa, ca);               // -Q
    tb = mm_ffc(FMb, Fsb, cb);
  }
  const Frag FQa = frag_from_c_neg(ta);      // Q
  const Frag FQb = frag_from_c_neg(tb);
  // S2 = 4*(Q^2 - Q) + I ; Q^2 - Q via C = -Q (= ta)
  f32x16 S2a, S2b;
  {
    f32x16 va = mm_ffc(FQa, FQa, ta);
    f32x16 vb = mm_ffc(FQb, FQb, tb);
#pragma unroll
    for (int i = 0; i < 16; ++i) {
      S2a[i] = fmaf(4.f, va[i], dm[i]);
      S2b[i] = fmaf(4.f, vb[i], dm[i]);
    }
  }
  const Frag Fya = frag_from_c(S2a);
  const Frag Fyb = frag_from_c(S2b);
  f32x16 wa = mm_ff(Fya, Fya);               // w = y^2
  f32x16 wb = mm_ff(Fyb, Fyb);
  const Frag Fwa = frag_from_c(wa);
  const Frag Fwb = frag_from_c(wb);
  // Gregory deg-8 pair-Horner in w
  f32x16 Ga, Gb;
#pragma unroll
  for (int i = 0; i < 16; ++i) {
    Ga[i] = fmaf(1.f/17.f, wa[i], (1.f/15.f) * S2a[i]);
    Gb[i] = fmaf(1.f/17.f, wb[i], (1.f/15.f) * S2b[i]);
  }
  addID(Ga, 1.f/13.f, dm);  addID(Gb, 1.f/13.f, dm);
  Frag FGa = frag_from_c(Ga);
  Frag FGb = frag_from_c(Gb);
#pragma unroll
  for (int s = 0; s < 3; ++s) {
    const float chi = (s == 0) ? (1.f/11.f) : (s == 1) ? (1.f/7.f) : (1.f/3.f);
    const float clo = (s == 0) ? (1.f/9.f)  : (s == 1) ? (1.f/5.f) : 1.f;
#pragma unroll
    for (int i = 0; i < 16; ++i) { ca[i] = chi * S2a[i]; cb[i] = chi * S2b[i]; }
    Ga = mm_ffc(FGa, Fwa, ca);
    Gb = mm_ffc(FGb, Fwb, cb);
    addID(Ga, clo, dm);  addID(Gb, clo, dm);
    FGa = frag_from_c(Ga);
    FGb = frag_from_c(Gb);
  }
  // uf = Q*G - 0.5*G ; L = -4*uf
#pragma unroll
  for (int i = 0; i < 16; ++i) { ca[i] = -0.5f * Ga[i]; cb[i] = -0.5f * Gb[i]; }
  ufa = mm_ffc(FQa, FGa, ca);
  ufb = mm_ffc(FQb, FGb, cb);
}

// In-register coupled NS sqrt/invsqrt (13 iters): A -> Y*sqrt(th)=A^{1/2},
// Z/sqrt(th)=A^{-1/2}.  All iterates symmetric (polynomials in A).
__device__ __forceinline__ void wave_sqrtinv_reg(const f32x16 A,
                                                 f32x16& Ysq, f32x16& Zis,
                                                 const f32x16 dm) {
  float ss = 0.f;
#pragma unroll
  for (int i = 0; i < 16; ++i) ss += A[i] * A[i];
  const float th = sqrtf(wsum(ss));
  const float inv = 1.f / th;
  f32x16 Y, Z;
#pragma unroll
  for (int i = 0; i < 16; ++i) { Y[i] = A[i] * inv; Z[i] = dm[i]; }
  Frag FY = frag_from_c(Y);
  Frag FZ = frag_from_c(Z);
#pragma unroll 1
  for (int it = 0; it < 13; ++it) {
    f32x16 W = mm_ff(FZ, FY);                // Z*Y
    f32x16 T;
#pragma unroll
    for (int i = 0; i < 16; ++i) T[i] = fmaf(-0.5f, W[i], 1.5f * dm[i]);
    const Frag FT = frag_from_c(T);
    Y = mm_ff(FY, FT);                       // Y*T
    Z = mm_ff(FT, FZ);                       // T*Z
    FY = frag_from_c(Y);
    FZ = frag_from_c(Z);
  }
  const float sth = sqrtf(th), isth = 1.f / sth;
#pragma unroll
  for (int i = 0; i < 16; ++i) { Ysq[i] = Y[i] * sth; Zis[i] = Z[i] * isth; }
}

// ------------------------------- kernels -----------------------------------

// per-n sum over the q matrices, plain stores into scratch (d_out).
__global__ __launch_bounds__(256) void k1_xsum(const float* __restrict__ X,
                                               float* __restrict__ scr,
                                               int N, int q) {
  const int w = threadIdx.x >> 6, lane = threadIdx.x & 63;
  const int n = blockIdx.x * 4 + w;
  if (n >= N) return;
  float acc[16];
#pragma unroll
  for (int i = 0; i < 16; ++i) acc[i] = 0.f;
  const float* base = X + (size_t)n * q * 1024 + lane * 16;
#pragma unroll 4
  for (int j = 0; j < q; ++j) {
    const float* g = base + (size_t)j * 1024;
#pragma unroll
    for (int u = 0; u < 4; ++u) {
      float4 v = *(const float4*)(g + u * 4);
      acc[u*4+0] += v.x; acc[u*4+1] += v.y; acc[u*4+2] += v.z; acc[u*4+3] += v.w;
    }
  }
  float* dst = scr + (size_t)n * 1024 + lane * 16;
#pragma unroll
  for (int u = 0; u < 4; ++u)
    *(float4*)(dst + u * 4) =
        make_float4(acc[u*4+0], acc[u*4+1], acc[u*4+2], acc[u*4+3]);
}

// gather-by-domain reduce: dst[d*1024+e] += sum_{n: ds[n]==d} src[n*1024+e].
__global__ __launch_bounds__(256) void kred(const int* __restrict__ ds,
                                            const float* __restrict__ src,
                                            float* __restrict__ dst,
                                            int N, int D) {
  const int obln = D * 4;
  const int chunk = blockIdx.x / obln;
  const int ob    = blockIdx.x % obln;
  const int out   = ob * 256 + threadIdx.x;
  const int d = out >> 10, e = out & 1023;
  const int cs = (N + 7) >> 3;
  const int n0 = chunk * cs;
  const int n1 = min(N, n0 + cs);
  float acc = 0.f;
#pragma unroll 16
  for (int n = n0; n < n1; ++n) {
    const float v = src[(size_t)n * 1024 + e];
    acc += (ds[n] == d) ? v : 0.f;
  }
  atomicAdd(dst + out, acc);
}

__global__ __launch_bounds__(128) void k2_g0funcs(float* __restrict__ ws,
                                                  const int* __restrict__ ds,
                                                  const float* __restrict__ B,
                                                  int N, int q) {
  const int d = blockIdx.x, tid = threadIdx.x;
  const int w = tid >> 6, lane = tid & 63;
  const int ccol = lane & 31, h = lane >> 5;
  f32x16 dm;
#pragma unroll
  for (int i = 0; i < 16; ++i) {
    const int row = (i & 3) + 8 * (i >> 2) + 4 * h;
    dm[i] = (row == ccol) ? 1.f : 0.f;
  }
  f32x16 A, Y, Z;
  if (w == 0) {
    int cnt = 0;
    for (int i = lane; i < N; i += 64) cnt += (ds[i] == d) ? 1 : 0;
    const float cntf = wsum((float)cnt);
    if (lane == 0) ws[WS_CNT + d] = cntf;
    ldg_c(ws + WS_G0SUM + d * 1024, A, ccol, h);
    const float s = 1.f / ((float)q * cntf);
#pragma unroll
    for (int i = 0; i < 16; ++i) A[i] *= s;
    wave_sqrtinv_reg(A, Y, Z, dm);
    stg_c(ws + WS_G0SQ  + d * 1024, Y, ccol, h);
    stg_c(ws + WS_G0ISQ + d * 1024, Z, ccol, h);
  } else {
    ldg_c(B + d * 1024, A, ccol, h);
    wave_sqrtinv_reg(A, Y, Z, dm);
    stg_c(ws + WS_BSQ + d * 1024, Y, ccol, h);
  }
}

__global__ __launch_bounds__(256, 2) void k3_gt(const float* __restrict__ X,
                                                const int* __restrict__ ds,
                                                const float* __restrict__ ws,
                                                float* __restrict__ scr, int q) {
  __shared__ float RED[3][1024];
  const int n = blockIdx.x, tid = threadIdx.x;
  const int w = tid >> 6, lane = tid & 63;
  const int ccol = lane & 31, h = lane >> 5;
  f32x16 dm;
#pragma unroll
  for (int i = 0; i < 16; ++i) {
    const int row = (i & 3) + 8 * (i >> 2) + 4 * h;
    dm[i] = (row == ccol) ? 1.f : 0.f;
  }
  const int d = ds[n];
  const Frag FGi = frag_rowmajor(ws + WS_G0ISQ + d * 1024, lane);
  f32x16 acc;
#pragma unroll
  for (int i = 0; i < 16; ++i) acc[i] = 0.f;
  const int qw = (q + 3) >> 2;
  const int jbeg = w * qw;
  const int jend = min(q, jbeg + qw);
#pragma unroll 1
  for (int j = jbeg; j < jend; j += 2) {
    const bool dual = (j + 1 < jend);
    const size_t ma = (size_t)n * q + j;
    const size_t mb = dual ? ma + 1 : ma;
    const Frag FXa = frag_rowmajor(X + ma * 1024, lane);   // symmetric
    const Frag FXb = frag_rowmajor(X + mb * 1024, lane);
    f32x16 ua = mm_ff(FXa, FGi);               // X * Gi
    f32x16 ub = mm_ff(FXb, FGi);
    const Frag Fua = frag_from_c(ua);          // B-only use
    const Frag Fub = frag_from_c(ub);
    f32x16 Pa = mm_ffc(FGi, Fua, dm);          // Gi X Gi + I
    f32x16 Pb = mm_ffc(FGi, Fub, dm);
    f32x16 ufa, ufb;
    logm2(Pa, Pb, ufa, ufb, dm);               // L = -4*uf
#pragma unroll
    for (int i = 0; i < 16; ++i) acc[i] = fmaf(-4.f, ufa[i], acc[i]);
    if (dual) {
#pragma unroll
      for (int i = 0; i < 16; ++i) acc[i] = fmaf(-4.f, ufb[i], acc[i]);
    }
  }
  // merge 4 waves via LDS, then ONE hoisted congruence by wave 3:
  // sum_j Gs L_j Gs = Gs (sum_j L_j) Gs
  if (w < 3) {
#pragma unroll
    for (int i = 0; i < 16; ++i) {
      const int row = (i & 3) + 8 * (i >> 2) + 4 * h;
      RED[w][row * 32 + ccol] = acc[i];
    }
  }
  __syncthreads();
  if (w == 3) {
#pragma unroll
    for (int i = 0; i < 16; ++i) {
      const int row = (i & 3) + 8 * (i >> 2) + 4 * h;
      const int e = row * 32 + ccol;
      acc[i] += RED[0][e] + RED[1][e] + RED[2][e];
    }
    const Frag FGs = frag_rowmajor(ws + WS_G0SQ + d * 1024, lane);
    const Frag FA  = frag_from_c(acc);         // symmetric
    f32x16 u = mm_ff(FA, FGs);                 // (sumL) * Gs
    const Frag Fu = frag_from_c(u);
    u = mm_ff(FGs, Fu);                        // Gs (sumL) Gs
    float* g = scr + (size_t)n * 1024;
#pragma unroll
    for (int i = 0; i < 16; ++i) {
      const int row = (i & 3) + 8 * (i >> 2) + 4 * h;
      g[row * 32 + ccol] = u[i];
    }
  }
}

__global__ __launch_bounds__(64) void k4_mean(float* __restrict__ ws, int q) {
  const int d = blockIdx.x, lane = threadIdx.x;
  const int ccol = lane & 31, h = lane >> 5;
  f32x16 dm;
#pragma unroll
  for (int i = 0; i < 16; ++i) {
    const int row = (i & 3) + 8 * (i >> 2) + 4 * h;
    dm[i] = (row == ccol) ? 1.f : 0.f;
  }
  const float cntf = ws[WS_CNT + d];
  f32x16 Gi, GT;
  ldg_c(ws + WS_G0ISQ + d * 1024, Gi, ccol, h);
  ldg_c(ws + WS_GTSUM + d * 1024, GT, ccol, h);
  const float s = 1.f / ((float)q * cntf);
#pragma unroll
  for (int i = 0; i < 16; ++i) GT[i] *= s;
  const Frag FGi = frag_from_c(Gi);
  const Frag FGT = frag_from_c(GT);
  f32x16 u = mm_ff(FGT, FGi);                  // GT*Gi
  Frag Fu = frag_from_c(u);
  f32x16 E = mm_ff(FGi, Fu);                   // E = Gi GT Gi
  // exp(E), deg-10 pair-Horner in w = E^2 (same Taylor polynomial as before)
  const Frag FE = frag_from_c(E);
  f32x16 wm = mm_ff(FE, FE);
  const Frag Fw = frag_from_c(wm);
  f32x16 G;
#pragma unroll
  for (int i = 0; i < 16; ++i)
    G[i] = fmaf(2.7557319e-7f, wm[i], 2.7557319e-6f * E[i]);  // 1/10!, 1/9!
  addID(G, 1.f/40320.f, dm);                                  // 1/8!
  Frag FG = frag_from_c(G);
#pragma unroll
  for (int sstep = 0; sstep < 4; ++sstep) {
    const float chi = (sstep == 0) ? (1.f/5040.f) : (sstep == 1) ? (1.f/120.f)
                     : (sstep == 2) ? (1.f/6.f) : 1.f;
    const float clo = (sstep == 0) ? (1.f/720.f) : (sstep == 1) ? (1.f/24.f)
                     : (sstep == 2) ? 0.5f : 1.f;
    f32x16 cc;
#pragma unroll
    for (int i = 0; i < 16; ++i) cc[i] = chi * E[i];
    G = mm_ffc(FG, Fw, cc);
    addID(G, clo, dm);
    FG = frag_from_c(G);
  }
  // Gm = Gs * exp(E) * Gs
  f32x16 Gs;
  ldg_c(ws + WS_G0SQ + d * 1024, Gs, ccol, h);
  const Frag FGs = frag_from_c(Gs);
  u = mm_ff(FG, FGs);                          // H*Gs  (H symmetric)
  Fu = frag_from_c(u);
  f32x16 Gm = mm_ff(FGs, Fu);                  // Gs H Gs
  f32x16 Y, Z;
  wave_sqrtinv_reg(Gm, Y, Z, dm);
  stg_c(ws + WS_GISQ + d * 1024, Z, ccol, h);
}

__global__ __launch_bounds__(256, 2) void k5_logxc(const float* __restrict__ X,
                                                   const int* __restrict__ ds,
                                                   float* __restrict__ ws,
                                                   float* __restrict__ Lout, int q) {
  __shared__ float V4[4];
  const int n = blockIdx.x, tid = threadIdx.x;
  const int w = tid >> 6, lane = tid & 63;
  const int ccol = lane & 31, h = lane >> 5;
  f32x16 dm;
#pragma unroll
  for (int i = 0; i < 16; ++i) {
    const int row = (i & 3) + 8 * (i >> 2) + 4 * h;
    dm[i] = (row == ccol) ? 1.f : 0.f;
  }
  const int d = ds[n];
  const Frag FGi = frag_rowmajor(ws + WS_GISQ + d * 1024, lane);
  float vacc = 0.f;
  const int qw = (q + 3) >> 2;
  const int jbeg = w * qw;
  const int jend = min(q, jbeg + qw);
#pragma unroll 1
  for (int j = jbeg; j < jend; j += 2) {
    const bool dual = (j + 1 < jend);
    const size_t ma = (size_t)n * q + j;
    const size_t mb = dual ? ma + 1 : ma;
    const Frag FXa = frag_rowmajor(X + ma * 1024, lane);
    const Frag FXb = frag_rowmajor(X + mb * 1024, lane);
    f32x16 ua = mm_ff(FXa, FGi);               // X * Gi
    f32x16 ub = mm_ff(FXb, FGi);
    const Frag Fua = frag_from_c(ua);
    const Frag Fub = frag_from_c(ub);
    f32x16 Pa = mm_ffc(FGi, Fua, dm);          // Gi X Gi + I
    f32x16 Pb = mm_ffc(FGi, Fub, dm);
    f32x16 ufa, ufb;
    logm2(Pa, Pb, ufa, ufb, dm);               // L = -4*uf
    float sq = 0.f;
#pragma unroll
    for (int i = 0; i < 16; ++i) sq += ufa[i] * ufa[i];
    vacc += sq;
    float* ga = Lout + ma * 1024;
#pragma unroll
    for (int i = 0; i < 16; ++i) {
      const int row = (i & 3) + 8 * (i >> 2) + 4 * h;
      ga[row * 32 + ccol] = -4.f * ufa[i];
    }
    if (dual) {
      float sqb = 0.f;
#pragma unroll
      for (int i = 0; i < 16; ++i) sqb += ufb[i] * ufb[i];
      vacc += sqb;
      float* gb = Lout + mb * 1024;
#pragma unroll
      for (int i = 0; i < 16; ++i) {
        const int row = (i & 3) + 8 * (i >> 2) + 4 * h;
        gb[row * 32 + ccol] = -4.f * ufb[i];
      }
    }
  }
  vacc = wsum(vacc * 16.f);                    // ||L||^2 = 16*||uf||^2
  if (lane == 0) V4[w] = vacc;
  __syncthreads();
  if (tid == 0) ws[WS_VPART + n] = V4[0] + V4[1] + V4[2] + V4[3];
}

__global__ __launch_bounds__(64) void k6_p(const int* __restrict__ ds,
                                           float* __restrict__ ws,
                                           int N, int q, int D) {
  const int lane = threadIdx.x;
  float a0 = 0.f, a1 = 0.f, a2 = 0.f, a3 = 0.f;
  for (int n = lane; n < N; n += 64) {
    const int d = ds[n];
    const float v = ws[WS_VPART + n];
    a0 += (d == 0) ? v : 0.f;
    a1 += (d == 1) ? v : 0.f;
    a2 += (d == 2) ? v : 0.f;
    a3 += (d == 3) ? v : 0.f;
  }
  a0 = wsum(a0); a1 = wsum(a1); a2 = wsum(a2); a3 = wsum(a3);
  if (lane < D) {
    const float var0 = (lane == 0) ? a0 : (lane == 1) ? a1 : (lane == 2) ? a2 : a3;
    const float cntf = ws[WS_CNT + lane];
    const float var = var0 / ((float)q * cntf);
    ws[WS_P + lane] = sqrtf(1.f / (var + 1e-5f));
  }
}

__global__ __launch_bounds__(256, 2) void k7_out(const int* __restrict__ ds,
                                                 const float* __restrict__ ws,
                                                 const float* __restrict__ R,
                                                 float* __restrict__ io, int q) {
  const int n = blockIdx.x, tid = threadIdx.x;
  const int w = tid >> 6, lane = tid & 63;
  const int ccol = lane & 31, h = lane >> 5;
  f32x16 dm;
#pragma unroll
  for (int i = 0; i < 16; ++i) {
    const int row = (i & 3) + 8 * (i >> 2) + 4 * h;
    dm[i] = (row == ccol) ? 1.f : 0.f;
  }
  const int d = ds[n];
  const Frag FR  = frag_rowmajor(R + d * 1024, lane);        // A of R / B of R^T
  const Frag FBs = frag_rowmajor(ws + WS_BSQ + d * 1024, lane);
  const float ph = 0.5f * ws[WS_P + d];
  // Taylor coeffs of exp(ph*L), deg 10
  float coef[11];
  coef[0] = 1.f;
  coef[1] = ph;
  coef[2] = coef[1] * ph * 0.5f;
  coef[3] = coef[2] * ph * (1.f / 3.f);
  coef[4] = coef[3] * ph * 0.25f;
  coef[5] = coef[4] * ph * 0.2f;
  coef[6] = coef[5] * ph * (1.f / 6.f);
  coef[7] = coef[6] * ph * (1.f / 7.f);
  coef[8] = coef[7] * ph * 0.125f;
  coef[9] = coef[8] * ph * (1.f / 9.f);
  coef[10] = coef[9] * ph * 0.1f;
  const int qw = (q + 3) >> 2;
  const int jbeg = w * qw;
  const int jend = min(q, jbeg + qw);
#pragma unroll 1
  for (int j = jbeg; j < jend; j += 2) {
    const bool dual = (j + 1 < jend);
    const size_t ma = (size_t)n * q + j;
    const size_t mb = dual ? ma + 1 : ma;
    float* ga = io + ma * 1024;
    float* gb = io + mb * 1024;
    f32x16 Lca, Lcb;
#pragma unroll
    for (int i = 0; i < 16; ++i) {
      const int row = (i & 3) + 8 * (i >> 2) + 4 * h;
      Lca[i] = ga[row * 32 + ccol];
      Lcb[i] = gb[row * 32 + ccol];
    }
    const Frag FLa = frag_from_c(Lca);         // symmetric
    const Frag FLb = frag_from_c(Lcb);
    f32x16 ta = mm_ff(FLa, FLa);               // wmat = L^2
    f32x16 tb = mm_ff(FLb, FLb);
    const Frag Fwa = frag_from_c(ta);
    const Frag Fwb = frag_from_c(tb);
    f32x16 Ga, Gb;
#pragma unroll
    for (int i = 0; i < 16; ++i) {
      Ga[i] = fmaf(coef[10], ta[i], coef[9] * Lca[i]);
      Gb[i] = fmaf(coef[10], tb[i], coef[9] * Lcb[i]);
    }
    addID(Ga, coef[8], dm);  addID(Gb, coef[8], dm);
    Frag FGa = frag_from_c(Ga);
    Frag FGb = frag_from_c(Gb);
#pragma unroll
    for (int kk = 7; kk >= 1; kk -= 2) {       // full unroll: coef idx constant
      f32x16 cca, ccb;
#pragma unroll
      for (int i = 0; i < 16; ++i) {
        cca[i] = coef[kk] * Lca[i];
        ccb[i] = coef[kk] * Lcb[i];
      }
      Ga = mm_ffc(FGa, Fwa, cca);
      Gb = mm_ffc(FGb, Fwb, ccb);
      addID(Ga, coef[kk - 1], dm);  addID(Gb, coef[kk - 1], dm);
      FGa = frag_from_c(Ga);
      FGb = frag_from_c(Gb);
    }
    ta = mm_ff(FGa, FGa);                      // Xp = H^2 = exp(p L)
    tb = mm_ff(FGb, FGb);
    const Frag FXpa = frag_from_c(ta);         // symmetric
    const Frag FXpb = frag_from_c(tb);
    ta = mm_ff(FXpa, FR);                      // Xp * R^T
    tb = mm_ff(FXpb, FR);
    Frag Fta = frag_from_c(ta);
    Frag Ftb = frag_from_c(tb);
    ta = mm_ff(FR, Fta);                       // Xr = R Xp R^T
    tb = mm_ff(FR, Ftb);
    const Frag FXra = frag_from_c(ta);         // symmetric
    const Frag FXrb = frag_from_c(tb);
    ta = mm_ff(FXra, FBs);                     // Xr * Bs
    tb = mm_ff(FXrb, FBs);
    Fta = frag_from_c(ta);
    Ftb = frag_from_c(tb);
    ta = mm_ff(FBs, Fta);                      // out = Bs Xr Bs
    tb = mm_ff(FBs, Ftb);
#pragma unroll
    for (int i = 0; i < 16; ++i) {
      const int row = (i & 3) + 8 * (i >> 2) + 4 * h;
      ga[row * 32 + ccol] = ta[i];
    }
    if (dual) {
#pragma unroll
      for (int i = 0; i < 16; ++i) {
        const int row = (i & 3) + 8 * (i >> 2) + 4 * h;
        gb[row * 32 + ccol] = tb[i];
      }
    }
  }
}

// ------------------------------- launcher ----------------------------------

extern "C" void kernel_launch(void* const* d_in, const int* in_sizes, int n_in,
                              void* d_out, int out_size, void* d_ws, size_t ws_size,
                              hipStream_t stream) {
  const float* X  = (const float*)d_in[0];
  const int*   ds = (const int*)d_in[1];
  const float* R  = (const float*)d_in[2];
  const float* B  = (const float*)d_in[3];
  float* out = (float*)d_out;
  float* ws  = (float*)d_ws;
  const int N = in_sizes[1];
  const int q = in_sizes[0] / (N * 1024);
  const int D = in_sizes[2] / 1024;
  (void)n_in; (void)out_size; (void)ws_size;

  // d_out doubles as an 8 MB reduction scratch until k5 overwrites it.
  float* scr = out;

  hipMemsetAsync(d_ws, 0, WS_ZERO * sizeof(float), stream);
  k1_xsum   <<<dim3((N + 3) / 4), dim3(256), 0, stream>>>(X, scr, N, q);
  kred      <<<dim3(8 * D * 4), dim3(256), 0, stream>>>(ds, scr, ws + WS_G0SUM, N, D);
  k2_g0funcs<<<dim3(D), dim3(128), 0, stream>>>(ws, ds, B, N, q);
  k3_gt     <<<dim3(N), dim3(256), 0, stream>>>(X, ds, ws, scr, q);
  kred      <<<dim3(8 * D * 4), dim3(256), 0, stream>>>(ds, scr, ws + WS_GTSUM, N, D);
  k4_mean   <<<dim3(D), dim3(64),  0, stream>>>(ws, q);
  k5_logxc  <<<dim3(N), dim3(256), 0, stream>>>(X, ds, ws, out, q);
  k6_p      <<<dim3(1), dim3(64),  0, stream>>>(ds, ws, N, q, D);
  k7_out    <<<dim3(N), dim3(256), 0, stream>>>(ds, ws, R, out, q);
}

// Round 7
// 525.276 us; speedup vs baseline: 2.1201x; 1.0643x over previous
//
#include <hip/hip_runtime.h>

// ---------------------------------------------------------------------------
// DomainGeneralisationBN (SPD batchnorm) — R10: W-merged output congruence,
// direct exp(pL), hi-only NS2/w, parallel k1.
// rocprof R9: k5=115us (VALU 68% + MFMA 32% ~ saturated issue).  Changes:
//  * logm2: NS2 square hi-only (only final-iteration roundings survive -> Q
//    err 3e-5->4e-5); Gregory w=S2^2 hi-only B-operand (mm_shc, L err +3e-4).
//    68 -> 60 MFMA/matrix.
//  * k7: out = W Xp W^T with W = Bs*R precomputed per-domain in k2 (stored in
//    WS_BSQ); Xp = exp(p*L) directly via deg-9 pair-Horner (||pL||<=1.2,
//    trunc <2e-6) — drops the half-angle squaring.  10->7 mm, 11->8 packs.
//  * k1: one block per n, 4 waves x q/4 matrices + LDS merge (4x waves).
// Reduction scheme (R4) unchanged: k1+kred, k3 LDS-merge+kred, VPART.
// ---------------------------------------------------------------------------

// workspace layout (float offsets)
#define WS_G0SUM 0
#define WS_GTSUM 4096
#define WS_VAR   8192
#define WS_CNT   8196
#define WS_P     8200
#define WS_G0SQ  8208
#define WS_G0ISQ 12304
#define WS_GISQ  16400
#define WS_BSQ   20496      // holds W = Bs*R after k2 (Bs itself not needed)
#define WS_VPART 24592      // N floats of per-block variance partials
#define WS_ZERO  8208

// (P+I)^-1 NS init: X0 = AL*I + BE*M, Chebyshev on eigs(M) in [1.15, 8]
#define LOG_AL 0.6073551f
#define LOG_BE (-0.0663776f)
#define LOG_RAB (-9.1500001f)   // AL/BE

typedef __attribute__((ext_vector_type(8)))  short bf16x8;
typedef __attribute__((ext_vector_type(16))) float f32x16;

union FragU { uint4 u; bf16x8 v; };

struct Frag  { bf16x8 h0, h1, l0, l1; };
struct FragH { bf16x8 h0, h1; };

__device__ __forceinline__ float wsum(float v) {
#pragma unroll
  for (int o = 32; o > 0; o >>= 1) v += __shfl_xor(v, o, 64);
  return v;
}

// ---------------- MFMA helpers ----------------

// C = A*B + Cin, split x split (3-term scheme), 6 MFMA.
__device__ __forceinline__ f32x16 mm_ffc(const Frag A, const Frag B,
                                         const f32x16 cin) {
  f32x16 c = cin;
  c = __builtin_amdgcn_mfma_f32_32x32x16_bf16(A.h0, B.h0, c, 0, 0, 0);
  c = __builtin_amdgcn_mfma_f32_32x32x16_bf16(A.h0, B.l0, c, 0, 0, 0);
  c = __builtin_amdgcn_mfma_f32_32x32x16_bf16(A.l0, B.h0, c, 0, 0, 0);
  c = __builtin_amdgcn_mfma_f32_32x32x16_bf16(A.h1, B.h1, c, 0, 0, 0);
  c = __builtin_amdgcn_mfma_f32_32x32x16_bf16(A.h1, B.l1, c, 0, 0, 0);
  c = __builtin_amdgcn_mfma_f32_32x32x16_bf16(A.l1, B.h1, c, 0, 0, 0);
  return c;
}

__device__ __forceinline__ f32x16 mm_ff(const Frag A, const Frag B) {
  f32x16 z;
#pragma unroll
  for (int i = 0; i < 16; ++i) z[i] = 0.f;
  return mm_ffc(A, B, z);
}

// hi x hi (exact product of rounded values), 2 MFMA.
__device__ __forceinline__ f32x16 mm_hh(const FragH A, const FragH B) {
  f32x16 c;
#pragma unroll
  for (int i = 0; i < 16; ++i) c[i] = 0.f;
  c = __builtin_amdgcn_mfma_f32_32x32x16_bf16(A.h0, B.h0, c, 0, 0, 0);
  c = __builtin_amdgcn_mfma_f32_32x32x16_bf16(A.h1, B.h1, c, 0, 0, 0);
  return c;
}

// split x hi, 4 MFMA.
__device__ __forceinline__ f32x16 mm_shc(const Frag A, const FragH B,
                                         const f32x16 cin) {
  f32x16 c = cin;
  c = __builtin_amdgcn_mfma_f32_32x32x16_bf16(A.h0, B.h0, c, 0, 0, 0);
  c = __builtin_amdgcn_mfma_f32_32x32x16_bf16(A.l0, B.h0, c, 0, 0, 0);
  c = __builtin_amdgcn_mfma_f32_32x32x16_bf16(A.h1, B.h1, c, 0, 0, 0);
  c = __builtin_amdgcn_mfma_f32_32x32x16_bf16(A.l1, B.h1, c, 0, 0, 0);
  return c;
}

// pack (x0,x1) -> hi word [bf16(x1)|bf16(x0)] (RTNE) + lo residual word.
__device__ __forceinline__ void packpair(float x0, float x1,
                                         unsigned& hw, unsigned& lw) {
  unsigned h;
  asm("v_cvt_pk_bf16_f32 %0, %1, %2" : "=v"(h) : "v"(x0), "v"(x1));
  const float h0 = __uint_as_float(h << 16);
  const float h1 = __uint_as_float(h & 0xFFFF0000u);
  const float l0 = x0 - h0;
  const float l1 = x1 - h1;
  asm("v_cvt_pk_bf16_f32 %0, %1, %2" : "=v"(lw) : "v"(l0), "v"(l1));
  hw = h;
}

__device__ __forceinline__ void plswap2(unsigned a, unsigned b,
                                        unsigned& r0, unsigned& r1) {
  auto p = __builtin_amdgcn_permlane32_swap(a, b, false, false);
  r0 = p[0]; r1 = p[1];
}

// C-regs (col=ccol, rows (i&3)+8*(i>>2)+4h) -> split-bf16 fragment of the
// SAME matrix: valid B-operand always; valid A-operand iff symmetric.
__device__ __forceinline__ Frag frag_from_c(const f32x16 c) {
  unsigned hw[8], lw[8];
#pragma unroll
  for (int g = 0; g < 4; ++g) {
    packpair(c[4*g+0], c[4*g+1], hw[2*g+0], lw[2*g+0]);
    packpair(c[4*g+2], c[4*g+3], hw[2*g+1], lw[2*g+1]);
  }
  unsigned w0, w1, w2, w3;
  FragU A, B, C, D;
  plswap2(hw[0], hw[2], w0, w2);
  plswap2(hw[1], hw[3], w1, w3);
  A.u = make_uint4(w0, w1, w2, w3);          // h0 : rows h*8..h*8+7
  plswap2(hw[4], hw[6], w0, w2);
  plswap2(hw[5], hw[7], w1, w3);
  B.u = make_uint4(w0, w1, w2, w3);          // h1 : rows 16+h*8..
  plswap2(lw[0], lw[2], w0, w2);
  plswap2(lw[1], lw[3], w1, w3);
  C.u = make_uint4(w0, w1, w2, w3);          // l0
  plswap2(lw[4], lw[6], w0, w2);
  plswap2(lw[5], lw[7], w1, w3);
  D.u = make_uint4(w0, w1, w2, w3);          // l1
  Frag f; f.h0 = A.v; f.h1 = B.v; f.l0 = C.v; f.l1 = D.v;
  return f;
}

__device__ __forceinline__ Frag frag_from_c_neg(const f32x16 c) {
  f32x16 n;
#pragma unroll
  for (int i = 0; i < 16; ++i) n[i] = -c[i];
  return frag_from_c(n);
}

// hi-only pack; also returns the ROUNDED values (C-layout) for consistent
// self-correcting NS steps.
__device__ __forceinline__ FragH fragh_from_c(const f32x16 c, f32x16& cr) {
  unsigned hw[8];
#pragma unroll
  for (int g = 0; g < 4; ++g) {
    unsigned w0, w1;
    asm("v_cvt_pk_bf16_f32 %0, %1, %2" : "=v"(w0) : "v"(c[4*g+0]), "v"(c[4*g+1]));
    asm("v_cvt_pk_bf16_f32 %0, %1, %2" : "=v"(w1) : "v"(c[4*g+2]), "v"(c[4*g+3]));
    cr[4*g+0] = __uint_as_float(w0 << 16);
    cr[4*g+1] = __uint_as_float(w0 & 0xFFFF0000u);
    cr[4*g+2] = __uint_as_float(w1 << 16);
    cr[4*g+3] = __uint_as_float(w1 & 0xFFFF0000u);
    hw[2*g] = w0; hw[2*g+1] = w1;
  }
  unsigned a0, a1, a2, a3, b0, b1, b2, b3;
  plswap2(hw[0], hw[2], a0, a2);
  plswap2(hw[1], hw[3], a1, a3);
  plswap2(hw[4], hw[6], b0, b2);
  plswap2(hw[5], hw[7], b1, b3);
  FragU A, B;
  A.u = make_uint4(a0, a1, a2, a3);
  B.u = make_uint4(b0, b1, b2, b3);
  FragH f; f.h0 = A.v; f.h1 = B.v;
  return f;
}

// hi-only pack without rounded-value output (for squares).
__device__ __forceinline__ FragH fragh_only(const f32x16 c) {
  unsigned hw[8];
#pragma unroll
  for (int g = 0; g < 4; ++g) {
    asm("v_cvt_pk_bf16_f32 %0, %1, %2" : "=v"(hw[2*g])   : "v"(c[4*g+0]), "v"(c[4*g+1]));
    asm("v_cvt_pk_bf16_f32 %0, %1, %2" : "=v"(hw[2*g+1]) : "v"(c[4*g+2]), "v"(c[4*g+3]));
  }
  unsigned a0, a1, a2, a3, b0, b1, b2, b3;
  plswap2(hw[0], hw[2], a0, a2);
  plswap2(hw[1], hw[3], a1, a3);
  plswap2(hw[4], hw[6], b0, b2);
  plswap2(hw[5], hw[7], b1, b3);
  FragU A, B;
  A.u = make_uint4(a0, a1, a2, a3);
  B.u = make_uint4(b0, b1, b2, b3);
  FragH f; f.h0 = A.v; f.h1 = B.v;
  return f;
}

// 32x32 f32 row-major global matrix M -> split fragment (A of M / B of M^T).
__device__ __forceinline__ Frag frag_rowmajor(const float* __restrict__ g,
                                              int lane) {
  const int r = lane & 31, h = lane >> 5;
  const float* p = g + r * 32 + h * 8;
  const float4 v0 = *(const float4*)(p);
  const float4 v1 = *(const float4*)(p + 4);
  const float4 v2 = *(const float4*)(p + 16);
  const float4 v3 = *(const float4*)(p + 20);
  unsigned hw[8], lw[8];
  packpair(v0.x, v0.y, hw[0], lw[0]);
  packpair(v0.z, v0.w, hw[1], lw[1]);
  packpair(v1.x, v1.y, hw[2], lw[2]);
  packpair(v1.z, v1.w, hw[3], lw[3]);
  packpair(v2.x, v2.y, hw[4], lw[4]);
  packpair(v2.z, v2.w, hw[5], lw[5]);
  packpair(v3.x, v3.y, hw[6], lw[6]);
  packpair(v3.z, v3.w, hw[7], lw[7]);
  FragU A, B, C, D;
  A.u = make_uint4(hw[0], hw[1], hw[2], hw[3]);
  B.u = make_uint4(hw[4], hw[5], hw[6], hw[7]);
  C.u = make_uint4(lw[0], lw[1], lw[2], lw[3]);
  D.u = make_uint4(lw[4], lw[5], lw[6], lw[7]);
  Frag f; f.h0 = A.v; f.h1 = B.v; f.l0 = C.v; f.l1 = D.v;
  return f;
}

__device__ __forceinline__ void addID(f32x16& c, float v, const f32x16 dm) {
#pragma unroll
  for (int i = 0; i < 16; ++i) c[i] = fmaf(v, dm[i], c[i]);
}

// C-layout global load/store (row = (i&3)+8*(i>>2)+4h, col = ccol).
__device__ __forceinline__ void ldg_c(const float* __restrict__ g, f32x16& c,
                                      int ccol, int h) {
#pragma unroll
  for (int i = 0; i < 16; ++i) {
    const int row = (i & 3) + 8 * (i >> 2) + 4 * h;
    c[i] = g[row * 32 + ccol];
  }
}
__device__ __forceinline__ void stg_c(float* __restrict__ g, const f32x16 c,
                                      int ccol, int h) {
#pragma unroll
  for (int i = 0; i < 16; ++i) {
    const int row = (i & 3) + 8 * (i >> 2) + 4 * h;
    g[row * 32 + ccol] = c[i];
  }
}

// Dual logm: input Ma/Mb = Gi X Gi + I.  Output uf with L = -4*uf.
// NS inverse (Chebyshev init + 3 iters; V/X/NS1/NS2 squares hi-only — only
// final-iteration roundings survive), Cayley S=I-2Q, Gregory deg-8
// pair-Horner in w=S2^2 (w hi-only B-operand).
__device__ __forceinline__ void logm2(const f32x16 Ma, const f32x16 Mb,
                                      f32x16& ufa, f32x16& ufb,
                                      const f32x16 dm) {
  const Frag FMa = frag_from_c(Ma);
  const Frag FMb = frag_from_c(Mb);
  f32x16 ca, cb, ta, tb;
  // t = M^2 + (AL/BE) M ; V = 2I - BE*t
#pragma unroll
  for (int i = 0; i < 16; ++i) { ca[i] = LOG_RAB * Ma[i]; cb[i] = LOG_RAB * Mb[i]; }
  ta = mm_ffc(FMa, FMa, ca);
  tb = mm_ffc(FMb, FMb, cb);
  f32x16 Va, Vb;
#pragma unroll
  for (int i = 0; i < 16; ++i) {
    Va[i] = fmaf(-LOG_BE, ta[i], 2.f * dm[i]);
    Vb[i] = fmaf(-LOG_BE, tb[i], 2.f * dm[i]);
  }
  f32x16 Xra, Xrb;                            // rounded-value carriers
  const FragH FVa = fragh_from_c(Va, Xra);    // Xra = Vr for now
  const FragH FVb = fragh_from_c(Vb, Xrb);
  // X1 = BE*(M*Vr + (AL/BE)*Vr)
#pragma unroll
  for (int i = 0; i < 16; ++i) { ca[i] = LOG_RAB * Xra[i]; cb[i] = LOG_RAB * Xrb[i]; }
  ta = mm_shc(FMa, FVa, ca);
  tb = mm_shc(FMb, FVb, cb);
  f32x16 Xa, Xb;
#pragma unroll
  for (int i = 0; i < 16; ++i) { Xa[i] = LOG_BE * ta[i]; Xb[i] = LOG_BE * tb[i]; }
  FragH FXa = fragh_from_c(Xa, Xra);
  FragH FXb = fragh_from_c(Xb, Xrb);
  // NS1 (hi square, hi s): X2 = 2*X1r - M*round(X1r^2)
  {
    f32x16 sa = mm_hh(FXa, FXa);
    f32x16 sb = mm_hh(FXb, FXb);
    const FragH Fsa = fragh_only(sa);
    const FragH Fsb = fragh_only(sb);
#pragma unroll
    for (int i = 0; i < 16; ++i) { ca[i] = -2.f * Xra[i]; cb[i] = -2.f * Xrb[i]; }
    ta = mm_shc(FMa, Fsa, ca);               // -X2
    tb = mm_shc(FMb, Fsb, cb);
#pragma unroll
    for (int i = 0; i < 16; ++i) { Xa[i] = -ta[i]; Xb[i] = -tb[i]; }
    FXa = fragh_from_c(Xa, Xra);
    FXb = fragh_from_c(Xb, Xrb);
  }
  // NS2 (hi square, hi s — error squared away by NS3): X3 = 2*X2r - M*s
  {
    f32x16 sa = mm_hh(FXa, FXa);
    f32x16 sb = mm_hh(FXb, FXb);
    const FragH Fsa = fragh_only(sa);
    const FragH Fsb = fragh_only(sb);
#pragma unroll
    for (int i = 0; i < 16; ++i) { ca[i] = -2.f * Xra[i]; cb[i] = -2.f * Xrb[i]; }
    ta = mm_shc(FMa, Fsa, ca);               // -X3
    tb = mm_shc(FMb, Fsb, cb);
#pragma unroll
    for (int i = 0; i < 16; ++i) { Xa[i] = -ta[i]; Xb[i] = -tb[i]; }
    FXa = fragh_from_c(Xa, Xra);
    FXb = fragh_from_c(Xb, Xrb);
  }
  // NS3 (final — split s, split product): Q = 2*X3r - M*split(X3r^2)
  {
    f32x16 sa = mm_hh(FXa, FXa);
    f32x16 sb = mm_hh(FXb, FXb);
    const Frag Fsa = frag_from_c(sa);
    const Frag Fsb = frag_from_c(sb);
#pragma unroll
    for (int i = 0; i < 16; ++i) { ca[i] = -2.f * Xra[i]; cb[i] = -2.f * Xrb[i]; }
    ta = mm_ffc(FMa, Fsa, ca);               // -Q
    tb = mm_ffc(FMb, Fsb, cb);
  }
  const Frag FQa = frag_from_c_neg(ta);      // Q
  const Frag FQb = frag_from_c_neg(tb);
  // S2 = 4*(Q^2 - Q) + I ; Q^2 - Q via C = -Q (= ta)
  f32x16 S2a, S2b;
  {
    f32x16 va = mm_ffc(FQa, FQa, ta);
    f32x16 vb = mm_ffc(FQb, FQb, tb);
#pragma unroll
    for (int i = 0; i < 16; ++i) {
      S2a[i] = fmaf(4.f, va[i], dm[i]);
      S2b[i] = fmaf(4.f, vb[i], dm[i]);
    }
  }
  const Frag Fya = frag_from_c(S2a);
  const Frag Fyb = frag_from_c(S2b);
  f32x16 wa = mm_ff(Fya, Fya);               // w = y^2 (split square)
  f32x16 wb = mm_ff(Fyb, Fyb);
  const FragH Fwa = fragh_only(wa);          // hi-only B-operand (||w||<=0.23)
  const FragH Fwb = fragh_only(wb);
  // Gregory deg-8 pair-Horner in w
  f32x16 Ga, Gb;
#pragma unroll
  for (int i = 0; i < 16; ++i) {
    Ga[i] = fmaf(1.f/17.f, wa[i], (1.f/15.f) * S2a[i]);
    Gb[i] = fmaf(1.f/17.f, wb[i], (1.f/15.f) * S2b[i]);
  }
  addID(Ga, 1.f/13.f, dm);  addID(Gb, 1.f/13.f, dm);
  Frag FGa = frag_from_c(Ga);
  Frag FGb = frag_from_c(Gb);
#pragma unroll
  for (int s = 0; s < 3; ++s) {
    const float chi = (s == 0) ? (1.f/11.f) : (s == 1) ? (1.f/7.f) : (1.f/3.f);
    const float clo = (s == 0) ? (1.f/9.f)  : (s == 1) ? (1.f/5.f) : 1.f;
#pragma unroll
    for (int i = 0; i < 16; ++i) { ca[i] = chi * S2a[i]; cb[i] = chi * S2b[i]; }
    Ga = mm_shc(FGa, Fwa, ca);
    Gb = mm_shc(FGb, Fwb, cb);
    addID(Ga, clo, dm);  addID(Gb, clo, dm);
    FGa = frag_from_c(Ga);
    FGb = frag_from_c(Gb);
  }
  // uf = Q*G - 0.5*G ; L = -4*uf
#pragma unroll
  for (int i = 0; i < 16; ++i) { ca[i] = -0.5f * Ga[i]; cb[i] = -0.5f * Gb[i]; }
  ufa = mm_ffc(FQa, FGa, ca);
  ufb = mm_ffc(FQb, FGb, cb);
}

// In-register coupled NS sqrt/invsqrt (13 iters): A -> Y*sqrt(th)=A^{1/2},
// Z/sqrt(th)=A^{-1/2}.  All iterates symmetric (polynomials in A).
__device__ __forceinline__ void wave_sqrtinv_reg(const f32x16 A,
                                                 f32x16& Ysq, f32x16& Zis,
                                                 const f32x16 dm) {
  float ss = 0.f;
#pragma unroll
  for (int i = 0; i < 16; ++i) ss += A[i] * A[i];
  const float th = sqrtf(wsum(ss));
  const float inv = 1.f / th;
  f32x16 Y, Z;
#pragma unroll
  for (int i = 0; i < 16; ++i) { Y[i] = A[i] * inv; Z[i] = dm[i]; }
  Frag FY = frag_from_c(Y);
  Frag FZ = frag_from_c(Z);
#pragma unroll 1
  for (int it = 0; it < 13; ++it) {
    f32x16 W = mm_ff(FZ, FY);                // Z*Y
    f32x16 T;
#pragma unroll
    for (int i = 0; i < 16; ++i) T[i] = fmaf(-0.5f, W[i], 1.5f * dm[i]);
    const Frag FT = frag_from_c(T);
    Y = mm_ff(FY, FT);                       // Y*T
    Z = mm_ff(FT, FZ);                       // T*Z
    FY = frag_from_c(Y);
    FZ = frag_from_c(Z);
  }
  const float sth = sqrtf(th), isth = 1.f / sth;
#pragma unroll
  for (int i = 0; i < 16; ++i) { Ysq[i] = Y[i] * sth; Zis[i] = Z[i] * isth; }
}

// ------------------------------- kernels -----------------------------------

// per-n sum over the q matrices: 4 waves x q/4 matrices + LDS merge.
__global__ __launch_bounds__(256) void k1_xsum(const float* __restrict__ X,
                                               float* __restrict__ scr,
                                               int N, int q) {
  __shared__ float RED[3][1024];
  const int n = blockIdx.x;
  const int w = threadIdx.x >> 6, lane = threadIdx.x & 63;
  const int qw = (q + 3) >> 2;
  const int jbeg = w * qw;
  const int jend = min(q, jbeg + qw);
  float acc[16];
#pragma unroll
  for (int i = 0; i < 16; ++i) acc[i] = 0.f;
  const float* base = X + (size_t)n * q * 1024 + lane * 16;
#pragma unroll 1
  for (int j = jbeg; j < jend; ++j) {
    const float* g = base + (size_t)j * 1024;
#pragma unroll
    for (int u = 0; u < 4; ++u) {
      float4 v = *(const float4*)(g + u * 4);
      acc[u*4+0] += v.x; acc[u*4+1] += v.y; acc[u*4+2] += v.z; acc[u*4+3] += v.w;
    }
  }
  if (w > 0) {
#pragma unroll
    for (int u = 0; u < 4; ++u)
      *(float4*)(&RED[w - 1][lane * 16 + u * 4]) =
          make_float4(acc[u*4+0], acc[u*4+1], acc[u*4+2], acc[u*4+3]);
  }
  __syncthreads();
  if (w == 0) {
    float* dst = scr + (size_t)n * 1024 + lane * 16;
#pragma unroll
    for (int u = 0; u < 4; ++u) {
      float4 r0 = *(const float4*)(&RED[0][lane * 16 + u * 4]);
      float4 r1 = *(const float4*)(&RED[1][lane * 16 + u * 4]);
      float4 r2 = *(const float4*)(&RED[2][lane * 16 + u * 4]);
      *(float4*)(dst + u * 4) = make_float4(
          acc[u*4+0] + r0.x + r1.x + r2.x, acc[u*4+1] + r0.y + r1.y + r2.y,
          acc[u*4+2] + r0.z + r1.z + r2.z, acc[u*4+3] + r0.w + r1.w + r2.w);
    }
  }
}

// gather-by-domain reduce: dst[d*1024+e] += sum_{n: ds[n]==d} src[n*1024+e].
__global__ __launch_bounds__(256) void kred(const int* __restrict__ ds,
                                            const float* __restrict__ src,
                                            float* __restrict__ dst,
                                            int N, int D) {
  const int obln = D * 4;
  const int chunk = blockIdx.x / obln;
  const int ob    = blockIdx.x % obln;
  const int out   = ob * 256 + threadIdx.x;
  const int d = out >> 10, e = out & 1023;
  const int cs = (N + 7) >> 3;
  const int n0 = chunk * cs;
  const int n1 = min(N, n0 + cs);
  float acc = 0.f;
#pragma unroll 16
  for (int n = n0; n < n1; ++n) {
    const float v = src[(size_t)n * 1024 + e];
    acc += (ds[n] == d) ? v : 0.f;
  }
  atomicAdd(dst + out, acc);
}

__global__ __launch_bounds__(128) void k2_g0funcs(float* __restrict__ ws,
                                                  const int* __restrict__ ds,
                                                  const float* __restrict__ B,
                                                  const float* __restrict__ R,
                                                  int N, int q) {
  const int d = blockIdx.x, tid = threadIdx.x;
  const int w = tid >> 6, lane = tid & 63;
  const int ccol = lane & 31, h = lane >> 5;
  f32x16 dm;
#pragma unroll
  for (int i = 0; i < 16; ++i) {
    const int row = (i & 3) + 8 * (i >> 2) + 4 * h;
    dm[i] = (row == ccol) ? 1.f : 0.f;
  }
  f32x16 A, Y, Z;
  if (w == 0) {
    int cnt = 0;
    for (int i = lane; i < N; i += 64) cnt += (ds[i] == d) ? 1 : 0;
    const float cntf = wsum((float)cnt);
    if (lane == 0) ws[WS_CNT + d] = cntf;
    ldg_c(ws + WS_G0SUM + d * 1024, A, ccol, h);
    const float s = 1.f / ((float)q * cntf);
#pragma unroll
    for (int i = 0; i < 16; ++i) A[i] *= s;
    wave_sqrtinv_reg(A, Y, Z, dm);
    stg_c(ws + WS_G0SQ  + d * 1024, Y, ccol, h);
    stg_c(ws + WS_G0ISQ + d * 1024, Z, ccol, h);
  } else {
    ldg_c(B + d * 1024, A, ccol, h);
    wave_sqrtinv_reg(A, Y, Z, dm);             // Y = Bs
    // W = Bs * R  (merged output congruence: out = W Xp W^T)
    const Frag FBs = frag_from_c(Y);           // A-op (symmetric)
    f32x16 Rc;
    ldg_c(R + d * 1024, Rc, ccol, h);
    const Frag FRb = frag_from_c(Rc);          // B-op of R
    f32x16 W = mm_ff(FBs, FRb);
    stg_c(ws + WS_BSQ + d * 1024, W, ccol, h);
  }
}

__global__ __launch_bounds__(256, 2) void k3_gt(const float* __restrict__ X,
                                                const int* __restrict__ ds,
                                                const float* __restrict__ ws,
                                                float* __restrict__ scr, int q) {
  __shared__ float RED[3][1024];
  const int n = blockIdx.x, tid = threadIdx.x;
  const int w = tid >> 6, lane = tid & 63;
  const int ccol = lane & 31, h = lane >> 5;
  f32x16 dm;
#pragma unroll
  for (int i = 0; i < 16; ++i) {
    const int row = (i & 3) + 8 * (i >> 2) + 4 * h;
    dm[i] = (row == ccol) ? 1.f : 0.f;
  }
  const int d = ds[n];
  const Frag FGi = frag_rowmajor(ws + WS_G0ISQ + d * 1024, lane);
  f32x16 acc;
#pragma unroll
  for (int i = 0; i < 16; ++i) acc[i] = 0.f;
  const int qw = (q + 3) >> 2;
  const int jbeg = w * qw;
  const int jend = min(q, jbeg + qw);
#pragma unroll 1
  for (int j = jbeg; j < jend; j += 2) {
    const bool dual = (j + 1 < jend);
    const size_t ma = (size_t)n * q + j;
    const size_t mb = dual ? ma + 1 : ma;
    const Frag FXa = frag_rowmajor(X + ma * 1024, lane);   // symmetric
    const Frag FXb = frag_rowmajor(X + mb * 1024, lane);
    f32x16 ua = mm_ff(FXa, FGi);               // X * Gi
    f32x16 ub = mm_ff(FXb, FGi);
    const Frag Fua = frag_from_c(ua);          // B-only use
    const Frag Fub = frag_from_c(ub);
    f32x16 Pa = mm_ffc(FGi, Fua, dm);          // Gi X Gi + I
    f32x16 Pb = mm_ffc(FGi, Fub, dm);
    f32x16 ufa, ufb;
    logm2(Pa, Pb, ufa, ufb, dm);               // L = -4*uf
#pragma unroll
    for (int i = 0; i < 16; ++i) acc[i] = fmaf(-4.f, ufa[i], acc[i]);
    if (dual) {
#pragma unroll
      for (int i = 0; i < 16; ++i) acc[i] = fmaf(-4.f, ufb[i], acc[i]);
    }
  }
  // merge 4 waves via LDS, then ONE hoisted congruence by wave 3:
  // sum_j Gs L_j Gs = Gs (sum_j L_j) Gs
  if (w < 3) {
#pragma unroll
    for (int i = 0; i < 16; ++i) {
      const int row = (i & 3) + 8 * (i >> 2) + 4 * h;
      RED[w][row * 32 + ccol] = acc[i];
    }
  }
  __syncthreads();
  if (w == 3) {
#pragma unroll
    for (int i = 0; i < 16; ++i) {
      const int row = (i & 3) + 8 * (i >> 2) + 4 * h;
      const int e = row * 32 + ccol;
      acc[i] += RED[0][e] + RED[1][e] + RED[2][e];
    }
    const Frag FGs = frag_rowmajor(ws + WS_G0SQ + d * 1024, lane);
    const Frag FA  = frag_from_c(acc);         // symmetric
    f32x16 u = mm_ff(FA, FGs);                 // (sumL) * Gs
    const Frag Fu = frag_from_c(u);
    u = mm_ff(FGs, Fu);                        // Gs (sumL) Gs
    float* g = scr + (size_t)n * 1024;
#pragma unroll
    for (int i = 0; i < 16; ++i) {
      const int row = (i & 3) + 8 * (i >> 2) + 4 * h;
      g[row * 32 + ccol] = u[i];
    }
  }
}

__global__ __launch_bounds__(64) void k4_mean(float* __restrict__ ws, int q) {
  const int d = blockIdx.x, lane = threadIdx.x;
  const int ccol = lane & 31, h = lane >> 5;
  f32x16 dm;
#pragma unroll
  for (int i = 0; i < 16; ++i) {
    const int row = (i & 3) + 8 * (i >> 2) + 4 * h;
    dm[i] = (row == ccol) ? 1.f : 0.f;
  }
  const float cntf = ws[WS_CNT + d];
  f32x16 Gi, GT;
  ldg_c(ws + WS_G0ISQ + d * 1024, Gi, ccol, h);
  ldg_c(ws + WS_GTSUM + d * 1024, GT, ccol, h);
  const float s = 1.f / ((float)q * cntf);
#pragma unroll
  for (int i = 0; i < 16; ++i) GT[i] *= s;
  const Frag FGi = frag_from_c(Gi);
  const Frag FGT = frag_from_c(GT);
  f32x16 u = mm_ff(FGT, FGi);                  // GT*Gi
  Frag Fu = frag_from_c(u);
  f32x16 E = mm_ff(FGi, Fu);                   // E = Gi GT Gi
  // exp(E), deg-10 pair-Horner in w = E^2
  const Frag FE = frag_from_c(E);
  f32x16 wm = mm_ff(FE, FE);
  const Frag Fw = frag_from_c(wm);
  f32x16 G;
#pragma unroll
  for (int i = 0; i < 16; ++i)
    G[i] = fmaf(2.7557319e-7f, wm[i], 2.7557319e-6f * E[i]);  // 1/10!, 1/9!
  addID(G, 1.f/40320.f, dm);                                  // 1/8!
  Frag FG = frag_from_c(G);
#pragma unroll
  for (int sstep = 0; sstep < 4; ++sstep) {
    const float chi = (sstep == 0) ? (1.f/5040.f) : (sstep == 1) ? (1.f/120.f)
                     : (sstep == 2) ? (1.f/6.f) : 1.f;
    const float clo = (sstep == 0) ? (1.f/720.f) : (sstep == 1) ? (1.f/24.f)
                     : (sstep == 2) ? 0.5f : 1.f;
    f32x16 cc;
#pragma unroll
    for (int i = 0; i < 16; ++i) cc[i] = chi * E[i];
    G = mm_ffc(FG, Fw, cc);
    addID(G, clo, dm);
    FG = frag_from_c(G);
  }
  // Gm = Gs * exp(E) * Gs
  f32x16 Gs;
  ldg_c(ws + WS_G0SQ + d * 1024, Gs, ccol, h);
  const Frag FGs = frag_from_c(Gs);
  u = mm_ff(FG, FGs);                          // H*Gs  (H symmetric)
  Fu = frag_from_c(u);
  f32x16 Gm = mm_ff(FGs, Fu);                  // Gs H Gs
  f32x16 Y, Z;
  wave_sqrtinv_reg(Gm, Y, Z, dm);
  stg_c(ws + WS_GISQ + d * 1024, Z, ccol, h);
}

__global__ __launch_bounds__(256, 2) void k5_logxc(const float* __restrict__ X,
                                                   const int* __restrict__ ds,
                                                   float* __restrict__ ws,
                                                   float* __restrict__ Lout, int q) {
  __shared__ float V4[4];
  const int n = blockIdx.x, tid = threadIdx.x;
  const int w = tid >> 6, lane = tid & 63;
  const int ccol = lane & 31, h = lane >> 5;
  f32x16 dm;
#pragma unroll
  for (int i = 0; i < 16; ++i) {
    const int row = (i & 3) + 8 * (i >> 2) + 4 * h;
    dm[i] = (row == ccol) ? 1.f : 0.f;
  }
  const int d = ds[n];
  const Frag FGi = frag_rowmajor(ws + WS_GISQ + d * 1024, lane);
  float vacc = 0.f;
  const int qw = (q + 3) >> 2;
  const int jbeg = w * qw;
  const int jend = min(q, jbeg + qw);
#pragma unroll 1
  for (int j = jbeg; j < jend; j += 2) {
    const bool dual = (j + 1 < jend);
    const size_t ma = (size_t)n * q + j;
    const size_t mb = dual ? ma + 1 : ma;
    const Frag FXa = frag_rowmajor(X + ma * 1024, lane);
    const Frag FXb = frag_rowmajor(X + mb * 1024, lane);
    f32x16 ua = mm_ff(FXa, FGi);               // X * Gi
    f32x16 ub = mm_ff(FXb, FGi);
    const Frag Fua = frag_from_c(ua);
    const Frag Fub = frag_from_c(ub);
    f32x16 Pa = mm_ffc(FGi, Fua, dm);          // Gi X Gi + I
    f32x16 Pb = mm_ffc(FGi, Fub, dm);
    f32x16 ufa, ufb;
    logm2(Pa, Pb, ufa, ufb, dm);               // L = -4*uf
    float sq = 0.f;
#pragma unroll
    for (int i = 0; i < 16; ++i) sq += ufa[i] * ufa[i];
    vacc += sq;
    float* ga = Lout + ma * 1024;
#pragma unroll
    for (int i = 0; i < 16; ++i) {
      const int row = (i & 3) + 8 * (i >> 2) + 4 * h;
      ga[row * 32 + ccol] = -4.f * ufa[i];
    }
    if (dual) {
      float sqb = 0.f;
#pragma unroll
      for (int i = 0; i < 16; ++i) sqb += ufb[i] * ufb[i];
      vacc += sqb;
      float* gb = Lout + mb * 1024;
#pragma unroll
      for (int i = 0; i < 16; ++i) {
        const int row = (i & 3) + 8 * (i >> 2) + 4 * h;
        gb[row * 32 + ccol] = -4.f * ufb[i];
      }
    }
  }
  vacc = wsum(vacc * 16.f);                    // ||L||^2 = 16*||uf||^2
  if (lane == 0) V4[w] = vacc;
  __syncthreads();
  if (tid == 0) ws[WS_VPART + n] = V4[0] + V4[1] + V4[2] + V4[3];
}

__global__ __launch_bounds__(64) void k6_p(const int* __restrict__ ds,
                                           float* __restrict__ ws,
                                           int N, int q, int D) {
  const int lane = threadIdx.x;
  float a0 = 0.f, a1 = 0.f, a2 = 0.f, a3 = 0.f;
  for (int n = lane; n < N; n += 64) {
    const int d = ds[n];
    const float v = ws[WS_VPART + n];
    a0 += (d == 0) ? v : 0.f;
    a1 += (d == 1) ? v : 0.f;
    a2 += (d == 2) ? v : 0.f;
    a3 += (d == 3) ? v : 0.f;
  }
  a0 = wsum(a0); a1 = wsum(a1); a2 = wsum(a2); a3 = wsum(a3);
  if (lane < D) {
    const float var0 = (lane == 0) ? a0 : (lane == 1) ? a1 : (lane == 2) ? a2 : a3;
    const float cntf = ws[WS_CNT + lane];
    const float var = var0 / ((float)q * cntf);
    ws[WS_P + lane] = sqrtf(1.f / (var + 1e-5f));
  }
}

__global__ __launch_bounds__(256, 2) void k7_out(const int* __restrict__ ds,
                                                 const float* __restrict__ ws,
                                                 float* __restrict__ io, int q) {
  const int n = blockIdx.x, tid = threadIdx.x;
  const int w = tid >> 6, lane = tid & 63;
  const int ccol = lane & 31, h = lane >> 5;
  f32x16 dm;
#pragma unroll
  for (int i = 0; i < 16; ++i) {
    const int row = (i & 3) + 8 * (i >> 2) + 4 * h;
    dm[i] = (row == ccol) ? 1.f : 0.f;
  }
  const int d = ds[n];
  const Frag FW = frag_rowmajor(ws + WS_BSQ + d * 1024, lane);  // A of W / B of W^T
  const float pe = ws[WS_P + d];
  // Taylor coeffs of exp(pe*L), deg 9 (||pe*L|| <~ 1.2 -> trunc < 2e-6)
  float coef[10];
  coef[0] = 1.f;
  coef[1] = pe;
  coef[2] = coef[1] * pe * 0.5f;
  coef[3] = coef[2] * pe * (1.f / 3.f);
  coef[4] = coef[3] * pe * 0.25f;
  coef[5] = coef[4] * pe * 0.2f;
  coef[6] = coef[5] * pe * (1.f / 6.f);
  coef[7] = coef[6] * pe * (1.f / 7.f);
  coef[8] = coef[7] * pe * 0.125f;
  coef[9] = coef[8] * pe * (1.f / 9.f);
  const int qw = (q + 3) >> 2;
  const int jbeg = w * qw;
  const int jend = min(q, jbeg + qw);
#pragma unroll 1
  for (int j = jbeg; j < jend; j += 2) {
    const bool dual = (j + 1 < jend);
    const size_t ma = (size_t)n * q + j;
    const size_t mb = dual ? ma + 1 : ma;
    float* ga = io + ma * 1024;
    float* gb = io + mb * 1024;
    f32x16 Lca, Lcb;
#pragma unroll
    for (int i = 0; i < 16; ++i) {
      const int row = (i & 3) + 8 * (i >> 2) + 4 * h;
      Lca[i] = ga[row * 32 + ccol];
      Lcb[i] = gb[row * 32 + ccol];
    }
    const Frag FLa = frag_from_c(Lca);         // symmetric
    const Frag FLb = frag_from_c(Lcb);
    f32x16 ta = mm_ff(FLa, FLa);               // wmat = L^2
    f32x16 tb = mm_ff(FLb, FLb);
    const Frag Fwa = frag_from_c(ta);          // split (||L^2|| up to ~3.6)
    const Frag Fwb = frag_from_c(tb);
    // Xp = exp(pe*L), deg-9 pair-Horner in w; coef[kk]*L folded into C
    f32x16 Ga, Gb;
#pragma unroll
    for (int i = 0; i < 16; ++i) {
      Ga[i] = coef[9] * Lca[i];
      Gb[i] = coef[9] * Lcb[i];
    }
    addID(Ga, coef[8], dm);  addID(Gb, coef[8], dm);
    Frag FGa = frag_from_c(Ga);
    Frag FGb = frag_from_c(Gb);
#pragma unroll
    for (int kk = 7; kk >= 1; kk -= 2) {       // full unroll: coef idx constant
      f32x16 cca, ccb;
#pragma unroll
      for (int i = 0; i < 16; ++i) {
        cca[i] = coef[kk] * Lca[i];
        ccb[i] = coef[kk] * Lcb[i];
      }
      Ga = mm_ffc(FGa, Fwa, cca);
      Gb = mm_ffc(FGb, Fwb, ccb);
      addID(Ga, coef[kk - 1], dm);  addID(Gb, coef[kk - 1], dm);
      FGa = frag_from_c(Ga);
      FGb = frag_from_c(Gb);
    }
    // out = W Xp W^T  (W = Bs R precomputed)
    ta = mm_ff(FGa, FW);                       // Xp * W^T (FGa = Xp, symmetric)
    tb = mm_ff(FGb, FW);
    const Frag Fta = frag_from_c(ta);
    const Frag Ftb = frag_from_c(tb);
    ta = mm_ff(FW, Fta);                       // W * (Xp W^T)
    tb = mm_ff(FW, Ftb);
#pragma unroll
    for (int i = 0; i < 16; ++i) {
      const int row = (i & 3) + 8 * (i >> 2) + 4 * h;
      ga[row * 32 + ccol] = ta[i];
    }
    if (dual) {
#pragma unroll
      for (int i = 0; i < 16; ++i) {
        const int row = (i & 3) + 8 * (i >> 2) + 4 * h;
        gb[row * 32 + ccol] = tb[i];
      }
    }
  }
}

// ------------------------------- launcher ----------------------------------

extern "C" void kernel_launch(void* const* d_in, const int* in_sizes, int n_in,
                              void* d_out, int out_size, void* d_ws, size_t ws_size,
                              hipStream_t stream) {
  const float* X  = (const float*)d_in[0];
  const int*   ds = (const int*)d_in[1];
  const float* R  = (const float*)d_in[2];
  const float* B  = (const float*)d_in[3];
  float* out = (float*)d_out;
  float* ws  = (float*)d_ws;
  const int N = in_sizes[1];
  const int q = in_sizes[0] / (N * 1024);
  const int D = in_sizes[2] / 1024;
  (void)n_in; (void)out_size; (void)ws_size;

  // d_out doubles as an 8 MB reduction scratch until k5 overwrites it.
  float* scr = out;

  hipMemsetAsync(d_ws, 0, WS_ZERO * sizeof(float), stream);
  k1_xsum   <<<dim3(N), dim3(256), 0, stream>>>(X, scr, N, q);
  kred      <<<dim3(8 * D * 4), dim3(256), 0, stream>>>(ds, scr, ws + WS_G0SUM, N, D);
  k2_g0funcs<<<dim3(D), dim3(128), 0, stream>>>(ws, ds, B, R, N, q);
  k3_gt     <<<dim3(N), dim3(256), 0, stream>>>(X, ds, ws, scr, q);
  kred      <<<dim3(8 * D * 4), dim3(256), 0, stream>>>(ds, scr, ws + WS_GTSUM, N, D);
  k4_mean   <<<dim3(D), dim3(64),  0, stream>>>(ws, q);
  k5_logxc  <<<dim3(N), dim3(256), 0, stream>>>(X, ds, ws, out, q);
  k6_p      <<<dim3(1), dim3(64),  0, stream>>>(ds, ws, N, q, D);
  k7_out    <<<dim3(N), dim3(256), 0, stream>>>(ds, ws, out, q);
}